// Round 12
// baseline (386.461 us; speedup 1.0000x reference)
//
#include <hip/hip_runtime.h>
#include <math.h>

#define HC 256      // H*C
#define NHEAD 4
#define NEG_SLOPE 0.2f
#define GG 64       // graphs

typedef unsigned short u16;
typedef unsigned int u32;
typedef __attribute__((ext_vector_type(8))) short short8;
typedef __attribute__((ext_vector_type(4))) float f32x4;

typedef __attribute__((address_space(1))) const void as1_void;
typedef __attribute__((address_space(3))) void as3_void;

static __device__ inline u16 f2bf_rn(float f) {
  u32 x = __float_as_uint(f);
  u32 r = (x + 0x7fffu + ((x >> 16) & 1u)) >> 16;
  return (u16)r;
}
static __device__ inline float bf2f(u16 u) { return __uint_as_float(((u32)u) << 16); }
static __device__ inline int swz(int b) { return b ^ (((b >> 8) & 7) << 4); }

// ---------------- CSR build ----------------

__global__ void count_deg_kernel(const int* __restrict__ ei, int E, int Nn, int* __restrict__ deg) {
  int idx = blockIdx.x * 256 + threadIdx.x;
  int Et = E + Nn;
  if (idx >= Et) return;
  int d = (idx < E) ? ei[E + idx] : (idx - E);   // row1 of edge_index = dst; self loops appended
  atomicAdd(&deg[d], 1);
}

__global__ void scan_partial_kernel(const int* __restrict__ deg, int Nn,
                                    int* __restrict__ rowptr, int* __restrict__ bsum) {
  __shared__ int s[256];
  int t = threadIdx.x, i = blockIdx.x * 256 + t;
  int v = (i < Nn) ? deg[i] : 0;
  s[t] = v; __syncthreads();
  for (int off = 1; off < 256; off <<= 1) {
    int x = (t >= off) ? s[t - off] : 0; __syncthreads();
    s[t] += x; __syncthreads();
  }
  if (i < Nn) rowptr[i] = s[t] - v;          // exclusive within block
  if (t == 255) bsum[blockIdx.x] = s[t];     // block total
}

__global__ void scan_bsum_kernel(int* __restrict__ bsum, int nb) {
  __shared__ int s[512];
  int t = threadIdx.x;
  int v = (t < nb) ? bsum[t] : 0;
  s[t] = v; __syncthreads();
  for (int off = 1; off < 512; off <<= 1) {
    int x = (t >= off) ? s[t - off] : 0; __syncthreads();
    s[t] += x; __syncthreads();
  }
  if (t < nb) bsum[t] = s[t] - v;            // exclusive block offsets
}

__global__ void scan_add_kernel(int* __restrict__ rowptr, const int* __restrict__ bsum,
                                int Nn, int Etot) {
  int i = blockIdx.x * 256 + threadIdx.x;
  if (i < Nn) rowptr[i] += bsum[blockIdx.x];
  if (i == 0) rowptr[Nn] = Etot;
}

__global__ void fill_csr_kernel(const int* __restrict__ ei, int E, int Nn,
                                const int* __restrict__ rowptr, int* __restrict__ cursor,
                                int* __restrict__ col) {
  int idx = blockIdx.x * 256 + threadIdx.x;
  int Et = E + Nn;
  if (idx >= Et) return;
  int s, d;
  if (idx < E) { s = ei[idx]; d = ei[E + idx]; } else { s = d = idx - E; }
  int pos = atomicAdd(&cursor[d], 1);
  col[rowptr[d] + pos] = s;
}

// ---------------- W transpose + bf16: Wt[n][k] ----------------

__global__ void convert_w_kernel(const float* __restrict__ W, u16* __restrict__ hi) {
  int idx = blockIdx.x * 256 + threadIdx.x;    // 65536 threads
  if (idx >= 256 * 256) return;
  int k = idx >> 8, n = idx & 255;             // coalesced read of W[k][n]
  hi[n * 256 + k] = f2bf_rn(W[idx]);
}

// ---------------- layer 1 (rank-2 factorization) ----------------
// va[k*4+q] = sum_{c in head q} W1[k][c]*a1s[c]; va[8+..] same with a1d.

__global__ void prep_va_kernel(const float* __restrict__ W1, const float* __restrict__ a1s,
                               const float* __restrict__ a1d, float* __restrict__ va) {
  int t = threadIdx.x;                       // 256 = 4 waves, wave q = head q
  int q = t >> 6, lane = t & 63;
  int c = t;
  float asv = a1s[c], adv = a1d[c];
  float w0 = W1[c], w1 = W1[256 + c];
  float s0 = w0 * asv, s1 = w1 * asv, d0 = w0 * adv, d1 = w1 * adv;
  #pragma unroll
  for (int off = 32; off >= 1; off >>= 1) {
    s0 += __shfl_xor(s0, off, 64); s1 += __shfl_xor(s1, off, 64);
    d0 += __shfl_xor(d0, off, 64); d1 += __shfl_xor(d1, off, 64);
  }
  if (lane == 0) {
    va[q] = s0; va[4 + q] = s1;
    va[8 + q] = d0; va[12 + q] = d1;
  }
}

// als/ald directly from x: als[q] = x0*va[q] + x1*va[4+q]
__global__ void logits1_kernel(const float* __restrict__ x, const float* __restrict__ va,
                               float* __restrict__ als, float* __restrict__ ald, int Nn) {
  int node = blockIdx.x * 256 + threadIdx.x;
  if (node >= Nn) return;
  float2 xv = *(const float2*)&x[(size_t)node * 2];
  float4 vs0 = *(const float4*)&va[0], vs1 = *(const float4*)&va[4];
  float4 vd0 = *(const float4*)&va[8], vd1 = *(const float4*)&va[12];
  float4 s, d;
  s.x = xv.x * vs0.x + xv.y * vs1.x; s.y = xv.x * vs0.y + xv.y * vs1.y;
  s.z = xv.x * vs0.z + xv.y * vs1.z; s.w = xv.x * vs0.w + xv.y * vs1.w;
  d.x = xv.x * vd0.x + xv.y * vd1.x; d.y = xv.x * vd0.y + xv.y * vd1.y;
  d.z = xv.x * vd0.z + xv.y * vd1.z; d.w = xv.x * vd0.w + xv.y * vd1.w;
  *(float4*)&als[node * 4] = s;
  *(float4*)&ald[node * 4] = d;
}

// fused max-free softmax + x-space gather: xbar[node][q*2+k] = (sum_e p^q_e x[s_e][k])/S_q
__global__ void sm_gather1_kernel(const float* __restrict__ x,
    const float* __restrict__ als, const float* __restrict__ ald,
    const int* __restrict__ rowptr, const int* __restrict__ col,
    float* __restrict__ xbar, int Nn) {
  int node = blockIdx.x * 256 + threadIdx.x;
  if (node >= Nn) return;
  int rs = rowptr[node], re = rowptr[node + 1];
  float4 ad = *(const float4*)&ald[node * 4];
  float S0 = 0.f, S1 = 0.f, S2 = 0.f, S3 = 0.f;
  float a0 = 0.f, a1 = 0.f, a2 = 0.f, a3 = 0.f, a4 = 0.f, a5 = 0.f, a6 = 0.f, a7 = 0.f;
  for (int i = rs; i < re; ++i) {
    int s = col[i];
    float4 a = *(const float4*)&als[(size_t)s * 4];
    float2 xs = *(const float2*)&x[(size_t)s * 2];
    float e0 = a.x + ad.x; e0 = e0 > 0.f ? e0 : NEG_SLOPE * e0;
    float e1 = a.y + ad.y; e1 = e1 > 0.f ? e1 : NEG_SLOPE * e1;
    float e2 = a.z + ad.z; e2 = e2 > 0.f ? e2 : NEG_SLOPE * e2;
    float e3 = a.w + ad.w; e3 = e3 > 0.f ? e3 : NEG_SLOPE * e3;
    float p0 = __expf(e0), p1 = __expf(e1), p2 = __expf(e2), p3 = __expf(e3);
    S0 += p0; S1 += p1; S2 += p2; S3 += p3;
    a0 += p0 * xs.x; a1 += p0 * xs.y;
    a2 += p1 * xs.x; a3 += p1 * xs.y;
    a4 += p2 * xs.x; a5 += p2 * xs.y;
    a6 += p3 * xs.x; a7 += p3 * xs.y;
  }
  float i0 = 1.f / (S0 + 1e-16f), i1 = 1.f / (S1 + 1e-16f);
  float i2 = 1.f / (S2 + 1e-16f), i3 = 1.f / (S3 + 1e-16f);
  *(float4*)&xbar[(size_t)node * 8]     = make_float4(a0 * i0, a1 * i0, a2 * i1, a3 * i1);
  *(float4*)&xbar[(size_t)node * 8 + 4] = make_float4(a4 * i2, a5 * i2, a6 * i3, a7 * i3);
}

// expand: out1[node][c] = xbar_q . W1[:,c] + b1[c], ELU, bf16-packed
__global__ __launch_bounds__(256) void expand1_kernel(const float* __restrict__ xbar,
    const float* __restrict__ W1, const float* __restrict__ b1,
    u16* __restrict__ out16, int Nn) {
  int node = blockIdx.x * 4 + (threadIdx.x >> 6);
  int lane = threadIdx.x & 63;
  if (node >= Nn) return;
  int hA = lane >> 5;                        // head of ch pair A (0/1); pair B head = 2+hA
  float4 xb0 = *(const float4*)&xbar[(size_t)node * 8];      // heads 0,1
  float4 xb1 = *(const float4*)&xbar[(size_t)node * 8 + 4];  // heads 2,3
  float xA0 = hA ? xb0.z : xb0.x, xA1 = hA ? xb0.w : xb0.y;
  float xB0 = hA ? xb1.z : xb1.x, xB1 = hA ? xb1.w : xb1.y;
  int cA = 2 * lane, cB = 128 + 2 * lane;
  float2 wA0 = *(const float2*)&W1[cA], wA1 = *(const float2*)&W1[256 + cA];
  float2 wB0 = *(const float2*)&W1[cB], wB1 = *(const float2*)&W1[256 + cB];
  float2 bA = *(const float2*)&b1[cA],  bB = *(const float2*)&b1[cB];
  float o0 = xA0 * wA0.x + xA1 * wA1.x + bA.x;
  float o1 = xA0 * wA0.y + xA1 * wA1.y + bA.y;
  float o2 = xB0 * wB0.x + xB1 * wB1.x + bB.x;
  float o3 = xB0 * wB0.y + xB1 * wB1.y + bB.y;
  o0 = o0 > 0.f ? o0 : (__expf(o0) - 1.0f);
  o1 = o1 > 0.f ? o1 : (__expf(o1) - 1.0f);
  o2 = o2 > 0.f ? o2 : (__expf(o2) - 1.0f);
  o3 = o3 > 0.f ? o3 : (__expf(o3) - 1.0f);
  u32* o32 = (u32*)out16;
  o32[(size_t)node * 128 + lane]      = (u32)f2bf_rn(o0) | ((u32)f2bf_rn(o1) << 16);
  o32[(size_t)node * 128 + 64 + lane] = (u32)f2bf_rn(o2) | ((u32)f2bf_rn(o3) << 16);
}

// ---------------- 3-stage pipelined MFMA GEMM ----------------
// global_load_lds (16B) staging, triple-buffered LDS, prefetch distance 2,
// counted vmcnt + raw s_barrier (loads stay in flight across barriers).
// LDS layout: LDS[swz(b)] = data[b]  (achieved by inverse-swizzling the
// per-lane global SOURCE address; LDS dest is linear: base + lane*16).

#define GBM 128
#define GBN 128

__global__ __launch_bounds__(256) void gemm_mfma_kernel(
    const u16* __restrict__ A, const u16* __restrict__ Bt,
    const float* __restrict__ as_, const float* __restrict__ ad_,
    u16* __restrict__ C16, float* __restrict__ als, float* __restrict__ ald, int Mrows) {
  __shared__ __align__(16) u16 sA[3][4096];   // 3 x 8KB
  __shared__ __align__(16) u16 sB[3][4096];   // 3 x 8KB
  int bc = blockIdx.x, br = blockIdx.y;
  int tid = threadIdx.x;
  int wid = tid >> 6, lane = tid & 63;
  int wr = wid >> 1, wc = wid & 1;             // 2x2 waves; each 64x64 output
  int row0 = br * GBM, col0 = bc * GBN;
  int fr = lane & 15, fg = lane >> 4;

  // staging: slot s = j*256 + tid; LDS byte s*16 receives global linear byte swz(s*16)
  const u16* ga[2];
  const u16* gb[2];
  u16* lA[2];
  u16* lB[2];
  #pragma unroll
  for (int j = 0; j < 2; ++j) {
    int sbase = j * 256 + wid * 64;            // wave-uniform slot base
    int s = sbase + lane;
    int b = swz(s * 16);                       // source linear byte within tile
    int row = b >> 6, inner = (b & 63) >> 1;   // tile row, u16 offset in row-chunk
    int gr = row0 + row; if (gr >= Mrows) gr = Mrows - 1;
    ga[j] = A  + (size_t)gr * 256 + inner;
    gb[j] = Bt + (size_t)(col0 + row) * 256 + inner;
    lA[j] = &sA[0][0] + sbase * 8;             // wave-uniform LDS base (lane*16 added by HW)
    lB[j] = &sB[0][0] + sbase * 8;
  }

  int rofA[4], rofB[4];
  #pragma unroll
  for (int m = 0; m < 4; ++m) rofA[m] = swz((wr * 64 + m * 16 + fr) * 64 + fg * 16);
  #pragma unroll
  for (int n = 0; n < 4; ++n) rofB[n] = swz((wc * 64 + n * 16 + fr) * 64 + fg * 16);

  f32x4 acc[4][4];
  #pragma unroll
  for (int m = 0; m < 4; ++m)
    #pragma unroll
    for (int n = 0; n < 4; ++n) acc[m][n] = (f32x4){0.f, 0.f, 0.f, 0.f};

  auto stage = [&](int buf, int kt) {
    #pragma unroll
    for (int j = 0; j < 2; ++j) {
      __builtin_amdgcn_global_load_lds((as1_void*)(ga[j] + kt * 32),
                                       (as3_void*)(lA[j] + buf * 4096), 16, 0, 0);
      __builtin_amdgcn_global_load_lds((as1_void*)(gb[j] + kt * 32),
                                       (as3_void*)(lB[j] + buf * 4096), 16, 0, 0);
    }
  };

  // prologue: tiles 0 and 1 in flight; wait tile 0 (4 newest stay outstanding)
  stage(0, 0);
  stage(1, 1);
  asm volatile("s_waitcnt vmcnt(4)\ns_barrier" ::: "memory");
  __builtin_amdgcn_sched_barrier(0);

  const char* sAc = (const char*)&sA[0][0];
  const char* sBc = (const char*)&sB[0][0];

  #pragma unroll
  for (int kt = 0; kt < 8; ++kt) {             // K = 8 x 32
    int buf = kt % 3;
    if (kt + 2 < 8) stage((kt + 2) % 3, kt + 2);   // distance-2 prefetch
    short8 af[4], bf[4];
    #pragma unroll
    for (int m = 0; m < 4; ++m) af[m] = *(const short8*)(sAc + buf * 8192 + rofA[m]);
    #pragma unroll
    for (int n = 0; n < 4; ++n) bf[n] = *(const short8*)(sBc + buf * 8192 + rofB[n]);
    #pragma unroll
    for (int m = 0; m < 4; ++m)
      #pragma unroll
      for (int n = 0; n < 4; ++n)
        acc[m][n] = __builtin_amdgcn_mfma_f32_16x16x32_bf16(af[m], bf[n], acc[m][n], 0, 0, 0);
    // wait next tile (leave distance-2 loads in flight); drain my ds_reads; sync
    if (kt + 2 < 8) {
      asm volatile("s_waitcnt vmcnt(4) lgkmcnt(0)\ns_barrier" ::: "memory");
    } else if (kt < 7) {
      asm volatile("s_waitcnt vmcnt(0) lgkmcnt(0)\ns_barrier" ::: "memory");
    }
    __builtin_amdgcn_sched_barrier(0);
  }

  // C write (bf16): col=lane&15 within frag, row=(lane>>4)*4+j
  #pragma unroll
  for (int m = 0; m < 4; ++m) {
    #pragma unroll
    for (int n = 0; n < 4; ++n) {
      int col = col0 + wc * 64 + n * 16 + fr;
      #pragma unroll
      for (int j = 0; j < 4; ++j) {
        int row = row0 + wr * 64 + m * 16 + fg * 4 + j;
        if (row < Mrows) C16[(size_t)row * 256 + col] = f2bf_rn(acc[m][n][j]);
      }
    }
  }

  // fused logits: this wave's 64 cols = one head
  int head = bc * 2 + wc;
  float asv[4], adv[4];
  #pragma unroll
  for (int n = 0; n < 4; ++n) {
    asv[n] = as_[head * 64 + n * 16 + fr];
    adv[n] = ad_[head * 64 + n * 16 + fr];
  }
  #pragma unroll
  for (int m = 0; m < 4; ++m) {
    #pragma unroll
    for (int j = 0; j < 4; ++j) {
      float ps = 0.f, pd = 0.f;
      #pragma unroll
      for (int n = 0; n < 4; ++n) {
        ps += acc[m][n][j] * asv[n];
        pd += acc[m][n][j] * adv[n];
      }
      #pragma unroll
      for (int off = 1; off < 16; off <<= 1) {
        ps += __shfl_xor(ps, off, 64);
        pd += __shfl_xor(pd, off, 64);
      }
      int grow = row0 + wr * 64 + m * 16 + fg * 4 + j;
      if (fr == 0 && grow < Mrows) {
        als[grow * 4 + head] = ps;
        ald[grow * 4 + head] = pd;
      }
    }
  }
}

// ---------------- edge softmax: single pass, max-free ----------------

__global__ void edge_softmax_kernel(const float* __restrict__ als, const float* __restrict__ ald,
                                    const int* __restrict__ rowptr, const int* __restrict__ col,
                                    float* __restrict__ w, float* __restrict__ invS, int Nn) {
  int node = blockIdx.x * 256 + threadIdx.x;
  if (node >= Nn) return;
  int rs = rowptr[node], re = rowptr[node + 1];
  float4 ad = *(const float4*)&ald[node * 4];
  float S0 = 0.f, S1 = 0.f, S2 = 0.f, S3 = 0.f;
  for (int i = rs; i < re; ++i) {
    int s = col[i];
    float4 a = *(const float4*)&als[(size_t)s * 4];
    float e0 = a.x + ad.x; e0 = e0 > 0.f ? e0 : NEG_SLOPE * e0;
    float e1 = a.y + ad.y; e1 = e1 > 0.f ? e1 : NEG_SLOPE * e1;
    float e2 = a.z + ad.z; e2 = e2 > 0.f ? e2 : NEG_SLOPE * e2;
    float e3 = a.w + ad.w; e3 = e3 > 0.f ? e3 : NEG_SLOPE * e3;
    float p0 = __expf(e0), p1 = __expf(e1), p2 = __expf(e2), p3 = __expf(e3);
    *(float4*)&w[(size_t)i * 4] = make_float4(p0, p1, p2, p3);
    S0 += p0; S1 += p1; S2 += p2; S3 += p3;
  }
  *(float4*)&invS[node * 4] = make_float4(1.f / (S0 + 1e-16f), 1.f / (S1 + 1e-16f),
                                          1.f / (S2 + 1e-16f), 1.f / (S3 + 1e-16f));
}

// ---------------- GAT gather v4: one dwordx2 per lane per edge ----------------

__global__ __launch_bounds__(256) void gat_gather_kernel(const u16* __restrict__ h16,
    const float* __restrict__ w, const float* __restrict__ invS,
    const int* __restrict__ rowptr, const int* __restrict__ col,
    const float* __restrict__ bias, u16* __restrict__ out16, int Nn) {
  int node = __builtin_amdgcn_readfirstlane(blockIdx.x * 4 + (threadIdx.x >> 6));
  int lane = threadIdx.x & 63;
  if (node >= Nn) return;
  int rs = rowptr[node], re = rowptr[node + 1];
  int head = lane >> 4;                       // 16 lanes per head
  float a0 = 0.f, a1 = 0.f, a2 = 0.f, a3 = 0.f;
  const uint2* h64 = (const uint2*)h16;       // 8B units; row = 64 units
  #pragma unroll 2
  for (int i = rs; i < re; ++i) {
    int s = col[i];
    float wq = w[(size_t)i * 4 + head];
    uint2 p = h64[(size_t)s * 64 + lane];     // ch 4l..4l+3
    a0 += wq * __uint_as_float(p.x << 16);
    a1 += wq * __uint_as_float(p.x & 0xffff0000u);
    a2 += wq * __uint_as_float(p.y << 16);
    a3 += wq * __uint_as_float(p.y & 0xffff0000u);
  }
  float iS = invS[node * 4 + head];
  float4 bv = *(const float4*)&bias[4 * lane];
  float o0 = a0 * iS + bv.x;
  float o1 = a1 * iS + bv.y;
  float o2 = a2 * iS + bv.z;
  float o3 = a3 * iS + bv.w;
  o0 = o0 > 0.f ? o0 : (__expf(o0) - 1.0f);   // ELU (alpha=1)
  o1 = o1 > 0.f ? o1 : (__expf(o1) - 1.0f);
  o2 = o2 > 0.f ? o2 : (__expf(o2) - 1.0f);
  o3 = o3 > 0.f ? o3 : (__expf(o3) - 1.0f);
  uint2 ov;
  ov.x = (u32)f2bf_rn(o0) | ((u32)f2bf_rn(o1) << 16);
  ov.y = (u32)f2bf_rn(o2) | ((u32)f2bf_rn(o3) << 16);
  ((uint2*)out16)[(size_t)node * 64 + lane] = ov;
}

// ---------------- pooling + MLP ----------------

__global__ void bounds_kernel(const int* __restrict__ batch, int Nn, int* __restrict__ bounds) {
  int g = threadIdx.x;
  if (g > GG) return;
  int lo = 0, hi = Nn;
  while (lo < hi) { int mid = (lo + hi) >> 1; if (batch[mid] < g) lo = mid + 1; else hi = mid; }
  bounds[g] = lo;   // lower_bound of g; bounds[64] = N
}

// one wave per (graph, split); uint4 loads (1KB/wave-instr); lane = (rowpar, chunk)
__global__ __launch_bounds__(64) void pool_kernel(const u16* __restrict__ X,
    const int* __restrict__ bounds, float* __restrict__ pooled) {
  int g = blockIdx.x, split = blockIdx.y;
  int lane = threadIdx.x;                     // 64
  int s = bounds[g], e = bounds[g + 1];
  int cnt = e - s;
  if (cnt <= 0) return;
  int chunk = (cnt + gridDim.y - 1) / gridDim.y;
  int s2 = s + split * chunk, e2 = min(e, s2 + chunk);
  if (s2 >= e2) return;
  int r = lane >> 5, c = lane & 31;           // row parity, 16B chunk
  float acc[8] = {};
  for (int n = s2 + r; n < e2; n += 2) {
    uint4 v = *(const uint4*)&X[(size_t)n * HC + c * 8];
    acc[0] += __uint_as_float(v.x << 16);
    acc[1] += __uint_as_float(v.x & 0xffff0000u);
    acc[2] += __uint_as_float(v.y << 16);
    acc[3] += __uint_as_float(v.y & 0xffff0000u);
    acc[4] += __uint_as_float(v.z << 16);
    acc[5] += __uint_as_float(v.z & 0xffff0000u);
    acc[6] += __uint_as_float(v.w << 16);
    acc[7] += __uint_as_float(v.w & 0xffff0000u);
  }
  #pragma unroll
  for (int j = 0; j < 8; ++j) acc[j] += __shfl_xor(acc[j], 32, 64);
  if (r == 0) {
    #pragma unroll
    for (int j = 0; j < 8; ++j) atomicAdd(&pooled[g * HC + c * 8 + j], acc[j]);
  }
}

__global__ __launch_bounds__(512) void mlp_kernel(const float* __restrict__ pooled,
    const int* __restrict__ bounds, const float* __restrict__ Wp1, const float* __restrict__ bp1,
    const float* __restrict__ Wp2, const float* __restrict__ bp2, float* __restrict__ out) {
  __shared__ float p[256];
  __shared__ float z1[512];
  int g = blockIdx.x, t = threadIdx.x;
  if (t < 256) {
    int cnt = bounds[g + 1] - bounds[g];
    float inv = 1.0f / (float)(cnt > 1 ? cnt : 1);
    p[t] = pooled[g * 256 + t] * inv;
  }
  __syncthreads();
  float a1 = bp1[t];
  for (int k = 0; k < 256; ++k) a1 += p[k] * Wp1[k * 512 + t];
  z1[t] = fmaxf(a1, 0.f);
  __syncthreads();
  if (t < 256) {
    float a2 = bp2[t];
    for (int k = 0; k < 512; ++k) a2 += z1[k] * Wp2[k * 256 + t];
    out[g * 256 + t] = a2;
  }
}

// ---------------- launch ----------------

static inline size_t align_up(size_t x, size_t a) { return (x + a - 1) & ~(a - 1); }

extern "C" void kernel_launch(void* const* d_in, const int* in_sizes, int n_in,
                              void* d_out, int out_size, void* d_ws, size_t ws_size,
                              hipStream_t stream) {
  const float* x    = (const float*)d_in[0];
  const int*   ei   = (const int*)d_in[1];
  const int*   batch= (const int*)d_in[2];
  const float* W1   = (const float*)d_in[3];
  const float* a1s  = (const float*)d_in[4];
  const float* a1d  = (const float*)d_in[5];
  const float* b1   = (const float*)d_in[6];
  const float* W2   = (const float*)d_in[7];
  const float* a2s  = (const float*)d_in[8];
  const float* a2d  = (const float*)d_in[9];
  const float* b2   = (const float*)d_in[10];
  const float* W3   = (const float*)d_in[11];
  const float* a3s  = (const float*)d_in[12];
  const float* a3d  = (const float*)d_in[13];
  const float* b3   = (const float*)d_in[14];
  const float* Wp1  = (const float*)d_in[15];
  const float* bp1  = (const float*)d_in[16];
  const float* Wp2  = (const float*)d_in[17];
  const float* bp2  = (const float*)d_in[18];

  const int N = in_sizes[0] / 2;       // 100000
  const int E = in_sizes[1] / 2;       // 400000
  const int Et = E + N;                // with self loops

  char* base = (char*)d_ws;
  size_t off = 0;
  auto alloc = [&](size_t bytes) { size_t o = off; off = align_up(off + bytes, 256); return o; };
  u16*   h16    = (u16*)  (base + alloc((size_t)N * HC * 2));   // message-path h (bf16)
  u16*   xhi    = (u16*)  (base + alloc((size_t)N * HC * 2));   // gather out (bf16)
  float* als    = (float*)(base + alloc((size_t)N * 4 * 4));
  float* ald    = (float*)(base + alloc((size_t)N * 4 * 4));
  float* invS   = (float*)(base + alloc((size_t)N * 4 * 4));
  float* xbar   = (float*)(base + alloc((size_t)N * 8 * 4));    // layer-1 x-space gather
  float* vabuf  = (float*)(base + alloc(16 * 4));
  int*   rowptr = (int*)  (base + alloc((size_t)(N + 1) * 4));
  int*   col    = (int*)  (base + alloc((size_t)Et * 4));
  float* w      = (float*)(base + alloc((size_t)Et * 4 * 4));   // per-edge softmax numerators
  int*   deg    = (int*)  (base + alloc((size_t)N * 4));
  int*   cursor = (int*)  (base + alloc((size_t)N * 4));
  int*   bsum   = (int*)  (base + alloc(512 * 4));
  int*   bounds = (int*)  (base + alloc((GG + 1) * 4));
  float* pooled = (float*)(base + alloc((size_t)GG * HC * 4));
  (void)ws_size; (void)n_in; (void)out_size;

  // W2t/W3t (bf16, 128KB each) parked in deg/cursor space (dead after CSR build)
  u16* W2t = (u16*)deg;
  u16* W3t = (u16*)cursor;

  hipMemsetAsync(deg, 0, (size_t)N * 4, stream);
  hipMemsetAsync(cursor, 0, (size_t)N * 4, stream);
  hipMemsetAsync(pooled, 0, (size_t)GG * HC * 4, stream);

  // CSR by destination (same edge set for all layers)
  int ebk = (Et + 255) / 256;
  count_deg_kernel<<<ebk, 256, 0, stream>>>(ei, E, N, deg);
  int NT = (N + 255) / 256;
  scan_partial_kernel<<<NT, 256, 0, stream>>>(deg, N, rowptr, bsum);
  scan_bsum_kernel<<<1, 512, 0, stream>>>(bsum, NT);
  scan_add_kernel<<<NT, 256, 0, stream>>>(rowptr, bsum, N, Et);
  fill_csr_kernel<<<ebk, 256, 0, stream>>>(ei, E, N, rowptr, cursor, col);

  // weight conversion (deg/cursor now dead)
  convert_w_kernel<<<256, 256, 0, stream>>>(W2, W2t);
  convert_w_kernel<<<256, 256, 0, stream>>>(W3, W3t);

  dim3 gemm_grid(HC / GBN, (N + GBM - 1) / GBM);
  int nodeblk = (N + 3) / 4;

  // layer 1 — rank-2 factorization: everything in x-space, then one expand
  prep_va_kernel<<<1, 256, 0, stream>>>(W1, a1s, a1d, vabuf);
  logits1_kernel<<<NT, 256, 0, stream>>>(x, vabuf, als, ald, N);
  sm_gather1_kernel<<<NT, 256, 0, stream>>>(x, als, ald, rowptr, col, xbar, N);
  expand1_kernel<<<nodeblk, 256, 0, stream>>>(xbar, W1, b1, xhi, N);
  // layer 2
  gemm_mfma_kernel<<<gemm_grid, 256, 0, stream>>>(xhi, W2t, a2s, a2d, h16, als, ald, N);
  edge_softmax_kernel<<<NT, 256, 0, stream>>>(als, ald, rowptr, col, w, invS, N);
  gat_gather_kernel<<<nodeblk, 256, 0, stream>>>(h16, w, invS, rowptr, col, b2, xhi, N);
  // layer 3
  gemm_mfma_kernel<<<gemm_grid, 256, 0, stream>>>(xhi, W3t, a3s, a3d, h16, als, ald, N);
  edge_softmax_kernel<<<NT, 256, 0, stream>>>(als, ald, rowptr, col, w, invS, N);
  gat_gather_kernel<<<nodeblk, 256, 0, stream>>>(h16, w, invS, rowptr, col, b3, xhi, N);

  // pool + MLP
  bounds_kernel<<<1, 128, 0, stream>>>(batch, N, bounds);
  pool_kernel<<<dim3(GG, 32), 64, 0, stream>>>(xhi, bounds, pooled);
  mlp_kernel<<<GG, 512, 0, stream>>>(pooled, bounds, Wp1, bp1, Wp2, bp2, (float*)d_out);
}

// Round 14
// 380.814 us; speedup vs baseline: 1.0148x; 1.0148x over previous
//
#include <hip/hip_runtime.h>
#include <math.h>

#define HC 256      // H*C
#define NHEAD 4
#define NEG_SLOPE 0.2f
#define GG 64       // graphs

typedef unsigned short u16;
typedef unsigned int u32;
typedef __attribute__((ext_vector_type(8))) short short8;
typedef __attribute__((ext_vector_type(4))) float f32x4;

static __device__ inline u16 f2bf_rn(float f) {
  u32 x = __float_as_uint(f);
  u32 r = (x + 0x7fffu + ((x >> 16) & 1u)) >> 16;
  return (u16)r;
}
static __device__ inline float bf2f(u16 u) { return __uint_as_float(((u32)u) << 16); }
static __device__ inline int swz(int b) { return b ^ (((b >> 8) & 7) << 4); }

// ---------------- CSR build ----------------

__global__ void count_deg_kernel(const int* __restrict__ ei, int E, int Nn, int* __restrict__ deg) {
  int idx = blockIdx.x * 256 + threadIdx.x;
  int Et = E + Nn;
  if (idx >= Et) return;
  int d = (idx < E) ? ei[E + idx] : (idx - E);   // row1 of edge_index = dst; self loops appended
  atomicAdd(&deg[d], 1);
}

__global__ void scan_partial_kernel(const int* __restrict__ deg, int Nn,
                                    int* __restrict__ rowptr, int* __restrict__ bsum) {
  __shared__ int s[256];
  int t = threadIdx.x, i = blockIdx.x * 256 + t;
  int v = (i < Nn) ? deg[i] : 0;
  s[t] = v; __syncthreads();
  for (int off = 1; off < 256; off <<= 1) {
    int x = (t >= off) ? s[t - off] : 0; __syncthreads();
    s[t] += x; __syncthreads();
  }
  if (i < Nn) rowptr[i] = s[t] - v;          // exclusive within block
  if (t == 255) bsum[blockIdx.x] = s[t];     // block total
}

__global__ void scan_bsum_kernel(int* __restrict__ bsum, int nb) {
  __shared__ int s[512];
  int t = threadIdx.x;
  int v = (t < nb) ? bsum[t] : 0;
  s[t] = v; __syncthreads();
  for (int off = 1; off < 512; off <<= 1) {
    int x = (t >= off) ? s[t - off] : 0; __syncthreads();
    s[t] += x; __syncthreads();
  }
  if (t < nb) bsum[t] = s[t] - v;            // exclusive block offsets
}

__global__ void scan_add_kernel(int* __restrict__ rowptr, const int* __restrict__ bsum,
                                int Nn, int Etot) {
  int i = blockIdx.x * 256 + threadIdx.x;
  if (i < Nn) rowptr[i] += bsum[blockIdx.x];
  if (i == 0) rowptr[Nn] = Etot;
}

__global__ void fill_csr_kernel(const int* __restrict__ ei, int E, int Nn,
                                const int* __restrict__ rowptr, int* __restrict__ cursor,
                                int* __restrict__ col) {
  int idx = blockIdx.x * 256 + threadIdx.x;
  int Et = E + Nn;
  if (idx >= Et) return;
  int s, d;
  if (idx < E) { s = ei[idx]; d = ei[E + idx]; } else { s = d = idx - E; }
  int pos = atomicAdd(&cursor[d], 1);
  col[rowptr[d] + pos] = s;
}

// ---------------- W transpose + bf16: Wt[n][k] ----------------

__global__ void convert_w_kernel(const float* __restrict__ W, u16* __restrict__ hi) {
  int idx = blockIdx.x * 256 + threadIdx.x;    // 65536 threads
  if (idx >= 256 * 256) return;
  int k = idx >> 8, n = idx & 255;             // coalesced read of W[k][n]
  hi[n * 256 + k] = f2bf_rn(W[idx]);
}

// ---------------- layer 1 (rank-2 factorization) ----------------
// va[k*4+q] = sum_{c in head q} W1[k][c]*a1s[c]; va[8+..] same with a1d.

__global__ void prep_va_kernel(const float* __restrict__ W1, const float* __restrict__ a1s,
                               const float* __restrict__ a1d, float* __restrict__ va) {
  int t = threadIdx.x;                       // 256 = 4 waves, wave q = head q
  int q = t >> 6, lane = t & 63;
  int c = t;
  float asv = a1s[c], adv = a1d[c];
  float w0 = W1[c], w1 = W1[256 + c];
  float s0 = w0 * asv, s1 = w1 * asv, d0 = w0 * adv, d1 = w1 * adv;
  #pragma unroll
  for (int off = 32; off >= 1; off >>= 1) {
    s0 += __shfl_xor(s0, off, 64); s1 += __shfl_xor(s1, off, 64);
    d0 += __shfl_xor(d0, off, 64); d1 += __shfl_xor(d1, off, 64);
  }
  if (lane == 0) {
    va[q] = s0; va[4 + q] = s1;
    va[8 + q] = d0; va[12 + q] = d1;
  }
}

// als/ald directly from x: als[q] = x0*va[q] + x1*va[4+q]
__global__ void logits1_kernel(const float* __restrict__ x, const float* __restrict__ va,
                               float* __restrict__ als, float* __restrict__ ald, int Nn) {
  int node = blockIdx.x * 256 + threadIdx.x;
  if (node >= Nn) return;
  float2 xv = *(const float2*)&x[(size_t)node * 2];
  float4 vs0 = *(const float4*)&va[0], vs1 = *(const float4*)&va[4];
  float4 vd0 = *(const float4*)&va[8], vd1 = *(const float4*)&va[12];
  float4 s, d;
  s.x = xv.x * vs0.x + xv.y * vs1.x; s.y = xv.x * vs0.y + xv.y * vs1.y;
  s.z = xv.x * vs0.z + xv.y * vs1.z; s.w = xv.x * vs0.w + xv.y * vs1.w;
  d.x = xv.x * vd0.x + xv.y * vd1.x; d.y = xv.x * vd0.y + xv.y * vd1.y;
  d.z = xv.x * vd0.z + xv.y * vd1.z; d.w = xv.x * vd0.w + xv.y * vd1.w;
  *(float4*)&als[node * 4] = s;
  *(float4*)&ald[node * 4] = d;
}

// fused max-free softmax + x-space gather: xbar[node][q*2+k] = (sum_e p^q_e x[s_e][k])/S_q
__global__ void sm_gather1_kernel(const float* __restrict__ x,
    const float* __restrict__ als, const float* __restrict__ ald,
    const int* __restrict__ rowptr, const int* __restrict__ col,
    float* __restrict__ xbar, int Nn) {
  int node = blockIdx.x * 256 + threadIdx.x;
  if (node >= Nn) return;
  int rs = rowptr[node], re = rowptr[node + 1];
  float4 ad = *(const float4*)&ald[node * 4];
  float S0 = 0.f, S1 = 0.f, S2 = 0.f, S3 = 0.f;
  float a0 = 0.f, a1 = 0.f, a2 = 0.f, a3 = 0.f, a4 = 0.f, a5 = 0.f, a6 = 0.f, a7 = 0.f;
  for (int i = rs; i < re; ++i) {
    int s = col[i];
    float4 a = *(const float4*)&als[(size_t)s * 4];
    float2 xs = *(const float2*)&x[(size_t)s * 2];
    float e0 = a.x + ad.x; e0 = e0 > 0.f ? e0 : NEG_SLOPE * e0;
    float e1 = a.y + ad.y; e1 = e1 > 0.f ? e1 : NEG_SLOPE * e1;
    float e2 = a.z + ad.z; e2 = e2 > 0.f ? e2 : NEG_SLOPE * e2;
    float e3 = a.w + ad.w; e3 = e3 > 0.f ? e3 : NEG_SLOPE * e3;
    float p0 = __expf(e0), p1 = __expf(e1), p2 = __expf(e2), p3 = __expf(e3);
    S0 += p0; S1 += p1; S2 += p2; S3 += p3;
    a0 += p0 * xs.x; a1 += p0 * xs.y;
    a2 += p1 * xs.x; a3 += p1 * xs.y;
    a4 += p2 * xs.x; a5 += p2 * xs.y;
    a6 += p3 * xs.x; a7 += p3 * xs.y;
  }
  float i0 = 1.f / (S0 + 1e-16f), i1 = 1.f / (S1 + 1e-16f);
  float i2 = 1.f / (S2 + 1e-16f), i3 = 1.f / (S3 + 1e-16f);
  *(float4*)&xbar[(size_t)node * 8]     = make_float4(a0 * i0, a1 * i0, a2 * i1, a3 * i1);
  *(float4*)&xbar[(size_t)node * 8 + 4] = make_float4(a4 * i2, a5 * i2, a6 * i3, a7 * i3);
}

// expand: out1[node][c] = xbar_q . W1[:,c] + b1[c], ELU, bf16-packed
__global__ __launch_bounds__(256) void expand1_kernel(const float* __restrict__ xbar,
    const float* __restrict__ W1, const float* __restrict__ b1,
    u16* __restrict__ out16, int Nn) {
  int node = blockIdx.x * 4 + (threadIdx.x >> 6);
  int lane = threadIdx.x & 63;
  if (node >= Nn) return;
  int hA = lane >> 5;                        // head of ch pair A (0/1); pair B head = 2+hA
  float4 xb0 = *(const float4*)&xbar[(size_t)node * 8];      // heads 0,1
  float4 xb1 = *(const float4*)&xbar[(size_t)node * 8 + 4];  // heads 2,3
  float xA0 = hA ? xb0.z : xb0.x, xA1 = hA ? xb0.w : xb0.y;
  float xB0 = hA ? xb1.z : xb1.x, xB1 = hA ? xb1.w : xb1.y;
  int cA = 2 * lane, cB = 128 + 2 * lane;
  float2 wA0 = *(const float2*)&W1[cA], wA1 = *(const float2*)&W1[256 + cA];
  float2 wB0 = *(const float2*)&W1[cB], wB1 = *(const float2*)&W1[256 + cB];
  float2 bA = *(const float2*)&b1[cA],  bB = *(const float2*)&b1[cB];
  float o0 = xA0 * wA0.x + xA1 * wA1.x + bA.x;
  float o1 = xA0 * wA0.y + xA1 * wA1.y + bA.y;
  float o2 = xB0 * wB0.x + xB1 * wB1.x + bB.x;
  float o3 = xB0 * wB0.y + xB1 * wB1.y + bB.y;
  o0 = o0 > 0.f ? o0 : (__expf(o0) - 1.0f);
  o1 = o1 > 0.f ? o1 : (__expf(o1) - 1.0f);
  o2 = o2 > 0.f ? o2 : (__expf(o2) - 1.0f);
  o3 = o3 > 0.f ? o3 : (__expf(o3) - 1.0f);
  u32* o32 = (u32*)out16;
  o32[(size_t)node * 128 + lane]      = (u32)f2bf_rn(o0) | ((u32)f2bf_rn(o1) << 16);
  o32[(size_t)node * 128 + 64 + lane] = (u32)f2bf_rn(o2) | ((u32)f2bf_rn(o3) << 16);
}

// ---------------- pipelined LDS MFMA GEMM (2-phase) + LDS-transposed C write ----------------
// K-loop = R8 structure (best measured). Epilogue: acc -> LDS (bf16, [64][128]
// per column-block) -> per-wave 4 x 256B contiguous uint4 row-segment stores
// (vs 32B scalar segments). cl covers THIS block's 128 cols only (R13 bug fix).

#define GBM 128
#define GBN 128

__global__ __launch_bounds__(256) void gemm_mfma_kernel(
    const u16* __restrict__ A, const u16* __restrict__ Bt,
    const float* __restrict__ as_, const float* __restrict__ ad_,
    u16* __restrict__ C16, float* __restrict__ als, float* __restrict__ ald, int Mrows) {
  __shared__ __align__(16) u16 smem[16384];   // 32KB: staging bufs; epilogue reuses 16KB
  char* sAc = (char*)smem;                    // A bufs at bytes 0, 8192
  char* sBc = (char*)smem + 16384;            // B bufs at bytes 16384, 16384+8192
  int bc = blockIdx.x, br = blockIdx.y;
  int tid = threadIdx.x;
  int wid = tid >> 6, lane = tid & 63;
  int wr = wid >> 1, wc = wid & 1;             // 2x2 waves; each 64x64 output
  int row0 = br * GBM, col0 = bc * GBN;
  int fr = lane & 15, fg = lane >> 4;

  const u16* agp[2];
  const u16* bgp[2];
  int wof[2];
  #pragma unroll
  for (int j = 0; j < 2; ++j) {
    int rr = wid * 32 + j * 16 + (lane >> 2);
    int kc = lane & 3;
    int gr = row0 + rr; if (gr >= Mrows) gr = Mrows - 1;
    agp[j] = A + (size_t)gr * 256 + kc * 8;
    bgp[j] = Bt + (size_t)(col0 + rr) * 256 + kc * 8;
    wof[j] = swz(rr * 64 + kc * 16);
  }
  int rofA[4], rofB[4];
  #pragma unroll
  for (int m = 0; m < 4; ++m) rofA[m] = swz((wr * 64 + m * 16 + fr) * 64 + fg * 16);
  #pragma unroll
  for (int n = 0; n < 4; ++n) rofB[n] = swz((wc * 64 + n * 16 + fr) * 64 + fg * 16);

  f32x4 acc[4][4];
  #pragma unroll
  for (int m = 0; m < 4; ++m)
    #pragma unroll
    for (int n = 0; n < 4; ++n) acc[m][n] = (f32x4){0.f, 0.f, 0.f, 0.f};

  uint4 va[2], vb[2];
  #pragma unroll
  for (int j = 0; j < 2; ++j) { va[j] = *(const uint4*)agp[j]; vb[j] = *(const uint4*)bgp[j]; }
  #pragma unroll
  for (int j = 0; j < 2; ++j) {
    *(uint4*)(sAc + wof[j]) = va[j];
    *(uint4*)(sBc + wof[j]) = vb[j];
  }
  __syncthreads();

  #pragma unroll
  for (int kt = 0; kt < 8; ++kt) {             // K = 8 x 32
    int buf = kt & 1;
    if (kt < 7) {                              // T14: issue next-tile loads early
      #pragma unroll
      for (int j = 0; j < 2; ++j) {
        va[j] = *(const uint4*)(agp[j] + (kt + 1) * 32);
        vb[j] = *(const uint4*)(bgp[j] + (kt + 1) * 32);
      }
    }
    short8 af[4], bf[4];
    #pragma unroll
    for (int m = 0; m < 4; ++m) af[m] = *(const short8*)(sAc + buf * 8192 + rofA[m]);
    #pragma unroll
    for (int n = 0; n < 4; ++n) bf[n] = *(const short8*)(sBc + buf * 8192 + rofB[n]);
    #pragma unroll
    for (int m = 0; m < 4; ++m)
      #pragma unroll
      for (int n = 0; n < 4; ++n)
        acc[m][n] = __builtin_amdgcn_mfma_f32_16x16x32_bf16(af[m], bf[n], acc[m][n], 0, 0, 0);
    if (kt < 7) {                              // write next buffer, one barrier
      int nb = buf ^ 1;
      #pragma unroll
      for (int j = 0; j < 2; ++j) {
        *(uint4*)(sAc + nb * 8192 + wof[j]) = va[j];
        *(uint4*)(sBc + nb * 8192 + wof[j]) = vb[j];
      }
      __syncthreads();
    }
  }

  // ---- C write via LDS transpose: 2 passes of 64 rows x 128 cols (this block) ----
  u16* cl = smem;                              // [64][128] bf16 = 16KB (reuses staging)
  #pragma unroll
  for (int p = 0; p < 2; ++p) {
    __syncthreads();                           // prior reads of smem/cl complete
    if (wr == p) {
      #pragma unroll
      for (int m = 0; m < 4; ++m) {
        #pragma unroll
        for (int n = 0; n < 4; ++n) {
          int c = wc * 64 + n * 16 + fr;
          #pragma unroll
          for (int j = 0; j < 4; ++j) {
            int lr = m * 16 + fg * 4 + j;
            cl[lr * 128 + c] = f2bf_rn(acc[m][n][j]);
          }
        }
      }
    }
    __syncthreads();
    #pragma unroll
    for (int i = 0; i < 4; ++i) {
      int u = i * 256 + tid;                   // uint4 index within 64x128 tile
      int lr = u >> 4, ch = u & 15;
      int grow = row0 + p * 64 + lr;
      if (grow < Mrows) {
        uint4 v = *(const uint4*)&cl[lr * 128 + ch * 8];
        *(uint4*)&C16[(size_t)grow * 256 + col0 + ch * 8] = v;
      }
    }
  }

  // fused logits: this wave's 64 cols = one head
  int head = bc * 2 + wc;
  float asv[4], adv[4];
  #pragma unroll
  for (int n = 0; n < 4; ++n) {
    asv[n] = as_[head * 64 + n * 16 + fr];
    adv[n] = ad_[head * 64 + n * 16 + fr];
  }
  #pragma unroll
  for (int m = 0; m < 4; ++m) {
    #pragma unroll
    for (int j = 0; j < 4; ++j) {
      float ps = 0.f, pd = 0.f;
      #pragma unroll
      for (int n = 0; n < 4; ++n) {
        ps += acc[m][n][j] * asv[n];
        pd += acc[m][n][j] * adv[n];
      }
      #pragma unroll
      for (int off = 1; off < 16; off <<= 1) {
        ps += __shfl_xor(ps, off, 64);
        pd += __shfl_xor(pd, off, 64);
      }
      int grow = row0 + wr * 64 + m * 16 + fg * 4 + j;
      if (fr == 0 && grow < Mrows) {
        als[grow * 4 + head] = ps;
        ald[grow * 4 + head] = pd;
      }
    }
  }
}

// ---------------- edge softmax: single pass, max-free ----------------

__global__ void edge_softmax_kernel(const float* __restrict__ als, const float* __restrict__ ald,
                                    const int* __restrict__ rowptr, const int* __restrict__ col,
                                    float* __restrict__ w, float* __restrict__ invS, int Nn) {
  int node = blockIdx.x * 256 + threadIdx.x;
  if (node >= Nn) return;
  int rs = rowptr[node], re = rowptr[node + 1];
  float4 ad = *(const float4*)&ald[node * 4];
  float S0 = 0.f, S1 = 0.f, S2 = 0.f, S3 = 0.f;
  for (int i = rs; i < re; ++i) {
    int s = col[i];
    float4 a = *(const float4*)&als[(size_t)s * 4];
    float e0 = a.x + ad.x; e0 = e0 > 0.f ? e0 : NEG_SLOPE * e0;
    float e1 = a.y + ad.y; e1 = e1 > 0.f ? e1 : NEG_SLOPE * e1;
    float e2 = a.z + ad.z; e2 = e2 > 0.f ? e2 : NEG_SLOPE * e2;
    float e3 = a.w + ad.w; e3 = e3 > 0.f ? e3 : NEG_SLOPE * e3;
    float p0 = __expf(e0), p1 = __expf(e1), p2 = __expf(e2), p3 = __expf(e3);
    *(float4*)&w[(size_t)i * 4] = make_float4(p0, p1, p2, p3);
    S0 += p0; S1 += p1; S2 += p2; S3 += p3;
  }
  *(float4*)&invS[node * 4] = make_float4(1.f / (S0 + 1e-16f), 1.f / (S1 + 1e-16f),
                                          1.f / (S2 + 1e-16f), 1.f / (S3 + 1e-16f));
}

// ---------------- GAT gather v4: one dwordx2 per lane per edge ----------------

__global__ __launch_bounds__(256) void gat_gather_kernel(const u16* __restrict__ h16,
    const float* __restrict__ w, const float* __restrict__ invS,
    const int* __restrict__ rowptr, const int* __restrict__ col,
    const float* __restrict__ bias, u16* __restrict__ out16, int Nn) {
  int node = __builtin_amdgcn_readfirstlane(blockIdx.x * 4 + (threadIdx.x >> 6));
  int lane = threadIdx.x & 63;
  if (node >= Nn) return;
  int rs = rowptr[node], re = rowptr[node + 1];
  int head = lane >> 4;                       // 16 lanes per head
  float a0 = 0.f, a1 = 0.f, a2 = 0.f, a3 = 0.f;
  const uint2* h64 = (const uint2*)h16;       // 8B units; row = 64 units
  #pragma unroll 2
  for (int i = rs; i < re; ++i) {
    int s = col[i];
    float wq = w[(size_t)i * 4 + head];
    uint2 p = h64[(size_t)s * 64 + lane];     // ch 4l..4l+3
    a0 += wq * __uint_as_float(p.x << 16);
    a1 += wq * __uint_as_float(p.x & 0xffff0000u);
    a2 += wq * __uint_as_float(p.y << 16);
    a3 += wq * __uint_as_float(p.y & 0xffff0000u);
  }
  float iS = invS[node * 4 + head];
  float4 bv = *(const float4*)&bias[4 * lane];
  float o0 = a0 * iS + bv.x;
  float o1 = a1 * iS + bv.y;
  float o2 = a2 * iS + bv.z;
  float o3 = a3 * iS + bv.w;
  o0 = o0 > 0.f ? o0 : (__expf(o0) - 1.0f);   // ELU (alpha=1)
  o1 = o1 > 0.f ? o1 : (__expf(o1) - 1.0f);
  o2 = o2 > 0.f ? o2 : (__expf(o2) - 1.0f);
  o3 = o3 > 0.f ? o3 : (__expf(o3) - 1.0f);
  uint2 ov;
  ov.x = (u32)f2bf_rn(o0) | ((u32)f2bf_rn(o1) << 16);
  ov.y = (u32)f2bf_rn(o2) | ((u32)f2bf_rn(o3) << 16);
  ((uint2*)out16)[(size_t)node * 64 + lane] = ov;
}

// ---------------- pooling + MLP ----------------

__global__ void bounds_kernel(const int* __restrict__ batch, int Nn, int* __restrict__ bounds) {
  int g = threadIdx.x;
  if (g > GG) return;
  int lo = 0, hi = Nn;
  while (lo < hi) { int mid = (lo + hi) >> 1; if (batch[mid] < g) lo = mid + 1; else hi = mid; }
  bounds[g] = lo;   // lower_bound of g; bounds[64] = N
}

// one wave per (graph, split); uint4 loads (1KB/wave-instr); lane = (rowpar, chunk)
__global__ __launch_bounds__(64) void pool_kernel(const u16* __restrict__ X,
    const int* __restrict__ bounds, float* __restrict__ pooled) {
  int g = blockIdx.x, split = blockIdx.y;
  int lane = threadIdx.x;                     // 64
  int s = bounds[g], e = bounds[g + 1];
  int cnt = e - s;
  if (cnt <= 0) return;
  int chunk = (cnt + gridDim.y - 1) / gridDim.y;
  int s2 = s + split * chunk, e2 = min(e, s2 + chunk);
  if (s2 >= e2) return;
  int r = lane >> 5, c = lane & 31;           // row parity, 16B chunk
  float acc[8] = {};
  for (int n = s2 + r; n < e2; n += 2) {
    uint4 v = *(const uint4*)&X[(size_t)n * HC + c * 8];
    acc[0] += __uint_as_float(v.x << 16);
    acc[1] += __uint_as_float(v.x & 0xffff0000u);
    acc[2] += __uint_as_float(v.y << 16);
    acc[3] += __uint_as_float(v.y & 0xffff0000u);
    acc[4] += __uint_as_float(v.z << 16);
    acc[5] += __uint_as_float(v.z & 0xffff0000u);
    acc[6] += __uint_as_float(v.w << 16);
    acc[7] += __uint_as_float(v.w & 0xffff0000u);
  }
  #pragma unroll
  for (int j = 0; j < 8; ++j) acc[j] += __shfl_xor(acc[j], 32, 64);
  if (r == 0) {
    #pragma unroll
    for (int j = 0; j < 8; ++j) atomicAdd(&pooled[g * HC + c * 8 + j], acc[j]);
  }
}

__global__ __launch_bounds__(512) void mlp_kernel(const float* __restrict__ pooled,
    const int* __restrict__ bounds, const float* __restrict__ Wp1, const float* __restrict__ bp1,
    const float* __restrict__ Wp2, const float* __restrict__ bp2, float* __restrict__ out) {
  __shared__ float p[256];
  __shared__ float z1[512];
  int g = blockIdx.x, t = threadIdx.x;
  if (t < 256) {
    int cnt = bounds[g + 1] - bounds[g];
    float inv = 1.0f / (float)(cnt > 1 ? cnt : 1);
    p[t] = pooled[g * 256 + t] * inv;
  }
  __syncthreads();
  float a1 = bp1[t];
  for (int k = 0; k < 256; ++k) a1 += p[k] * Wp1[k * 512 + t];
  z1[t] = fmaxf(a1, 0.f);
  __syncthreads();
  if (t < 256) {
    float a2 = bp2[t];
    for (int k = 0; k < 512; ++k) a2 += z1[k] * Wp2[k * 256 + t];
    out[g * 256 + t] = a2;
  }
}

// ---------------- launch ----------------

static inline size_t align_up(size_t x, size_t a) { return (x + a - 1) & ~(a - 1); }

extern "C" void kernel_launch(void* const* d_in, const int* in_sizes, int n_in,
                              void* d_out, int out_size, void* d_ws, size_t ws_size,
                              hipStream_t stream) {
  const float* x    = (const float*)d_in[0];
  const int*   ei   = (const int*)d_in[1];
  const int*   batch= (const int*)d_in[2];
  const float* W1   = (const float*)d_in[3];
  const float* a1s  = (const float*)d_in[4];
  const float* a1d  = (const float*)d_in[5];
  const float* b1   = (const float*)d_in[6];
  const float* W2   = (const float*)d_in[7];
  const float* a2s  = (const float*)d_in[8];
  const float* a2d  = (const float*)d_in[9];
  const float* b2   = (const float*)d_in[10];
  const float* W3   = (const float*)d_in[11];
  const float* a3s  = (const float*)d_in[12];
  const float* a3d  = (const float*)d_in[13];
  const float* b3   = (const float*)d_in[14];
  const float* Wp1  = (const float*)d_in[15];
  const float* bp1  = (const float*)d_in[16];
  const float* Wp2  = (const float*)d_in[17];
  const float* bp2  = (const float*)d_in[18];

  const int N = in_sizes[0] / 2;       // 100000
  const int E = in_sizes[1] / 2;       // 400000
  const int Et = E + N;                // with self loops

  char* base = (char*)d_ws;
  size_t off = 0;
  auto alloc = [&](size_t bytes) { size_t o = off; off = align_up(off + bytes, 256); return o; };
  u16*   h16    = (u16*)  (base + alloc((size_t)N * HC * 2));   // message-path h (bf16)
  u16*   xhi    = (u16*)  (base + alloc((size_t)N * HC * 2));   // gather out (bf16)
  float* als    = (float*)(base + alloc((size_t)N * 4 * 4));
  float* ald    = (float*)(base + alloc((size_t)N * 4 * 4));
  float* invS   = (float*)(base + alloc((size_t)N * 4 * 4));
  float* xbar   = (float*)(base + alloc((size_t)N * 8 * 4));    // layer-1 x-space gather
  float* vabuf  = (float*)(base + alloc(16 * 4));
  int*   rowptr = (int*)  (base + alloc((size_t)(N + 1) * 4));
  int*   col    = (int*)  (base + alloc((size_t)Et * 4));
  float* w      = (float*)(base + alloc((size_t)Et * 4 * 4));   // per-edge softmax numerators
  int*   deg    = (int*)  (base + alloc((size_t)N * 4));
  int*   cursor = (int*)  (base + alloc((size_t)N * 4));
  int*   bsum   = (int*)  (base + alloc(512 * 4));
  int*   bounds = (int*)  (base + alloc((GG + 1) * 4));
  float* pooled = (float*)(base + alloc((size_t)GG * HC * 4));
  (void)ws_size; (void)n_in; (void)out_size;

  // W2t/W3t (bf16, 128KB each) parked in deg/cursor space (dead after CSR build)
  u16* W2t = (u16*)deg;
  u16* W3t = (u16*)cursor;

  hipMemsetAsync(deg, 0, (size_t)N * 4, stream);
  hipMemsetAsync(cursor, 0, (size_t)N * 4, stream);
  hipMemsetAsync(pooled, 0, (size_t)GG * HC * 4, stream);

  // CSR by destination (same edge set for all layers)
  int ebk = (Et + 255) / 256;
  count_deg_kernel<<<ebk, 256, 0, stream>>>(ei, E, N, deg);
  int NT = (N + 255) / 256;
  scan_partial_kernel<<<NT, 256, 0, stream>>>(deg, N, rowptr, bsum);
  scan_bsum_kernel<<<1, 512, 0, stream>>>(bsum, NT);
  scan_add_kernel<<<NT, 256, 0, stream>>>(rowptr, bsum, N, Et);
  fill_csr_kernel<<<ebk, 256, 0, stream>>>(ei, E, N, rowptr, cursor, col);

  // weight conversion (deg/cursor now dead)
  convert_w_kernel<<<256, 256, 0, stream>>>(W2, W2t);
  convert_w_kernel<<<256, 256, 0, stream>>>(W3, W3t);

  dim3 gemm_grid(HC / GBN, (N + GBM - 1) / GBM);
  int nodeblk = (N + 3) / 4;

  // layer 1 — rank-2 factorization: everything in x-space, then one expand
  prep_va_kernel<<<1, 256, 0, stream>>>(W1, a1s, a1d, vabuf);
  logits1_kernel<<<NT, 256, 0, stream>>>(x, vabuf, als, ald, N);
  sm_gather1_kernel<<<NT, 256, 0, stream>>>(x, als, ald, rowptr, col, xbar, N);
  expand1_kernel<<<nodeblk, 256, 0, stream>>>(xbar, W1, b1, xhi, N);
  // layer 2
  gemm_mfma_kernel<<<gemm_grid, 256, 0, stream>>>(xhi, W2t, a2s, a2d, h16, als, ald, N);
  edge_softmax_kernel<<<NT, 256, 0, stream>>>(als, ald, rowptr, col, w, invS, N);
  gat_gather_kernel<<<nodeblk, 256, 0, stream>>>(h16, w, invS, rowptr, col, b2, xhi, N);
  // layer 3
  gemm_mfma_kernel<<<gemm_grid, 256, 0, stream>>>(xhi, W3t, a3s, a3d, h16, als, ald, N);
  edge_softmax_kernel<<<NT, 256, 0, stream>>>(als, ald, rowptr, col, w, invS, N);
  gat_gather_kernel<<<nodeblk, 256, 0, stream>>>(h16, w, invS, rowptr, col, b3, xhi, N);

  // pool + MLP
  bounds_kernel<<<1, 128, 0, stream>>>(batch, N, bounds);
  pool_kernel<<<dim3(GG, 32), 64, 0, stream>>>(xhi, bounds, pooled);
  mlp_kernel<<<GG, 512, 0, stream>>>(pooled, bounds, Wp1, bp1, Wp2, bp2, (float*)d_out);
}

// Round 15
// 374.357 us; speedup vs baseline: 1.0323x; 1.0172x over previous
//
#include <hip/hip_runtime.h>
#include <math.h>

#define HC 256      // H*C
#define NHEAD 4
#define NEG_SLOPE 0.2f
#define GG 64       // graphs

typedef unsigned short u16;
typedef unsigned int u32;
typedef __attribute__((ext_vector_type(8))) short short8;
typedef __attribute__((ext_vector_type(4))) float f32x4;

static __device__ inline u16 f2bf_rn(float f) {
  u32 x = __float_as_uint(f);
  u32 r = (x + 0x7fffu + ((x >> 16) & 1u)) >> 16;
  return (u16)r;
}
static __device__ inline float bf2f(u16 u) { return __uint_as_float(((u32)u) << 16); }

// ---------------- CSR build ----------------

__global__ void count_deg_kernel(const int* __restrict__ ei, int E, int Nn, int* __restrict__ deg) {
  int idx = blockIdx.x * 256 + threadIdx.x;
  int Et = E + Nn;
  if (idx >= Et) return;
  int d = (idx < E) ? ei[E + idx] : (idx - E);   // row1 of edge_index = dst; self loops appended
  atomicAdd(&deg[d], 1);
}

__global__ void scan_partial_kernel(const int* __restrict__ deg, int Nn,
                                    int* __restrict__ rowptr, int* __restrict__ bsum) {
  __shared__ int s[256];
  int t = threadIdx.x, i = blockIdx.x * 256 + t;
  int v = (i < Nn) ? deg[i] : 0;
  s[t] = v; __syncthreads();
  for (int off = 1; off < 256; off <<= 1) {
    int x = (t >= off) ? s[t - off] : 0; __syncthreads();
    s[t] += x; __syncthreads();
  }
  if (i < Nn) rowptr[i] = s[t] - v;          // exclusive within block
  if (t == 255) bsum[blockIdx.x] = s[t];     // block total
}

__global__ void scan_bsum_kernel(int* __restrict__ bsum, int nb) {
  __shared__ int s[512];
  int t = threadIdx.x;
  int v = (t < nb) ? bsum[t] : 0;
  s[t] = v; __syncthreads();
  for (int off = 1; off < 512; off <<= 1) {
    int x = (t >= off) ? s[t - off] : 0; __syncthreads();
    s[t] += x; __syncthreads();
  }
  if (t < nb) bsum[t] = s[t] - v;            // exclusive block offsets
}

__global__ void scan_add_kernel(int* __restrict__ rowptr, const int* __restrict__ bsum,
                                int Nn, int Etot) {
  int i = blockIdx.x * 256 + threadIdx.x;
  if (i < Nn) rowptr[i] += bsum[blockIdx.x];
  if (i == 0) rowptr[Nn] = Etot;
}

__global__ void fill_csr_kernel(const int* __restrict__ ei, int E, int Nn,
                                const int* __restrict__ rowptr, int* __restrict__ cursor,
                                int* __restrict__ col) {
  int idx = blockIdx.x * 256 + threadIdx.x;
  int Et = E + Nn;
  if (idx >= Et) return;
  int s, d;
  if (idx < E) { s = ei[idx]; d = ei[E + idx]; } else { s = d = idx - E; }
  int pos = atomicAdd(&cursor[d], 1);
  col[rowptr[d] + pos] = s;
}

// ---------------- W transpose + bf16: Wt[n][k] ----------------

__global__ void convert_w_kernel(const float* __restrict__ W, u16* __restrict__ hi) {
  int idx = blockIdx.x * 256 + threadIdx.x;    // 65536 threads
  if (idx >= 256 * 256) return;
  int k = idx >> 8, n = idx & 255;             // coalesced read of W[k][n]
  hi[n * 256 + k] = f2bf_rn(W[idx]);
}

// ---------------- layer 1 (rank-2 factorization) ----------------

__global__ void prep_va_kernel(const float* __restrict__ W1, const float* __restrict__ a1s,
                               const float* __restrict__ a1d, float* __restrict__ va) {
  int t = threadIdx.x;                       // 256 = 4 waves, wave q = head q
  int q = t >> 6, lane = t & 63;
  int c = t;
  float asv = a1s[c], adv = a1d[c];
  float w0 = W1[c], w1 = W1[256 + c];
  float s0 = w0 * asv, s1 = w1 * asv, d0 = w0 * adv, d1 = w1 * adv;
  #pragma unroll
  for (int off = 32; off >= 1; off >>= 1) {
    s0 += __shfl_xor(s0, off, 64); s1 += __shfl_xor(s1, off, 64);
    d0 += __shfl_xor(d0, off, 64); d1 += __shfl_xor(d1, off, 64);
  }
  if (lane == 0) {
    va[q] = s0; va[4 + q] = s1;
    va[8 + q] = d0; va[12 + q] = d1;
  }
}

__global__ void logits1_kernel(const float* __restrict__ x, const float* __restrict__ va,
                               float* __restrict__ als, float* __restrict__ ald, int Nn) {
  int node = blockIdx.x * 256 + threadIdx.x;
  if (node >= Nn) return;
  float2 xv = *(const float2*)&x[(size_t)node * 2];
  float4 vs0 = *(const float4*)&va[0], vs1 = *(const float4*)&va[4];
  float4 vd0 = *(const float4*)&va[8], vd1 = *(const float4*)&va[12];
  float4 s, d;
  s.x = xv.x * vs0.x + xv.y * vs1.x; s.y = xv.x * vs0.y + xv.y * vs1.y;
  s.z = xv.x * vs0.z + xv.y * vs1.z; s.w = xv.x * vs0.w + xv.y * vs1.w;
  d.x = xv.x * vd0.x + xv.y * vd1.x; d.y = xv.x * vd0.y + xv.y * vd1.y;
  d.z = xv.x * vd0.z + xv.y * vd1.z; d.w = xv.x * vd0.w + xv.y * vd1.w;
  *(float4*)&als[node * 4] = s;
  *(float4*)&ald[node * 4] = d;
}

// fused max-free softmax + x-space gather
__global__ void sm_gather1_kernel(const float* __restrict__ x,
    const float* __restrict__ als, const float* __restrict__ ald,
    const int* __restrict__ rowptr, const int* __restrict__ col,
    float* __restrict__ xbar, int Nn) {
  int node = blockIdx.x * 256 + threadIdx.x;
  if (node >= Nn) return;
  int rs = rowptr[node], re = rowptr[node + 1];
  float4 ad = *(const float4*)&ald[node * 4];
  float S0 = 0.f, S1 = 0.f, S2 = 0.f, S3 = 0.f;
  float a0 = 0.f, a1 = 0.f, a2 = 0.f, a3 = 0.f, a4 = 0.f, a5 = 0.f, a6 = 0.f, a7 = 0.f;
  for (int i = rs; i < re; ++i) {
    int s = col[i];
    float4 a = *(const float4*)&als[(size_t)s * 4];
    float2 xs = *(const float2*)&x[(size_t)s * 2];
    float e0 = a.x + ad.x; e0 = e0 > 0.f ? e0 : NEG_SLOPE * e0;
    float e1 = a.y + ad.y; e1 = e1 > 0.f ? e1 : NEG_SLOPE * e1;
    float e2 = a.z + ad.z; e2 = e2 > 0.f ? e2 : NEG_SLOPE * e2;
    float e3 = a.w + ad.w; e3 = e3 > 0.f ? e3 : NEG_SLOPE * e3;
    float p0 = __expf(e0), p1 = __expf(e1), p2 = __expf(e2), p3 = __expf(e3);
    S0 += p0; S1 += p1; S2 += p2; S3 += p3;
    a0 += p0 * xs.x; a1 += p0 * xs.y;
    a2 += p1 * xs.x; a3 += p1 * xs.y;
    a4 += p2 * xs.x; a5 += p2 * xs.y;
    a6 += p3 * xs.x; a7 += p3 * xs.y;
  }
  float i0 = 1.f / (S0 + 1e-16f), i1 = 1.f / (S1 + 1e-16f);
  float i2 = 1.f / (S2 + 1e-16f), i3 = 1.f / (S3 + 1e-16f);
  *(float4*)&xbar[(size_t)node * 8]     = make_float4(a0 * i0, a1 * i0, a2 * i1, a3 * i1);
  *(float4*)&xbar[(size_t)node * 8 + 4] = make_float4(a4 * i2, a5 * i2, a6 * i3, a7 * i3);
}

// expand: out1[node][c] = xbar_q . W1[:,c] + b1[c], ELU, bf16-packed
__global__ __launch_bounds__(256) void expand1_kernel(const float* __restrict__ xbar,
    const float* __restrict__ W1, const float* __restrict__ b1,
    u16* __restrict__ out16, int Nn) {
  int node = blockIdx.x * 4 + (threadIdx.x >> 6);
  int lane = threadIdx.x & 63;
  if (node >= Nn) return;
  int hA = lane >> 5;                        // head of ch pair A (0/1); pair B head = 2+hA
  float4 xb0 = *(const float4*)&xbar[(size_t)node * 8];      // heads 0,1
  float4 xb1 = *(const float4*)&xbar[(size_t)node * 8 + 4];  // heads 2,3
  float xA0 = hA ? xb0.z : xb0.x, xA1 = hA ? xb0.w : xb0.y;
  float xB0 = hA ? xb1.z : xb1.x, xB1 = hA ? xb1.w : xb1.y;
  int cA = 2 * lane, cB = 128 + 2 * lane;
  float2 wA0 = *(const float2*)&W1[cA], wA1 = *(const float2*)&W1[256 + cA];
  float2 wB0 = *(const float2*)&W1[cB], wB1 = *(const float2*)&W1[256 + cB];
  float2 bA = *(const float2*)&b1[cA],  bB = *(const float2*)&b1[cB];
  float o0 = xA0 * wA0.x + xA1 * wA1.x + bA.x;
  float o1 = xA0 * wA0.y + xA1 * wA1.y + bA.y;
  float o2 = xB0 * wB0.x + xB1 * wB1.x + bB.x;
  float o3 = xB0 * wB0.y + xB1 * wB1.y + bB.y;
  o0 = o0 > 0.f ? o0 : (__expf(o0) - 1.0f);
  o1 = o1 > 0.f ? o1 : (__expf(o1) - 1.0f);
  o2 = o2 > 0.f ? o2 : (__expf(o2) - 1.0f);
  o3 = o3 > 0.f ? o3 : (__expf(o3) - 1.0f);
  u32* o32 = (u32*)out16;
  o32[(size_t)node * 128 + lane]      = (u32)f2bf_rn(o0) | ((u32)f2bf_rn(o1) << 16);
  o32[(size_t)node * 128 + 64 + lane] = (u32)f2bf_rn(o2) | ((u32)f2bf_rn(o3) << 16);
}

// ---------------- pipelined LDS MFMA GEMM: BK=64, 128B-granule staging ----------------
// Staging geometry: pass p, thread t -> row p*32+(t>>3), 16B chunk t&7: per
// wave-instruction 8 rows x 128B CONTIGUOUS (2x the BK=32 granule that capped
// HBM at ~2.1 TB/s). 2-phase double buffer (64KB), T14 issue-early, XOR chunk
// swizzle (chunk ^= row&7) on both write and read sides. LDS-transposed C write.

#define GBM 128
#define GBN 128

__global__ __launch_bounds__(256) void gemm_mfma_kernel(
    const u16* __restrict__ A, const u16* __restrict__ Bt,
    const float* __restrict__ as_, const float* __restrict__ ad_,
    u16* __restrict__ C16, float* __restrict__ als, float* __restrict__ ald, int Mrows) {
  __shared__ __align__(16) u16 smem[32768];   // 64KB: A bufs @0,16K; B bufs @32K,48K
  char* base_ = (char*)smem;
  int bc = blockIdx.x, br = blockIdx.y;
  int tid = threadIdx.x;
  int wid = tid >> 6, lane = tid & 63;
  int wr = wid >> 1, wc = wid & 1;             // 2x2 waves; each 64x64 output
  int row0 = br * GBM, col0 = bc * GBN;
  int fr = lane & 15, fg = lane >> 4;

  // staging: 4 passes x 16B; row = p*32+(t>>3), chunk c = t&7 (8x16B = 128B/row)
  const u16* agp[4];
  const u16* bgp[4];
  int wof[4];
  #pragma unroll
  for (int p = 0; p < 4; ++p) {
    int row = p * 32 + (tid >> 3), c = tid & 7;
    int gr = row0 + row; if (gr >= Mrows) gr = Mrows - 1;
    agp[p] = A + (size_t)gr * 256 + c * 8;     // + kt*64 at use
    bgp[p] = Bt + (size_t)(col0 + row) * 256 + c * 8;
    wof[p] = row * 128 + ((c ^ (row & 7)) << 4);
  }
  // fragment LDS offsets: row*128 + swizzled 16B chunk (chunk = ks*4+fg)
  int rofA[2][4], rofB[2][4];
  #pragma unroll
  for (int ks = 0; ks < 2; ++ks) {
    #pragma unroll
    for (int m = 0; m < 4; ++m) {
      int rl = wr * 64 + m * 16 + fr;
      rofA[ks][m] = rl * 128 + (((ks * 4 + fg) ^ (rl & 7)) << 4);
      int cl_ = wc * 64 + m * 16 + fr;
      rofB[ks][m] = cl_ * 128 + (((ks * 4 + fg) ^ (cl_ & 7)) << 4);
    }
  }

  f32x4 acc[4][4];
  #pragma unroll
  for (int m = 0; m < 4; ++m)
    #pragma unroll
    for (int n = 0; n < 4; ++n) acc[m][n] = (f32x4){0.f, 0.f, 0.f, 0.f};

  uint4 va[4], vb[4];
  #pragma unroll
  for (int p = 0; p < 4; ++p) { va[p] = *(const uint4*)agp[p]; vb[p] = *(const uint4*)bgp[p]; }
  #pragma unroll
  for (int p = 0; p < 4; ++p) {
    *(uint4*)(base_ + wof[p]) = va[p];
    *(uint4*)(base_ + 32768 + wof[p]) = vb[p];
  }
  __syncthreads();

  #pragma unroll
  for (int kt = 0; kt < 4; ++kt) {             // K = 4 x 64
    int buf = kt & 1;
    if (kt < 3) {                              // T14: issue next-tile loads early
      #pragma unroll
      for (int p = 0; p < 4; ++p) {
        va[p] = *(const uint4*)(agp[p] + (kt + 1) * 64);
        vb[p] = *(const uint4*)(bgp[p] + (kt + 1) * 64);
      }
    }
    #pragma unroll
    for (int ks = 0; ks < 2; ++ks) {
      short8 af[4], bf[4];
      #pragma unroll
      for (int m = 0; m < 4; ++m) af[m] = *(const short8*)(base_ + buf * 16384 + rofA[ks][m]);
      #pragma unroll
      for (int n = 0; n < 4; ++n) bf[n] = *(const short8*)(base_ + 32768 + buf * 16384 + rofB[ks][n]);
      #pragma unroll
      for (int m = 0; m < 4; ++m)
        #pragma unroll
        for (int n = 0; n < 4; ++n)
          acc[m][n] = __builtin_amdgcn_mfma_f32_16x16x32_bf16(af[m], bf[n], acc[m][n], 0, 0, 0);
    }
    if (kt < 3) {                              // write next buffer, one barrier
      int nb = buf ^ 1;
      #pragma unroll
      for (int p = 0; p < 4; ++p) {
        *(uint4*)(base_ + nb * 16384 + wof[p]) = va[p];
        *(uint4*)(base_ + 32768 + nb * 16384 + wof[p]) = vb[p];
      }
      __syncthreads();
    }
  }

  // ---- C write via LDS transpose: 2 passes of 64 rows x 128 cols ----
  u16* cl = smem;                              // [64][128] bf16 = 16KB (reuses buf A0)
  #pragma unroll
  for (int p = 0; p < 2; ++p) {
    __syncthreads();                           // prior smem reads complete
    if (wr == p) {
      #pragma unroll
      for (int m = 0; m < 4; ++m) {
        #pragma unroll
        for (int n = 0; n < 4; ++n) {
          int c = wc * 64 + n * 16 + fr;
          #pragma unroll
          for (int j = 0; j < 4; ++j) {
            int lr = m * 16 + fg * 4 + j;
            cl[lr * 128 + c] = f2bf_rn(acc[m][n][j]);
          }
        }
      }
    }
    __syncthreads();
    #pragma unroll
    for (int i = 0; i < 4; ++i) {
      int u = i * 256 + tid;                   // uint4 index within 64x128 tile
      int lr = u >> 4, ch = u & 15;
      int grow = row0 + p * 64 + lr;
      if (grow < Mrows) {
        uint4 v = *(const uint4*)&cl[lr * 128 + ch * 8];
        *(uint4*)&C16[(size_t)grow * 256 + col0 + ch * 8] = v;
      }
    }
  }

  // fused logits: this wave's 64 cols = one head
  int head = bc * 2 + wc;
  float asv[4], adv[4];
  #pragma unroll
  for (int n = 0; n < 4; ++n) {
    asv[n] = as_[head * 64 + n * 16 + fr];
    adv[n] = ad_[head * 64 + n * 16 + fr];
  }
  #pragma unroll
  for (int m = 0; m < 4; ++m) {
    #pragma unroll
    for (int j = 0; j < 4; ++j) {
      float ps = 0.f, pd = 0.f;
      #pragma unroll
      for (int n = 0; n < 4; ++n) {
        ps += acc[m][n][j] * asv[n];
        pd += acc[m][n][j] * adv[n];
      }
      #pragma unroll
      for (int off = 1; off < 16; off <<= 1) {
        ps += __shfl_xor(ps, off, 64);
        pd += __shfl_xor(pd, off, 64);
      }
      int grow = row0 + wr * 64 + m * 16 + fg * 4 + j;
      if (fr == 0 && grow < Mrows) {
        als[grow * 4 + head] = ps;
        ald[grow * 4 + head] = pd;
      }
    }
  }
}

// ---------------- edge softmax: single pass, max-free ----------------

__global__ void edge_softmax_kernel(const float* __restrict__ als, const float* __restrict__ ald,
                                    const int* __restrict__ rowptr, const int* __restrict__ col,
                                    float* __restrict__ w, float* __restrict__ invS, int Nn) {
  int node = blockIdx.x * 256 + threadIdx.x;
  if (node >= Nn) return;
  int rs = rowptr[node], re = rowptr[node + 1];
  float4 ad = *(const float4*)&ald[node * 4];
  float S0 = 0.f, S1 = 0.f, S2 = 0.f, S3 = 0.f;
  for (int i = rs; i < re; ++i) {
    int s = col[i];
    float4 a = *(const float4*)&als[(size_t)s * 4];
    float e0 = a.x + ad.x; e0 = e0 > 0.f ? e0 : NEG_SLOPE * e0;
    float e1 = a.y + ad.y; e1 = e1 > 0.f ? e1 : NEG_SLOPE * e1;
    float e2 = a.z + ad.z; e2 = e2 > 0.f ? e2 : NEG_SLOPE * e2;
    float e3 = a.w + ad.w; e3 = e3 > 0.f ? e3 : NEG_SLOPE * e3;
    float p0 = __expf(e0), p1 = __expf(e1), p2 = __expf(e2), p3 = __expf(e3);
    *(float4*)&w[(size_t)i * 4] = make_float4(p0, p1, p2, p3);
    S0 += p0; S1 += p1; S2 += p2; S3 += p3;
  }
  *(float4*)&invS[node * 4] = make_float4(1.f / (S0 + 1e-16f), 1.f / (S1 + 1e-16f),
                                          1.f / (S2 + 1e-16f), 1.f / (S3 + 1e-16f));
}

// ---------------- GAT gather v4: one dwordx2 per lane per edge ----------------

__global__ __launch_bounds__(256) void gat_gather_kernel(const u16* __restrict__ h16,
    const float* __restrict__ w, const float* __restrict__ invS,
    const int* __restrict__ rowptr, const int* __restrict__ col,
    const float* __restrict__ bias, u16* __restrict__ out16, int Nn) {
  int node = __builtin_amdgcn_readfirstlane(blockIdx.x * 4 + (threadIdx.x >> 6));
  int lane = threadIdx.x & 63;
  if (node >= Nn) return;
  int rs = rowptr[node], re = rowptr[node + 1];
  int head = lane >> 4;                       // 16 lanes per head
  float a0 = 0.f, a1 = 0.f, a2 = 0.f, a3 = 0.f;
  const uint2* h64 = (const uint2*)h16;       // 8B units; row = 64 units
  #pragma unroll 2
  for (int i = rs; i < re; ++i) {
    int s = col[i];
    float wq = w[(size_t)i * 4 + head];
    uint2 p = h64[(size_t)s * 64 + lane];     // ch 4l..4l+3
    a0 += wq * __uint_as_float(p.x << 16);
    a1 += wq * __uint_as_float(p.x & 0xffff0000u);
    a2 += wq * __uint_as_float(p.y << 16);
    a3 += wq * __uint_as_float(p.y & 0xffff0000u);
  }
  float iS = invS[node * 4 + head];
  float4 bv = *(const float4*)&bias[4 * lane];
  float o0 = a0 * iS + bv.x;
  float o1 = a1 * iS + bv.y;
  float o2 = a2 * iS + bv.z;
  float o3 = a3 * iS + bv.w;
  o0 = o0 > 0.f ? o0 : (__expf(o0) - 1.0f);   // ELU (alpha=1)
  o1 = o1 > 0.f ? o1 : (__expf(o1) - 1.0f);
  o2 = o2 > 0.f ? o2 : (__expf(o2) - 1.0f);
  o3 = o3 > 0.f ? o3 : (__expf(o3) - 1.0f);
  uint2 ov;
  ov.x = (u32)f2bf_rn(o0) | ((u32)f2bf_rn(o1) << 16);
  ov.y = (u32)f2bf_rn(o2) | ((u32)f2bf_rn(o3) << 16);
  ((uint2*)out16)[(size_t)node * 64 + lane] = ov;
}

// ---------------- pooling + MLP ----------------

__global__ void bounds_kernel(const int* __restrict__ batch, int Nn, int* __restrict__ bounds) {
  int g = threadIdx.x;
  if (g > GG) return;
  int lo = 0, hi = Nn;
  while (lo < hi) { int mid = (lo + hi) >> 1; if (batch[mid] < g) lo = mid + 1; else hi = mid; }
  bounds[g] = lo;   // lower_bound of g; bounds[64] = N
}

__global__ __launch_bounds__(64) void pool_kernel(const u16* __restrict__ X,
    const int* __restrict__ bounds, float* __restrict__ pooled) {
  int g = blockIdx.x, split = blockIdx.y;
  int lane = threadIdx.x;                     // 64
  int s = bounds[g], e = bounds[g + 1];
  int cnt = e - s;
  if (cnt <= 0) return;
  int chunk = (cnt + gridDim.y - 1) / gridDim.y;
  int s2 = s + split * chunk, e2 = min(e, s2 + chunk);
  if (s2 >= e2) return;
  int r = lane >> 5, c = lane & 31;           // row parity, 16B chunk
  float acc[8] = {};
  for (int n = s2 + r; n < e2; n += 2) {
    uint4 v = *(const uint4*)&X[(size_t)n * HC + c * 8];
    acc[0] += __uint_as_float(v.x << 16);
    acc[1] += __uint_as_float(v.x & 0xffff0000u);
    acc[2] += __uint_as_float(v.y << 16);
    acc[3] += __uint_as_float(v.y & 0xffff0000u);
    acc[4] += __uint_as_float(v.z << 16);
    acc[5] += __uint_as_float(v.z & 0xffff0000u);
    acc[6] += __uint_as_float(v.w << 16);
    acc[7] += __uint_as_float(v.w & 0xffff0000u);
  }
  #pragma unroll
  for (int j = 0; j < 8; ++j) acc[j] += __shfl_xor(acc[j], 32, 64);
  if (r == 0) {
    #pragma unroll
    for (int j = 0; j < 8; ++j) atomicAdd(&pooled[g * HC + c * 8 + j], acc[j]);
  }
}

__global__ __launch_bounds__(512) void mlp_kernel(const float* __restrict__ pooled,
    const int* __restrict__ bounds, const float* __restrict__ Wp1, const float* __restrict__ bp1,
    const float* __restrict__ Wp2, const float* __restrict__ bp2, float* __restrict__ out) {
  __shared__ float p[256];
  __shared__ float z1[512];
  int g = blockIdx.x, t = threadIdx.x;
  if (t < 256) {
    int cnt = bounds[g + 1] - bounds[g];
    float inv = 1.0f / (float)(cnt > 1 ? cnt : 1);
    p[t] = pooled[g * 256 + t] * inv;
  }
  __syncthreads();
  float a1 = bp1[t];
  for (int k = 0; k < 256; ++k) a1 += p[k] * Wp1[k * 512 + t];
  z1[t] = fmaxf(a1, 0.f);
  __syncthreads();
  if (t < 256) {
    float a2 = bp2[t];
    for (int k = 0; k < 512; ++k) a2 += z1[k] * Wp2[k * 256 + t];
    out[g * 256 + t] = a2;
  }
}

// ---------------- launch ----------------

static inline size_t align_up(size_t x, size_t a) { return (x + a - 1) & ~(a - 1); }

extern "C" void kernel_launch(void* const* d_in, const int* in_sizes, int n_in,
                              void* d_out, int out_size, void* d_ws, size_t ws_size,
                              hipStream_t stream) {
  const float* x    = (const float*)d_in[0];
  const int*   ei   = (const int*)d_in[1];
  const int*   batch= (const int*)d_in[2];
  const float* W1   = (const float*)d_in[3];
  const float* a1s  = (const float*)d_in[4];
  const float* a1d  = (const float*)d_in[5];
  const float* b1   = (const float*)d_in[6];
  const float* W2   = (const float*)d_in[7];
  const float* a2s  = (const float*)d_in[8];
  const float* a2d  = (const float*)d_in[9];
  const float* b2   = (const float*)d_in[10];
  const float* W3   = (const float*)d_in[11];
  const float* a3s  = (const float*)d_in[12];
  const float* a3d  = (const float*)d_in[13];
  const float* b3   = (const float*)d_in[14];
  const float* Wp1  = (const float*)d_in[15];
  const float* bp1  = (const float*)d_in[16];
  const float* Wp2  = (const float*)d_in[17];
  const float* bp2  = (const float*)d_in[18];

  const int N = in_sizes[0] / 2;       // 100000
  const int E = in_sizes[1] / 2;       // 400000
  const int Et = E + N;                // with self loops

  char* base = (char*)d_ws;
  size_t off = 0;
  auto alloc = [&](size_t bytes) { size_t o = off; off = align_up(off + bytes, 256); return o; };
  u16*   h16    = (u16*)  (base + alloc((size_t)N * HC * 2));   // message-path h (bf16)
  u16*   xhi    = (u16*)  (base + alloc((size_t)N * HC * 2));   // gather out (bf16)
  float* als    = (float*)(base + alloc((size_t)N * 4 * 4));
  float* ald    = (float*)(base + alloc((size_t)N * 4 * 4));
  float* invS   = (float*)(base + alloc((size_t)N * 4 * 4));
  float* xbar   = (float*)(base + alloc((size_t)N * 8 * 4));    // layer-1 x-space gather
  float* vabuf  = (float*)(base + alloc(16 * 4));
  int*   rowptr = (int*)  (base + alloc((size_t)(N + 1) * 4));
  int*   col    = (int*)  (base + alloc((size_t)Et * 4));
  float* w      = (float*)(base + alloc((size_t)Et * 4 * 4));   // per-edge softmax numerators
  int*   deg    = (int*)  (base + alloc((size_t)N * 4));
  int*   cursor = (int*)  (base + alloc((size_t)N * 4));
  int*   bsum   = (int*)  (base + alloc(512 * 4));
  int*   bounds = (int*)  (base + alloc((GG + 1) * 4));
  float* pooled = (float*)(base + alloc((size_t)GG * HC * 4));
  (void)ws_size; (void)n_in; (void)out_size;

  // W2t/W3t (bf16, 128KB each) parked in deg/cursor space (dead after CSR build)
  u16* W2t = (u16*)deg;
  u16* W3t = (u16*)cursor;

  hipMemsetAsync(deg, 0, (size_t)N * 4, stream);
  hipMemsetAsync(cursor, 0, (size_t)N * 4, stream);
  hipMemsetAsync(pooled, 0, (size_t)GG * HC * 4, stream);

  // CSR by destination (same edge set for all layers)
  int ebk = (Et + 255) / 256;
  count_deg_kernel<<<ebk, 256, 0, stream>>>(ei, E, N, deg);
  int NT = (N + 255) / 256;
  scan_partial_kernel<<<NT, 256, 0, stream>>>(deg, N, rowptr, bsum);
  scan_bsum_kernel<<<1, 512, 0, stream>>>(bsum, NT);
  scan_add_kernel<<<NT, 256, 0, stream>>>(rowptr, bsum, N, Et);
  fill_csr_kernel<<<ebk, 256, 0, stream>>>(ei, E, N, rowptr, cursor, col);

  // weight conversion (deg/cursor now dead)
  convert_w_kernel<<<256, 256, 0, stream>>>(W2, W2t);
  convert_w_kernel<<<256, 256, 0, stream>>>(W3, W3t);

  dim3 gemm_grid(HC / GBN, (N + GBM - 1) / GBM);
  int nodeblk = (N + 3) / 4;

  // layer 1 — rank-2 factorization: everything in x-space, then one expand
  prep_va_kernel<<<1, 256, 0, stream>>>(W1, a1s, a1d, vabuf);
  logits1_kernel<<<NT, 256, 0, stream>>>(x, vabuf, als, ald, N);
  sm_gather1_kernel<<<NT, 256, 0, stream>>>(x, als, ald, rowptr, col, xbar, N);
  expand1_kernel<<<nodeblk, 256, 0, stream>>>(xbar, W1, b1, xhi, N);
  // layer 2
  gemm_mfma_kernel<<<gemm_grid, 256, 0, stream>>>(xhi, W2t, a2s, a2d, h16, als, ald, N);
  edge_softmax_kernel<<<NT, 256, 0, stream>>>(als, ald, rowptr, col, w, invS, N);
  gat_gather_kernel<<<nodeblk, 256, 0, stream>>>(h16, w, invS, rowptr, col, b2, xhi, N);
  // layer 3
  gemm_mfma_kernel<<<gemm_grid, 256, 0, stream>>>(xhi, W3t, a3s, a3d, h16, als, ald, N);
  edge_softmax_kernel<<<NT, 256, 0, stream>>>(als, ald, rowptr, col, w, invS, N);
  gat_gather_kernel<<<nodeblk, 256, 0, stream>>>(h16, w, invS, rowptr, col, b3, xhi, N);

  // pool + MLP
  bounds_kernel<<<1, 128, 0, stream>>>(batch, N, bounds);
  pool_kernel<<<dim3(GG, 32), 64, 0, stream>>>(xhi, bounds, pooled);
  mlp_kernel<<<GG, 512, 0, stream>>>(pooled, bounds, Wp1, bp1, Wp2, bp2, (float*)d_out);
}

// Round 16
// 355.508 us; speedup vs baseline: 1.0871x; 1.0530x over previous
//
#include <hip/hip_runtime.h>
#include <math.h>

#define HC 256      // H*C
#define NHEAD 4
#define NEG_SLOPE 0.2f
#define GG 64       // graphs

typedef unsigned short u16;
typedef unsigned int u32;
typedef __attribute__((ext_vector_type(8))) short short8;
typedef __attribute__((ext_vector_type(4))) float f32x4;

static __device__ inline u16 f2bf_rn(float f) {
  u32 x = __float_as_uint(f);
  u32 r = (x + 0x7fffu + ((x >> 16) & 1u)) >> 16;
  return (u16)r;
}
static __device__ inline float bf2f(u16 u) { return __uint_as_float(((u32)u) << 16); }

// ---------------- CSR build ----------------

__global__ void count_deg_kernel(const int* __restrict__ ei, int E, int Nn, int* __restrict__ deg) {
  int idx = blockIdx.x * 256 + threadIdx.x;
  int Et = E + Nn;
  if (idx >= Et) return;
  int d = (idx < E) ? ei[E + idx] : (idx - E);   // row1 of edge_index = dst; self loops appended
  atomicAdd(&deg[d], 1);
}

__global__ void scan_partial_kernel(const int* __restrict__ deg, int Nn,
                                    int* __restrict__ rowptr, int* __restrict__ bsum) {
  __shared__ int s[256];
  int t = threadIdx.x, i = blockIdx.x * 256 + t;
  int v = (i < Nn) ? deg[i] : 0;
  s[t] = v; __syncthreads();
  for (int off = 1; off < 256; off <<= 1) {
    int x = (t >= off) ? s[t - off] : 0; __syncthreads();
    s[t] += x; __syncthreads();
  }
  if (i < Nn) rowptr[i] = s[t] - v;          // exclusive within block
  if (t == 255) bsum[blockIdx.x] = s[t];     // block total
}

__global__ void scan_bsum_kernel(int* __restrict__ bsum, int nb) {
  __shared__ int s[512];
  int t = threadIdx.x;
  int v = (t < nb) ? bsum[t] : 0;
  s[t] = v; __syncthreads();
  for (int off = 1; off < 512; off <<= 1) {
    int x = (t >= off) ? s[t - off] : 0; __syncthreads();
    s[t] += x; __syncthreads();
  }
  if (t < nb) bsum[t] = s[t] - v;            // exclusive block offsets
}

__global__ void scan_add_kernel(int* __restrict__ rowptr, const int* __restrict__ bsum,
                                int Nn, int Etot) {
  int i = blockIdx.x * 256 + threadIdx.x;
  if (i < Nn) rowptr[i] += bsum[blockIdx.x];
  if (i == 0) rowptr[Nn] = Etot;
}

__global__ void fill_csr_kernel(const int* __restrict__ ei, int E, int Nn,
                                const int* __restrict__ rowptr, int* __restrict__ cursor,
                                int* __restrict__ col) {
  int idx = blockIdx.x * 256 + threadIdx.x;
  int Et = E + Nn;
  if (idx >= Et) return;
  int s, d;
  if (idx < E) { s = ei[idx]; d = ei[E + idx]; } else { s = d = idx - E; }
  int pos = atomicAdd(&cursor[d], 1);
  col[rowptr[d] + pos] = s;
}

// ---------------- W transpose + bf16: Wt[n][k] ----------------

__global__ void convert_w_kernel(const float* __restrict__ W, u16* __restrict__ hi) {
  int idx = blockIdx.x * 256 + threadIdx.x;    // 65536 threads
  if (idx >= 256 * 256) return;
  int k = idx >> 8, n = idx & 255;             // coalesced read of W[k][n]
  hi[n * 256 + k] = f2bf_rn(W[idx]);
}

// ---------------- layer 1 (rank-2 factorization) ----------------

__global__ void prep_va_kernel(const float* __restrict__ W1, const float* __restrict__ a1s,
                               const float* __restrict__ a1d, float* __restrict__ va) {
  int t = threadIdx.x;                       // 256 = 4 waves, wave q = head q
  int q = t >> 6, lane = t & 63;
  int c = t;
  float asv = a1s[c], adv = a1d[c];
  float w0 = W1[c], w1 = W1[256 + c];
  float s0 = w0 * asv, s1 = w1 * asv, d0 = w0 * adv, d1 = w1 * adv;
  #pragma unroll
  for (int off = 32; off >= 1; off >>= 1) {
    s0 += __shfl_xor(s0, off, 64); s1 += __shfl_xor(s1, off, 64);
    d0 += __shfl_xor(d0, off, 64); d1 += __shfl_xor(d1, off, 64);
  }
  if (lane == 0) {
    va[q] = s0; va[4 + q] = s1;
    va[8 + q] = d0; va[12 + q] = d1;
  }
}

__global__ void logits1_kernel(const float* __restrict__ x, const float* __restrict__ va,
                               float* __restrict__ als, float* __restrict__ ald, int Nn) {
  int node = blockIdx.x * 256 + threadIdx.x;
  if (node >= Nn) return;
  float2 xv = *(const float2*)&x[(size_t)node * 2];
  float4 vs0 = *(const float4*)&va[0], vs1 = *(const float4*)&va[4];
  float4 vd0 = *(const float4*)&va[8], vd1 = *(const float4*)&va[12];
  float4 s, d;
  s.x = xv.x * vs0.x + xv.y * vs1.x; s.y = xv.x * vs0.y + xv.y * vs1.y;
  s.z = xv.x * vs0.z + xv.y * vs1.z; s.w = xv.x * vs0.w + xv.y * vs1.w;
  d.x = xv.x * vd0.x + xv.y * vd1.x; d.y = xv.x * vd0.y + xv.y * vd1.y;
  d.z = xv.x * vd0.z + xv.y * vd1.z; d.w = xv.x * vd0.w + xv.y * vd1.w;
  *(float4*)&als[node * 4] = s;
  *(float4*)&ald[node * 4] = d;
}

// fused max-free softmax + x-space gather
__global__ void sm_gather1_kernel(const float* __restrict__ x,
    const float* __restrict__ als, const float* __restrict__ ald,
    const int* __restrict__ rowptr, const int* __restrict__ col,
    float* __restrict__ xbar, int Nn) {
  int node = blockIdx.x * 256 + threadIdx.x;
  if (node >= Nn) return;
  int rs = rowptr[node], re = rowptr[node + 1];
  float4 ad = *(const float4*)&ald[node * 4];
  float S0 = 0.f, S1 = 0.f, S2 = 0.f, S3 = 0.f;
  float a0 = 0.f, a1 = 0.f, a2 = 0.f, a3 = 0.f, a4 = 0.f, a5 = 0.f, a6 = 0.f, a7 = 0.f;
  for (int i = rs; i < re; ++i) {
    int s = col[i];
    float4 a = *(const float4*)&als[(size_t)s * 4];
    float2 xs = *(const float2*)&x[(size_t)s * 2];
    float e0 = a.x + ad.x; e0 = e0 > 0.f ? e0 : NEG_SLOPE * e0;
    float e1 = a.y + ad.y; e1 = e1 > 0.f ? e1 : NEG_SLOPE * e1;
    float e2 = a.z + ad.z; e2 = e2 > 0.f ? e2 : NEG_SLOPE * e2;
    float e3 = a.w + ad.w; e3 = e3 > 0.f ? e3 : NEG_SLOPE * e3;
    float p0 = __expf(e0), p1 = __expf(e1), p2 = __expf(e2), p3 = __expf(e3);
    S0 += p0; S1 += p1; S2 += p2; S3 += p3;
    a0 += p0 * xs.x; a1 += p0 * xs.y;
    a2 += p1 * xs.x; a3 += p1 * xs.y;
    a4 += p2 * xs.x; a5 += p2 * xs.y;
    a6 += p3 * xs.x; a7 += p3 * xs.y;
  }
  float i0 = 1.f / (S0 + 1e-16f), i1 = 1.f / (S1 + 1e-16f);
  float i2 = 1.f / (S2 + 1e-16f), i3 = 1.f / (S3 + 1e-16f);
  *(float4*)&xbar[(size_t)node * 8]     = make_float4(a0 * i0, a1 * i0, a2 * i1, a3 * i1);
  *(float4*)&xbar[(size_t)node * 8 + 4] = make_float4(a4 * i2, a5 * i2, a6 * i3, a7 * i3);
}

// expand: out1[node][c] = xbar_q . W1[:,c] + b1[c], ELU, bf16-packed
__global__ __launch_bounds__(256) void expand1_kernel(const float* __restrict__ xbar,
    const float* __restrict__ W1, const float* __restrict__ b1,
    u16* __restrict__ out16, int Nn) {
  int node = blockIdx.x * 4 + (threadIdx.x >> 6);
  int lane = threadIdx.x & 63;
  if (node >= Nn) return;
  int hA = lane >> 5;                        // head of ch pair A (0/1); pair B head = 2+hA
  float4 xb0 = *(const float4*)&xbar[(size_t)node * 8];      // heads 0,1
  float4 xb1 = *(const float4*)&xbar[(size_t)node * 8 + 4];  // heads 2,3
  float xA0 = hA ? xb0.z : xb0.x, xA1 = hA ? xb0.w : xb0.y;
  float xB0 = hA ? xb1.z : xb1.x, xB1 = hA ? xb1.w : xb1.y;
  int cA = 2 * lane, cB = 128 + 2 * lane;
  float2 wA0 = *(const float2*)&W1[cA], wA1 = *(const float2*)&W1[256 + cA];
  float2 wB0 = *(const float2*)&W1[cB], wB1 = *(const float2*)&W1[256 + cB];
  float2 bA = *(const float2*)&b1[cA],  bB = *(const float2*)&b1[cB];
  float o0 = xA0 * wA0.x + xA1 * wA1.x + bA.x;
  float o1 = xA0 * wA0.y + xA1 * wA1.y + bA.y;
  float o2 = xB0 * wB0.x + xB1 * wB1.x + bB.x;
  float o3 = xB0 * wB0.y + xB1 * wB1.y + bB.y;
  o0 = o0 > 0.f ? o0 : (__expf(o0) - 1.0f);
  o1 = o1 > 0.f ? o1 : (__expf(o1) - 1.0f);
  o2 = o2 > 0.f ? o2 : (__expf(o2) - 1.0f);
  o3 = o3 > 0.f ? o3 : (__expf(o3) - 1.0f);
  u32* o32 = (u32*)out16;
  o32[(size_t)node * 128 + lane]      = (u32)f2bf_rn(o0) | ((u32)f2bf_rn(o1) << 16);
  o32[(size_t)node * 128 + 64 + lane] = (u32)f2bf_rn(o2) | ((u32)f2bf_rn(o3) << 16);
}

// ---------------- pipelined LDS MFMA GEMM: BK=64, 128B-granule staging ----------------

#define GBM 128
#define GBN 128

__global__ __launch_bounds__(256) void gemm_mfma_kernel(
    const u16* __restrict__ A, const u16* __restrict__ Bt,
    const float* __restrict__ as_, const float* __restrict__ ad_,
    u16* __restrict__ C16, float* __restrict__ als, float* __restrict__ ald, int Mrows) {
  __shared__ __align__(16) u16 smem[32768];   // 64KB: A bufs @0,16K; B bufs @32K,48K
  char* base_ = (char*)smem;
  int bc = blockIdx.x, br = blockIdx.y;
  int tid = threadIdx.x;
  int wid = tid >> 6, lane = tid & 63;
  int wr = wid >> 1, wc = wid & 1;             // 2x2 waves; each 64x64 output
  int row0 = br * GBM, col0 = bc * GBN;
  int fr = lane & 15, fg = lane >> 4;

  const u16* agp[4];
  const u16* bgp[4];
  int wof[4];
  #pragma unroll
  for (int p = 0; p < 4; ++p) {
    int row = p * 32 + (tid >> 3), c = tid & 7;
    int gr = row0 + row; if (gr >= Mrows) gr = Mrows - 1;
    agp[p] = A + (size_t)gr * 256 + c * 8;     // + kt*64 at use
    bgp[p] = Bt + (size_t)(col0 + row) * 256 + c * 8;
    wof[p] = row * 128 + ((c ^ (row & 7)) << 4);
  }
  int rofA[2][4], rofB[2][4];
  #pragma unroll
  for (int ks = 0; ks < 2; ++ks) {
    #pragma unroll
    for (int m = 0; m < 4; ++m) {
      int rl = wr * 64 + m * 16 + fr;
      rofA[ks][m] = rl * 128 + (((ks * 4 + fg) ^ (rl & 7)) << 4);
      int cl_ = wc * 64 + m * 16 + fr;
      rofB[ks][m] = cl_ * 128 + (((ks * 4 + fg) ^ (cl_ & 7)) << 4);
    }
  }

  f32x4 acc[4][4];
  #pragma unroll
  for (int m = 0; m < 4; ++m)
    #pragma unroll
    for (int n = 0; n < 4; ++n) acc[m][n] = (f32x4){0.f, 0.f, 0.f, 0.f};

  uint4 va[4], vb[4];
  #pragma unroll
  for (int p = 0; p < 4; ++p) { va[p] = *(const uint4*)agp[p]; vb[p] = *(const uint4*)bgp[p]; }
  #pragma unroll
  for (int p = 0; p < 4; ++p) {
    *(uint4*)(base_ + wof[p]) = va[p];
    *(uint4*)(base_ + 32768 + wof[p]) = vb[p];
  }
  __syncthreads();

  #pragma unroll
  for (int kt = 0; kt < 4; ++kt) {             // K = 4 x 64
    int buf = kt & 1;
    if (kt < 3) {                              // T14: issue next-tile loads early
      #pragma unroll
      for (int p = 0; p < 4; ++p) {
        va[p] = *(const uint4*)(agp[p] + (kt + 1) * 64);
        vb[p] = *(const uint4*)(bgp[p] + (kt + 1) * 64);
      }
    }
    #pragma unroll
    for (int ks = 0; ks < 2; ++ks) {
      short8 af[4], bf[4];
      #pragma unroll
      for (int m = 0; m < 4; ++m) af[m] = *(const short8*)(base_ + buf * 16384 + rofA[ks][m]);
      #pragma unroll
      for (int n = 0; n < 4; ++n) bf[n] = *(const short8*)(base_ + 32768 + buf * 16384 + rofB[ks][n]);
      #pragma unroll
      for (int m = 0; m < 4; ++m)
        #pragma unroll
        for (int n = 0; n < 4; ++n)
          acc[m][n] = __builtin_amdgcn_mfma_f32_16x16x32_bf16(af[m], bf[n], acc[m][n], 0, 0, 0);
    }
    if (kt < 3) {                              // write next buffer, one barrier
      int nb = buf ^ 1;
      #pragma unroll
      for (int p = 0; p < 4; ++p) {
        *(uint4*)(base_ + nb * 16384 + wof[p]) = va[p];
        *(uint4*)(base_ + 32768 + nb * 16384 + wof[p]) = vb[p];
      }
      __syncthreads();
    }
  }

  // ---- C write via LDS transpose: 2 passes of 64 rows x 128 cols ----
  u16* cl = smem;                              // [64][128] bf16 = 16KB (reuses buf A0)
  #pragma unroll
  for (int p = 0; p < 2; ++p) {
    __syncthreads();                           // prior smem reads complete
    if (wr == p) {
      #pragma unroll
      for (int m = 0; m < 4; ++m) {
        #pragma unroll
        for (int n = 0; n < 4; ++n) {
          int c = wc * 64 + n * 16 + fr;
          #pragma unroll
          for (int j = 0; j < 4; ++j) {
            int lr = m * 16 + fg * 4 + j;
            cl[lr * 128 + c] = f2bf_rn(acc[m][n][j]);
          }
        }
      }
    }
    __syncthreads();
    #pragma unroll
    for (int i = 0; i < 4; ++i) {
      int u = i * 256 + tid;                   // uint4 index within 64x128 tile
      int lr = u >> 4, ch = u & 15;
      int grow = row0 + p * 64 + lr;
      if (grow < Mrows) {
        uint4 v = *(const uint4*)&cl[lr * 128 + ch * 8];
        *(uint4*)&C16[(size_t)grow * 256 + col0 + ch * 8] = v;
      }
    }
  }

  // fused logits: this wave's 64 cols = one head
  int head = bc * 2 + wc;
  float asv[4], adv[4];
  #pragma unroll
  for (int n = 0; n < 4; ++n) {
    asv[n] = as_[head * 64 + n * 16 + fr];
    adv[n] = ad_[head * 64 + n * 16 + fr];
  }
  #pragma unroll
  for (int m = 0; m < 4; ++m) {
    #pragma unroll
    for (int j = 0; j < 4; ++j) {
      float ps = 0.f, pd = 0.f;
      #pragma unroll
      for (int n = 0; n < 4; ++n) {
        ps += acc[m][n][j] * asv[n];
        pd += acc[m][n][j] * adv[n];
      }
      #pragma unroll
      for (int off = 1; off < 16; off <<= 1) {
        ps += __shfl_xor(ps, off, 64);
        pd += __shfl_xor(pd, off, 64);
      }
      int grow = row0 + wr * 64 + m * 16 + fg * 4 + j;
      if (fr == 0 && grow < Mrows) {
        als[grow * 4 + head] = ps;
        ald[grow * 4 + head] = pd;
      }
    }
  }
}

// ---------------- GAT gather v5: fused edge softmax (per-head redundant, no shuffles) ----
// wave per node; lane l owns ch {4l..4l+3}, head = l>>4 (16 lanes/head).
// Per edge: uniform col + broadcast als[s][head] dword + leakyrelu + exp
// (redundant within head group, VALU-cheap) + 1 dwordx2 h load + 4 FMA.
// S accumulated per-lane (identical within group); normalize at end.

__global__ __launch_bounds__(256) void gat_gather_kernel(const u16* __restrict__ h16,
    const float* __restrict__ als, const float* __restrict__ ald,
    const int* __restrict__ rowptr, const int* __restrict__ col,
    const float* __restrict__ bias, u16* __restrict__ out16, int Nn) {
  int node = __builtin_amdgcn_readfirstlane(blockIdx.x * 4 + (threadIdx.x >> 6));
  int lane = threadIdx.x & 63;
  if (node >= Nn) return;
  int rs = rowptr[node], re = rowptr[node + 1];
  int head = lane >> 4;                       // 16 lanes per head
  float adv = ald[(size_t)node * 4 + head];
  float S = 0.f;
  float a0 = 0.f, a1 = 0.f, a2 = 0.f, a3 = 0.f;
  const uint2* h64 = (const uint2*)h16;       // 8B units; row = 64 units
  #pragma unroll 2
  for (int i = rs; i < re; ++i) {
    int s = col[i];
    float e = als[(size_t)s * 4 + head] + adv;
    e = e > 0.f ? e : NEG_SLOPE * e;
    float p = __expf(e);                      // max-free: logits O(1)-bounded
    S += p;
    uint2 pv = h64[(size_t)s * 64 + lane];    // ch 4l..4l+3
    a0 += p * __uint_as_float(pv.x << 16);
    a1 += p * __uint_as_float(pv.x & 0xffff0000u);
    a2 += p * __uint_as_float(pv.y << 16);
    a3 += p * __uint_as_float(pv.y & 0xffff0000u);
  }
  float iS = 1.f / (S + 1e-16f);
  float4 bv = *(const float4*)&bias[4 * lane];
  float o0 = a0 * iS + bv.x;
  float o1 = a1 * iS + bv.y;
  float o2 = a2 * iS + bv.z;
  float o3 = a3 * iS + bv.w;
  o0 = o0 > 0.f ? o0 : (__expf(o0) - 1.0f);   // ELU (alpha=1)
  o1 = o1 > 0.f ? o1 : (__expf(o1) - 1.0f);
  o2 = o2 > 0.f ? o2 : (__expf(o2) - 1.0f);
  o3 = o3 > 0.f ? o3 : (__expf(o3) - 1.0f);
  uint2 ov;
  ov.x = (u32)f2bf_rn(o0) | ((u32)f2bf_rn(o1) << 16);
  ov.y = (u32)f2bf_rn(o2) | ((u32)f2bf_rn(o3) << 16);
  ((uint2*)out16)[(size_t)node * 64 + lane] = ov;
}

// ---------------- pooling + MLP ----------------

__global__ void bounds_kernel(const int* __restrict__ batch, int Nn, int* __restrict__ bounds) {
  int g = threadIdx.x;
  if (g > GG) return;
  int lo = 0, hi = Nn;
  while (lo < hi) { int mid = (lo + hi) >> 1; if (batch[mid] < g) lo = mid + 1; else hi = mid; }
  bounds[g] = lo;   // lower_bound of g; bounds[64] = N
}

__global__ __launch_bounds__(64) void pool_kernel(const u16* __restrict__ X,
    const int* __restrict__ bounds, float* __restrict__ pooled) {
  int g = blockIdx.x, split = blockIdx.y;
  int lane = threadIdx.x;                     // 64
  int s = bounds[g], e = bounds[g + 1];
  int cnt = e - s;
  if (cnt <= 0) return;
  int chunk = (cnt + gridDim.y - 1) / gridDim.y;
  int s2 = s + split * chunk, e2 = min(e, s2 + chunk);
  if (s2 >= e2) return;
  int r = lane >> 5, c = lane & 31;           // row parity, 16B chunk
  float acc[8] = {};
  for (int n = s2 + r; n < e2; n += 2) {
    uint4 v = *(const uint4*)&X[(size_t)n * HC + c * 8];
    acc[0] += __uint_as_float(v.x << 16);
    acc[1] += __uint_as_float(v.x & 0xffff0000u);
    acc[2] += __uint_as_float(v.y << 16);
    acc[3] += __uint_as_float(v.y & 0xffff0000u);
    acc[4] += __uint_as_float(v.z << 16);
    acc[5] += __uint_as_float(v.z & 0xffff0000u);
    acc[6] += __uint_as_float(v.w << 16);
    acc[7] += __uint_as_float(v.w & 0xffff0000u);
  }
  #pragma unroll
  for (int j = 0; j < 8; ++j) acc[j] += __shfl_xor(acc[j], 32, 64);
  if (r == 0) {
    #pragma unroll
    for (int j = 0; j < 8; ++j) atomicAdd(&pooled[g * HC + c * 8 + j], acc[j]);
  }
}

__global__ __launch_bounds__(512) void mlp_kernel(const float* __restrict__ pooled,
    const int* __restrict__ bounds, const float* __restrict__ Wp1, const float* __restrict__ bp1,
    const float* __restrict__ Wp2, const float* __restrict__ bp2, float* __restrict__ out) {
  __shared__ float p[256];
  __shared__ float z1[512];
  int g = blockIdx.x, t = threadIdx.x;
  if (t < 256) {
    int cnt = bounds[g + 1] - bounds[g];
    float inv = 1.0f / (float)(cnt > 1 ? cnt : 1);
    p[t] = pooled[g * 256 + t] * inv;
  }
  __syncthreads();
  float a1 = bp1[t];
  for (int k = 0; k < 256; ++k) a1 += p[k] * Wp1[k * 512 + t];
  z1[t] = fmaxf(a1, 0.f);
  __syncthreads();
  if (t < 256) {
    float a2 = bp2[t];
    for (int k = 0; k < 512; ++k) a2 += z1[k] * Wp2[k * 256 + t];
    out[g * 256 + t] = a2;
  }
}

// ---------------- launch ----------------

static inline size_t align_up(size_t x, size_t a) { return (x + a - 1) & ~(a - 1); }

extern "C" void kernel_launch(void* const* d_in, const int* in_sizes, int n_in,
                              void* d_out, int out_size, void* d_ws, size_t ws_size,
                              hipStream_t stream) {
  const float* x    = (const float*)d_in[0];
  const int*   ei   = (const int*)d_in[1];
  const int*   batch= (const int*)d_in[2];
  const float* W1   = (const float*)d_in[3];
  const float* a1s  = (const float*)d_in[4];
  const float* a1d  = (const float*)d_in[5];
  const float* b1   = (const float*)d_in[6];
  const float* W2   = (const float*)d_in[7];
  const float* a2s  = (const float*)d_in[8];
  const float* a2d  = (const float*)d_in[9];
  const float* b2   = (const float*)d_in[10];
  const float* W3   = (const float*)d_in[11];
  const float* a3s  = (const float*)d_in[12];
  const float* a3d  = (const float*)d_in[13];
  const float* b3   = (const float*)d_in[14];
  const float* Wp1  = (const float*)d_in[15];
  const float* bp1  = (const float*)d_in[16];
  const float* Wp2  = (const float*)d_in[17];
  const float* bp2  = (const float*)d_in[18];

  const int N = in_sizes[0] / 2;       // 100000
  const int E = in_sizes[1] / 2;       // 400000
  const int Et = E + N;                // with self loops

  char* base = (char*)d_ws;
  size_t off = 0;
  auto alloc = [&](size_t bytes) { size_t o = off; off = align_up(off + bytes, 256); return o; };
  u16*   h16    = (u16*)  (base + alloc((size_t)N * HC * 2));   // message-path h (bf16)
  u16*   xhi    = (u16*)  (base + alloc((size_t)N * HC * 2));   // gather out (bf16)
  float* als    = (float*)(base + alloc((size_t)N * 4 * 4));
  float* ald    = (float*)(base + alloc((size_t)N * 4 * 4));
  float* xbar   = (float*)(base + alloc((size_t)N * 8 * 4));    // layer-1 x-space gather
  float* vabuf  = (float*)(base + alloc(16 * 4));
  int*   rowptr = (int*)  (base + alloc((size_t)(N + 1) * 4));
  int*   col    = (int*)  (base + alloc((size_t)Et * 4));
  int*   deg    = (int*)  (base + alloc((size_t)N * 4));
  int*   cursor = (int*)  (base + alloc((size_t)N * 4));
  int*   bsum   = (int*)  (base + alloc(512 * 4));
  int*   bounds = (int*)  (base + alloc((GG + 1) * 4));
  float* pooled = (float*)(base + alloc((size_t)GG * HC * 4));
  (void)ws_size; (void)n_in; (void)out_size;

  // W2t/W3t (bf16, 128KB each) parked in deg/cursor space (dead after CSR build)
  u16* W2t = (u16*)deg;
  u16* W3t = (u16*)cursor;

  hipMemsetAsync(deg, 0, (size_t)N * 4, stream);
  hipMemsetAsync(cursor, 0, (size_t)N * 4, stream);
  hipMemsetAsync(pooled, 0, (size_t)GG * HC * 4, stream);

  // CSR by destination (same edge set for all layers)
  int ebk = (Et + 255) / 256;
  count_deg_kernel<<<ebk, 256, 0, stream>>>(ei, E, N, deg);
  int NT = (N + 255) / 256;
  scan_partial_kernel<<<NT, 256, 0, stream>>>(deg, N, rowptr, bsum);
  scan_bsum_kernel<<<1, 512, 0, stream>>>(bsum, NT);
  scan_add_kernel<<<NT, 256, 0, stream>>>(rowptr, bsum, N, Et);
  fill_csr_kernel<<<ebk, 256, 0, stream>>>(ei, E, N, rowptr, cursor, col);

  // weight conversion (deg/cursor now dead)
  convert_w_kernel<<<256, 256, 0, stream>>>(W2, W2t);
  convert_w_kernel<<<256, 256, 0, stream>>>(W3, W3t);

  dim3 gemm_grid(HC / GBN, (N + GBM - 1) / GBM);
  int nodeblk = (N + 3) / 4;

  // layer 1 — rank-2 factorization: everything in x-space, then one expand
  prep_va_kernel<<<1, 256, 0, stream>>>(W1, a1s, a1d, vabuf);
  logits1_kernel<<<NT, 256, 0, stream>>>(x, vabuf, als, ald, N);
  sm_gather1_kernel<<<NT, 256, 0, stream>>>(x, als, ald, rowptr, col, xbar, N);
  expand1_kernel<<<nodeblk, 256, 0, stream>>>(xbar, W1, b1, xhi, N);
  // layer 2 (edge softmax fused into gather)
  gemm_mfma_kernel<<<gemm_grid, 256, 0, stream>>>(xhi, W2t, a2s, a2d, h16, als, ald, N);
  gat_gather_kernel<<<nodeblk, 256, 0, stream>>>(h16, als, ald, rowptr, col, b2, xhi, N);
  // layer 3
  gemm_mfma_kernel<<<gemm_grid, 256, 0, stream>>>(xhi, W3t, a3s, a3d, h16, als, ald, N);
  gat_gather_kernel<<<nodeblk, 256, 0, stream>>>(h16, als, ald, rowptr, col, b3, xhi, N);

  // pool + MLP
  bounds_kernel<<<1, 128, 0, stream>>>(batch, N, bounds);
  pool_kernel<<<dim3(GG, 32), 64, 0, stream>>>(xhi, bounds, pooled);
  mlp_kernel<<<GG, 512, 0, stream>>>(pooled, bounds, Wp1, bp1, Wp2, bp2, (float*)d_out);
}

// Round 17
// 339.817 us; speedup vs baseline: 1.1373x; 1.0462x over previous
//
#include <hip/hip_runtime.h>
#include <math.h>

#define HC 256      // H*C
#define NHEAD 4
#define NEG_SLOPE 0.2f
#define GG 64       // graphs

typedef unsigned short u16;
typedef unsigned int u32;
typedef __attribute__((ext_vector_type(8))) short short8;
typedef __attribute__((ext_vector_type(4))) float f32x4;

static __device__ inline u16 f2bf_rn(float f) {
  u32 x = __float_as_uint(f);
  u32 r = (x + 0x7fffu + ((x >> 16) & 1u)) >> 16;
  return (u16)r;
}
static __device__ inline float bf2f(u16 u) { return __uint_as_float(((u32)u) << 16); }

// ---------------- CSR build ----------------

__global__ void count_deg_kernel(const int* __restrict__ ei, int E, int Nn, int* __restrict__ deg) {
  int idx = blockIdx.x * 256 + threadIdx.x;
  int Et = E + Nn;
  if (idx >= Et) return;
  int d = (idx < E) ? ei[E + idx] : (idx - E);   // row1 of edge_index = dst; self loops appended
  atomicAdd(&deg[d], 1);
}

__global__ void scan_partial_kernel(const int* __restrict__ deg, int Nn,
                                    int* __restrict__ rowptr, int* __restrict__ bsum) {
  __shared__ int s[256];
  int t = threadIdx.x, i = blockIdx.x * 256 + t;
  int v = (i < Nn) ? deg[i] : 0;
  s[t] = v; __syncthreads();
  for (int off = 1; off < 256; off <<= 1) {
    int x = (t >= off) ? s[t - off] : 0; __syncthreads();
    s[t] += x; __syncthreads();
  }
  if (i < Nn) rowptr[i] = s[t] - v;          // exclusive within block
  if (t == 255) bsum[blockIdx.x] = s[t];     // block total
}

__global__ void scan_bsum_kernel(int* __restrict__ bsum, int nb) {
  __shared__ int s[512];
  int t = threadIdx.x;
  int v = (t < nb) ? bsum[t] : 0;
  s[t] = v; __syncthreads();
  for (int off = 1; off < 512; off <<= 1) {
    int x = (t >= off) ? s[t - off] : 0; __syncthreads();
    s[t] += x; __syncthreads();
  }
  if (t < nb) bsum[t] = s[t] - v;            // exclusive block offsets
}

__global__ void scan_add_kernel(int* __restrict__ rowptr, const int* __restrict__ bsum,
                                int Nn, int Etot) {
  int i = blockIdx.x * 256 + threadIdx.x;
  if (i < Nn) rowptr[i] += bsum[blockIdx.x];
  if (i == 0) rowptr[Nn] = Etot;
}

__global__ void fill_csr_kernel(const int* __restrict__ ei, int E, int Nn,
                                const int* __restrict__ rowptr, int* __restrict__ cursor,
                                int* __restrict__ col) {
  int idx = blockIdx.x * 256 + threadIdx.x;
  int Et = E + Nn;
  if (idx >= Et) return;
  int s, d;
  if (idx < E) { s = ei[idx]; d = ei[E + idx]; } else { s = d = idx - E; }
  int pos = atomicAdd(&cursor[d], 1);
  col[rowptr[d] + pos] = s;
}

// ---------------- W transpose + bf16: Wt[n][k] ----------------

__global__ void convert_w_kernel(const float* __restrict__ W, u16* __restrict__ hi) {
  int idx = blockIdx.x * 256 + threadIdx.x;    // 65536 threads
  if (idx >= 256 * 256) return;
  int k = idx >> 8, n = idx & 255;             // coalesced read of W[k][n]
  hi[n * 256 + k] = f2bf_rn(W[idx]);
}

// ---------------- layer 1 (rank-2 factorization) ----------------

__global__ void prep_va_kernel(const float* __restrict__ W1, const float* __restrict__ a1s,
                               const float* __restrict__ a1d, float* __restrict__ va) {
  int t = threadIdx.x;                       // 256 = 4 waves, wave q = head q
  int q = t >> 6, lane = t & 63;
  int c = t;
  float asv = a1s[c], adv = a1d[c];
  float w0 = W1[c], w1 = W1[256 + c];
  float s0 = w0 * asv, s1 = w1 * asv, d0 = w0 * adv, d1 = w1 * adv;
  #pragma unroll
  for (int off = 32; off >= 1; off >>= 1) {
    s0 += __shfl_xor(s0, off, 64); s1 += __shfl_xor(s1, off, 64);
    d0 += __shfl_xor(d0, off, 64); d1 += __shfl_xor(d1, off, 64);
  }
  if (lane == 0) {
    va[q] = s0; va[4 + q] = s1;
    va[8 + q] = d0; va[12 + q] = d1;
  }
}

__global__ void logits1_kernel(const float* __restrict__ x, const float* __restrict__ va,
                               float* __restrict__ als, float* __restrict__ ald, int Nn) {
  int node = blockIdx.x * 256 + threadIdx.x;
  if (node >= Nn) return;
  float2 xv = *(const float2*)&x[(size_t)node * 2];
  float4 vs0 = *(const float4*)&va[0], vs1 = *(const float4*)&va[4];
  float4 vd0 = *(const float4*)&va[8], vd1 = *(const float4*)&va[12];
  float4 s, d;
  s.x = xv.x * vs0.x + xv.y * vs1.x; s.y = xv.x * vs0.y + xv.y * vs1.y;
  s.z = xv.x * vs0.z + xv.y * vs1.z; s.w = xv.x * vs0.w + xv.y * vs1.w;
  d.x = xv.x * vd0.x + xv.y * vd1.x; d.y = xv.x * vd0.y + xv.y * vd1.y;
  d.z = xv.x * vd0.z + xv.y * vd1.z; d.w = xv.x * vd0.w + xv.y * vd1.w;
  *(float4*)&als[node * 4] = s;
  *(float4*)&ald[node * 4] = d;
}

// fused max-free softmax + x-space gather
__global__ void sm_gather1_kernel(const float* __restrict__ x,
    const float* __restrict__ als, const float* __restrict__ ald,
    const int* __restrict__ rowptr, const int* __restrict__ col,
    float* __restrict__ xbar, int Nn) {
  int node = blockIdx.x * 256 + threadIdx.x;
  if (node >= Nn) return;
  int rs = rowptr[node], re = rowptr[node + 1];
  float4 ad = *(const float4*)&ald[node * 4];
  float S0 = 0.f, S1 = 0.f, S2 = 0.f, S3 = 0.f;
  float a0 = 0.f, a1 = 0.f, a2 = 0.f, a3 = 0.f, a4 = 0.f, a5 = 0.f, a6 = 0.f, a7 = 0.f;
  for (int i = rs; i < re; ++i) {
    int s = col[i];
    float4 a = *(const float4*)&als[(size_t)s * 4];
    float2 xs = *(const float2*)&x[(size_t)s * 2];
    float e0 = a.x + ad.x; e0 = e0 > 0.f ? e0 : NEG_SLOPE * e0;
    float e1 = a.y + ad.y; e1 = e1 > 0.f ? e1 : NEG_SLOPE * e1;
    float e2 = a.z + ad.z; e2 = e2 > 0.f ? e2 : NEG_SLOPE * e2;
    float e3 = a.w + ad.w; e3 = e3 > 0.f ? e3 : NEG_SLOPE * e3;
    float p0 = __expf(e0), p1 = __expf(e1), p2 = __expf(e2), p3 = __expf(e3);
    S0 += p0; S1 += p1; S2 += p2; S3 += p3;
    a0 += p0 * xs.x; a1 += p0 * xs.y;
    a2 += p1 * xs.x; a3 += p1 * xs.y;
    a4 += p2 * xs.x; a5 += p2 * xs.y;
    a6 += p3 * xs.x; a7 += p3 * xs.y;
  }
  float i0 = 1.f / (S0 + 1e-16f), i1 = 1.f / (S1 + 1e-16f);
  float i2 = 1.f / (S2 + 1e-16f), i3 = 1.f / (S3 + 1e-16f);
  *(float4*)&xbar[(size_t)node * 8]     = make_float4(a0 * i0, a1 * i0, a2 * i1, a3 * i1);
  *(float4*)&xbar[(size_t)node * 8 + 4] = make_float4(a4 * i2, a5 * i2, a6 * i3, a7 * i3);
}

// expand: out1[node][c] = xbar_q . W1[:,c] + b1[c], ELU, bf16-packed
__global__ __launch_bounds__(256) void expand1_kernel(const float* __restrict__ xbar,
    const float* __restrict__ W1, const float* __restrict__ b1,
    u16* __restrict__ out16, int Nn) {
  int node = blockIdx.x * 4 + (threadIdx.x >> 6);
  int lane = threadIdx.x & 63;
  if (node >= Nn) return;
  int hA = lane >> 5;                        // head of ch pair A (0/1); pair B head = 2+hA
  float4 xb0 = *(const float4*)&xbar[(size_t)node * 8];      // heads 0,1
  float4 xb1 = *(const float4*)&xbar[(size_t)node * 8 + 4];  // heads 2,3
  float xA0 = hA ? xb0.z : xb0.x, xA1 = hA ? xb0.w : xb0.y;
  float xB0 = hA ? xb1.z : xb1.x, xB1 = hA ? xb1.w : xb1.y;
  int cA = 2 * lane, cB = 128 + 2 * lane;
  float2 wA0 = *(const float2*)&W1[cA], wA1 = *(const float2*)&W1[256 + cA];
  float2 wB0 = *(const float2*)&W1[cB], wB1 = *(const float2*)&W1[256 + cB];
  float2 bA = *(const float2*)&b1[cA],  bB = *(const float2*)&b1[cB];
  float o0 = xA0 * wA0.x + xA1 * wA1.x + bA.x;
  float o1 = xA0 * wA0.y + xA1 * wA1.y + bA.y;
  float o2 = xB0 * wB0.x + xB1 * wB1.x + bB.x;
  float o3 = xB0 * wB0.y + xB1 * wB1.y + bB.y;
  o0 = o0 > 0.f ? o0 : (__expf(o0) - 1.0f);
  o1 = o1 > 0.f ? o1 : (__expf(o1) - 1.0f);
  o2 = o2 > 0.f ? o2 : (__expf(o2) - 1.0f);
  o3 = o3 > 0.f ? o3 : (__expf(o3) - 1.0f);
  u32* o32 = (u32*)out16;
  o32[(size_t)node * 128 + lane]      = (u32)f2bf_rn(o0) | ((u32)f2bf_rn(o1) << 16);
  o32[(size_t)node * 128 + 64 + lane] = (u32)f2bf_rn(o2) | ((u32)f2bf_rn(o3) << 16);
}

// ---------------- pipelined LDS MFMA GEMM: BM=64, BN=128, BK=64 (3 blocks/CU) ----------------
// Smaller tile -> 48KB LDS -> 3 resident blocks/CU (12 waves/CU, 1.5x streams)
// to raise outstanding-request concurrency (BW was 2.2 TB/s at 2 blocks/CU).
// Same 128B-granule staging, XOR swizzle both sides, T14 issue-early,
// LDS-transposed C write, fused per-head logits.

#define GBM 64
#define GBN 128

__global__ __launch_bounds__(256) void gemm_mfma_kernel(
    const u16* __restrict__ A, const u16* __restrict__ Bt,
    const float* __restrict__ as_, const float* __restrict__ ad_,
    u16* __restrict__ C16, float* __restrict__ als, float* __restrict__ ald, int Mrows) {
  __shared__ __align__(16) u16 smem[24576];   // 48KB: A dbuf @0,8K; B dbuf @16K,32K
  char* base_ = (char*)smem;
  int bc = blockIdx.x, br = blockIdx.y;
  int tid = threadIdx.x;
  int wid = tid >> 6, lane = tid & 63;
  int wr = wid >> 1, wc = wid & 1;             // 2x2 waves; each 32 rows x 64 cols
  int row0 = br * GBM, col0 = bc * GBN;
  int fr = lane & 15, fg = lane >> 4;

  // staging: A 2 passes (64 rows), B 4 passes (128 rows); row=p*32+(t>>3), chunk=t&7
  const u16* agp[2];
  int wofA[2];
  #pragma unroll
  for (int p = 0; p < 2; ++p) {
    int row = p * 32 + (tid >> 3), c = tid & 7;
    int gr = row0 + row; if (gr >= Mrows) gr = Mrows - 1;
    agp[p] = A + (size_t)gr * 256 + c * 8;     // + kt*64 at use
    wofA[p] = row * 128 + ((c ^ (row & 7)) << 4);
  }
  const u16* bgp[4];
  int wofB[4];
  #pragma unroll
  for (int p = 0; p < 4; ++p) {
    int row = p * 32 + (tid >> 3), c = tid & 7;
    bgp[p] = Bt + (size_t)(col0 + row) * 256 + c * 8;
    wofB[p] = row * 128 + ((c ^ (row & 7)) << 4);
  }
  // fragment LDS offsets (chunk = ks*4+fg, XOR row&7)
  int rofA[2][2], rofB[2][4];
  #pragma unroll
  for (int ks = 0; ks < 2; ++ks) {
    #pragma unroll
    for (int m = 0; m < 2; ++m) {
      int rl = wr * 32 + m * 16 + fr;
      rofA[ks][m] = rl * 128 + (((ks * 4 + fg) ^ (rl & 7)) << 4);
    }
    #pragma unroll
    for (int n = 0; n < 4; ++n) {
      int cl_ = wc * 64 + n * 16 + fr;
      rofB[ks][n] = cl_ * 128 + (((ks * 4 + fg) ^ (cl_ & 7)) << 4);
    }
  }

  f32x4 acc[2][4];
  #pragma unroll
  for (int m = 0; m < 2; ++m)
    #pragma unroll
    for (int n = 0; n < 4; ++n) acc[m][n] = (f32x4){0.f, 0.f, 0.f, 0.f};

  uint4 va[2], vb[4];
  #pragma unroll
  for (int p = 0; p < 2; ++p) va[p] = *(const uint4*)agp[p];
  #pragma unroll
  for (int p = 0; p < 4; ++p) vb[p] = *(const uint4*)bgp[p];
  #pragma unroll
  for (int p = 0; p < 2; ++p) *(uint4*)(base_ + wofA[p]) = va[p];
  #pragma unroll
  for (int p = 0; p < 4; ++p) *(uint4*)(base_ + 16384 + wofB[p]) = vb[p];
  __syncthreads();

  #pragma unroll
  for (int kt = 0; kt < 4; ++kt) {             // K = 4 x 64
    int buf = kt & 1;
    if (kt < 3) {                              // T14: issue next-tile loads early
      #pragma unroll
      for (int p = 0; p < 2; ++p) va[p] = *(const uint4*)(agp[p] + (kt + 1) * 64);
      #pragma unroll
      for (int p = 0; p < 4; ++p) vb[p] = *(const uint4*)(bgp[p] + (kt + 1) * 64);
    }
    #pragma unroll
    for (int ks = 0; ks < 2; ++ks) {
      short8 af[2], bf[4];
      #pragma unroll
      for (int m = 0; m < 2; ++m) af[m] = *(const short8*)(base_ + buf * 8192 + rofA[ks][m]);
      #pragma unroll
      for (int n = 0; n < 4; ++n) bf[n] = *(const short8*)(base_ + 16384 + buf * 16384 + rofB[ks][n]);
      #pragma unroll
      for (int m = 0; m < 2; ++m)
        #pragma unroll
        for (int n = 0; n < 4; ++n)
          acc[m][n] = __builtin_amdgcn_mfma_f32_16x16x32_bf16(af[m], bf[n], acc[m][n], 0, 0, 0);
    }
    if (kt < 3) {                              // write next buffer, one barrier
      int nb = buf ^ 1;
      #pragma unroll
      for (int p = 0; p < 2; ++p) *(uint4*)(base_ + nb * 8192 + wofA[p]) = va[p];
      #pragma unroll
      for (int p = 0; p < 4; ++p) *(uint4*)(base_ + 16384 + nb * 16384 + wofB[p]) = vb[p];
      __syncthreads();
    }
  }

  // ---- C write via LDS transpose: [64][128] bf16 = 16KB, contiguous uint4 stores ----
  u16* cl = smem;
  __syncthreads();                             // all frag reads done
  #pragma unroll
  for (int m = 0; m < 2; ++m) {
    #pragma unroll
    for (int n = 0; n < 4; ++n) {
      int c = wc * 64 + n * 16 + fr;
      #pragma unroll
      for (int j = 0; j < 4; ++j) {
        int lr = wr * 32 + m * 16 + fg * 4 + j;
        cl[lr * 128 + c] = f2bf_rn(acc[m][n][j]);
      }
    }
  }
  __syncthreads();
  #pragma unroll
  for (int i = 0; i < 4; ++i) {
    int u = i * 256 + tid;                     // uint4 index within 64x128 tile
    int lr = u >> 4, ch = u & 15;
    int grow = row0 + lr;
    if (grow < Mrows) {
      uint4 v = *(const uint4*)&cl[lr * 128 + ch * 8];
      *(uint4*)&C16[(size_t)grow * 256 + col0 + ch * 8] = v;
    }
  }

  // fused logits: this wave's 64 cols = one head
  int head = bc * 2 + wc;
  float asv[4], adv[4];
  #pragma unroll
  for (int n = 0; n < 4; ++n) {
    asv[n] = as_[head * 64 + n * 16 + fr];
    adv[n] = ad_[head * 64 + n * 16 + fr];
  }
  #pragma unroll
  for (int m = 0; m < 2; ++m) {
    #pragma unroll
    for (int j = 0; j < 4; ++j) {
      float ps = 0.f, pd = 0.f;
      #pragma unroll
      for (int n = 0; n < 4; ++n) {
        ps += acc[m][n][j] * asv[n];
        pd += acc[m][n][j] * adv[n];
      }
      #pragma unroll
      for (int off = 1; off < 16; off <<= 1) {
        ps += __shfl_xor(ps, off, 64);
        pd += __shfl_xor(pd, off, 64);
      }
      int grow = row0 + wr * 32 + m * 16 + fg * 4 + j;
      if (fr == 0 && grow < Mrows) {
        als[grow * 4 + head] = ps;
        ald[grow * 4 + head] = pd;
      }
    }
  }
}

// ---------------- GAT gather v5: fused edge softmax (per-head redundant, no shuffles) ----

__global__ __launch_bounds__(256) void gat_gather_kernel(const u16* __restrict__ h16,
    const float* __restrict__ als, const float* __restrict__ ald,
    const int* __restrict__ rowptr, const int* __restrict__ col,
    const float* __restrict__ bias, u16* __restrict__ out16, int Nn) {
  int node = __builtin_amdgcn_readfirstlane(blockIdx.x * 4 + (threadIdx.x >> 6));
  int lane = threadIdx.x & 63;
  if (node >= Nn) return;
  int rs = rowptr[node], re = rowptr[node + 1];
  int head = lane >> 4;                       // 16 lanes per head
  float adv = ald[(size_t)node * 4 + head];
  float S = 0.f;
  float a0 = 0.f, a1 = 0.f, a2 = 0.f, a3 = 0.f;
  const uint2* h64 = (const uint2*)h16;       // 8B units; row = 64 units
  #pragma unroll 2
  for (int i = rs; i < re; ++i) {
    int s = col[i];
    float e = als[(size_t)s * 4 + head] + adv;
    e = e > 0.f ? e : NEG_SLOPE * e;
    float p = __expf(e);                      // max-free: logits O(1)-bounded
    S += p;
    uint2 pv = h64[(size_t)s * 64 + lane];    // ch 4l..4l+3
    a0 += p * __uint_as_float(pv.x << 16);
    a1 += p * __uint_as_float(pv.x & 0xffff0000u);
    a2 += p * __uint_as_float(pv.y << 16);
    a3 += p * __uint_as_float(pv.y & 0xffff0000u);
  }
  float iS = 1.f / (S + 1e-16f);
  float4 bv = *(const float4*)&bias[4 * lane];
  float o0 = a0 * iS + bv.x;
  float o1 = a1 * iS + bv.y;
  float o2 = a2 * iS + bv.z;
  float o3 = a3 * iS + bv.w;
  o0 = o0 > 0.f ? o0 : (__expf(o0) - 1.0f);   // ELU (alpha=1)
  o1 = o1 > 0.f ? o1 : (__expf(o1) - 1.0f);
  o2 = o2 > 0.f ? o2 : (__expf(o2) - 1.0f);
  o3 = o3 > 0.f ? o3 : (__expf(o3) - 1.0f);
  uint2 ov;
  ov.x = (u32)f2bf_rn(o0) | ((u32)f2bf_rn(o1) << 16);
  ov.y = (u32)f2bf_rn(o2) | ((u32)f2bf_rn(o3) << 16);
  ((uint2*)out16)[(size_t)node * 64 + lane] = ov;
}

// ---------------- pooling + MLP ----------------

__global__ void bounds_kernel(const int* __restrict__ batch, int Nn, int* __restrict__ bounds) {
  int g = threadIdx.x;
  if (g > GG) return;
  int lo = 0, hi = Nn;
  while (lo < hi) { int mid = (lo + hi) >> 1; if (batch[mid] < g) lo = mid + 1; else hi = mid; }
  bounds[g] = lo;   // lower_bound of g; bounds[64] = N
}

__global__ __launch_bounds__(64) void pool_kernel(const u16* __restrict__ X,
    const int* __restrict__ bounds, float* __restrict__ pooled) {
  int g = blockIdx.x, split = blockIdx.y;
  int lane = threadIdx.x;                     // 64
  int s = bounds[g], e = bounds[g + 1];
  int cnt = e - s;
  if (cnt <= 0) return;
  int chunk = (cnt + gridDim.y - 1) / gridDim.y;
  int s2 = s + split * chunk, e2 = min(e, s2 + chunk);
  if (s2 >= e2) return;
  int r = lane >> 5, c = lane & 31;           // row parity, 16B chunk
  float acc[8] = {};
  for (int n = s2 + r; n < e2; n += 2) {
    uint4 v = *(const uint4*)&X[(size_t)n * HC + c * 8];
    acc[0] += __uint_as_float(v.x << 16);
    acc[1] += __uint_as_float(v.x & 0xffff0000u);
    acc[2] += __uint_as_float(v.y << 16);
    acc[3] += __uint_as_float(v.y & 0xffff0000u);
    acc[4] += __uint_as_float(v.z << 16);
    acc[5] += __uint_as_float(v.z & 0xffff0000u);
    acc[6] += __uint_as_float(v.w << 16);
    acc[7] += __uint_as_float(v.w & 0xffff0000u);
  }
  #pragma unroll
  for (int j = 0; j < 8; ++j) acc[j] += __shfl_xor(acc[j], 32, 64);
  if (r == 0) {
    #pragma unroll
    for (int j = 0; j < 8; ++j) atomicAdd(&pooled[g * HC + c * 8 + j], acc[j]);
  }
}

__global__ __launch_bounds__(512) void mlp_kernel(const float* __restrict__ pooled,
    const int* __restrict__ bounds, const float* __restrict__ Wp1, const float* __restrict__ bp1,
    const float* __restrict__ Wp2, const float* __restrict__ bp2, float* __restrict__ out) {
  __shared__ float p[256];
  __shared__ float z1[512];
  int g = blockIdx.x, t = threadIdx.x;
  if (t < 256) {
    int cnt = bounds[g + 1] - bounds[g];
    float inv = 1.0f / (float)(cnt > 1 ? cnt : 1);
    p[t] = pooled[g * 256 + t] * inv;
  }
  __syncthreads();
  float a1 = bp1[t];
  for (int k = 0; k < 256; ++k) a1 += p[k] * Wp1[k * 512 + t];
  z1[t] = fmaxf(a1, 0.f);
  __syncthreads();
  if (t < 256) {
    float a2 = bp2[t];
    for (int k = 0; k < 512; ++k) a2 += z1[k] * Wp2[k * 256 + t];
    out[g * 256 + t] = a2;
  }
}

// ---------------- launch ----------------

static inline size_t align_up(size_t x, size_t a) { return (x + a - 1) & ~(a - 1); }

extern "C" void kernel_launch(void* const* d_in, const int* in_sizes, int n_in,
                              void* d_out, int out_size, void* d_ws, size_t ws_size,
                              hipStream_t stream) {
  const float* x    = (const float*)d_in[0];
  const int*   ei   = (const int*)d_in[1];
  const int*   batch= (const int*)d_in[2];
  const float* W1   = (const float*)d_in[3];
  const float* a1s  = (const float*)d_in[4];
  const float* a1d  = (const float*)d_in[5];
  const float* b1   = (const float*)d_in[6];
  const float* W2   = (const float*)d_in[7];
  const float* a2s  = (const float*)d_in[8];
  const float* a2d  = (const float*)d_in[9];
  const float* b2   = (const float*)d_in[10];
  const float* W3   = (const float*)d_in[11];
  const float* a3s  = (const float*)d_in[12];
  const float* a3d  = (const float*)d_in[13];
  const float* b3   = (const float*)d_in[14];
  const float* Wp1  = (const float*)d_in[15];
  const float* bp1  = (const float*)d_in[16];
  const float* Wp2  = (const float*)d_in[17];
  const float* bp2  = (const float*)d_in[18];

  const int N = in_sizes[0] / 2;       // 100000
  const int E = in_sizes[1] / 2;       // 400000
  const int Et = E + N;                // with self loops

  char* base = (char*)d_ws;
  size_t off = 0;
  auto alloc = [&](size_t bytes) { size_t o = off; off = align_up(off + bytes, 256); return o; };
  u16*   h16    = (u16*)  (base + alloc((size_t)N * HC * 2));   // message-path h (bf16)
  u16*   xhi    = (u16*)  (base + alloc((size_t)N * HC * 2));   // gather out (bf16)
  float* als    = (float*)(base + alloc((size_t)N * 4 * 4));
  float* ald    = (float*)(base + alloc((size_t)N * 4 * 4));
  float* xbar   = (float*)(base + alloc((size_t)N * 8 * 4));    // layer-1 x-space gather
  float* vabuf  = (float*)(base + alloc(16 * 4));
  int*   rowptr = (int*)  (base + alloc((size_t)(N + 1) * 4));
  int*   col    = (int*)  (base + alloc((size_t)Et * 4));
  int*   deg    = (int*)  (base + alloc((size_t)N * 4));
  int*   cursor = (int*)  (base + alloc((size_t)N * 4));
  int*   bsum   = (int*)  (base + alloc(512 * 4));
  int*   bounds = (int*)  (base + alloc((GG + 1) * 4));
  float* pooled = (float*)(base + alloc((size_t)GG * HC * 4));
  (void)ws_size; (void)n_in; (void)out_size;

  // W2t/W3t (bf16, 128KB each) parked in deg/cursor space (dead after CSR build)
  u16* W2t = (u16*)deg;
  u16* W3t = (u16*)cursor;

  hipMemsetAsync(deg, 0, (size_t)N * 4, stream);
  hipMemsetAsync(cursor, 0, (size_t)N * 4, stream);
  hipMemsetAsync(pooled, 0, (size_t)GG * HC * 4, stream);

  // CSR by destination (same edge set for all layers)
  int ebk = (Et + 255) / 256;
  count_deg_kernel<<<ebk, 256, 0, stream>>>(ei, E, N, deg);
  int NT = (N + 255) / 256;
  scan_partial_kernel<<<NT, 256, 0, stream>>>(deg, N, rowptr, bsum);
  scan_bsum_kernel<<<1, 512, 0, stream>>>(bsum, NT);
  scan_add_kernel<<<NT, 256, 0, stream>>>(rowptr, bsum, N, Et);
  fill_csr_kernel<<<ebk, 256, 0, stream>>>(ei, E, N, rowptr, cursor, col);

  // weight conversion (deg/cursor now dead)
  convert_w_kernel<<<256, 256, 0, stream>>>(W2, W2t);
  convert_w_kernel<<<256, 256, 0, stream>>>(W3, W3t);

  dim3 gemm_grid(HC / GBN, (N + GBM - 1) / GBM);
  int nodeblk = (N + 3) / 4;

  // layer 1 — rank-2 factorization: everything in x-space, then one expand
  prep_va_kernel<<<1, 256, 0, stream>>>(W1, a1s, a1d, vabuf);
  logits1_kernel<<<NT, 256, 0, stream>>>(x, vabuf, als, ald, N);
  sm_gather1_kernel<<<NT, 256, 0, stream>>>(x, als, ald, rowptr, col, xbar, N);
  expand1_kernel<<<nodeblk, 256, 0, stream>>>(xbar, W1, b1, xhi, N);
  // layer 2 (edge softmax fused into gather)
  gemm_mfma_kernel<<<gemm_grid, 256, 0, stream>>>(xhi, W2t, a2s, a2d, h16, als, ald, N);
  gat_gather_kernel<<<nodeblk, 256, 0, stream>>>(h16, als, ald, rowptr, col, b2, xhi, N);
  // layer 3
  gemm_mfma_kernel<<<gemm_grid, 256, 0, stream>>>(xhi, W3t, a3s, a3d, h16, als, ald, N);
  gat_gather_kernel<<<nodeblk, 256, 0, stream>>>(h16, als, ald, rowptr, col, b3, xhi, N);

  // pool + MLP
  bounds_kernel<<<1, 128, 0, stream>>>(batch, N, bounds);
  pool_kernel<<<dim3(GG, 32), 64, 0, stream>>>(xhi, bounds, pooled);
  mlp_kernel<<<GG, 512, 0, stream>>>(pooled, bounds, Wp1, bp1, Wp2, bp2, (float*)d_out);
}

// Round 18
// 321.738 us; speedup vs baseline: 1.2012x; 1.0562x over previous
//
#include <hip/hip_runtime.h>
#include <math.h>

#define HC 256      // H*C
#define NHEAD 4
#define NEG_SLOPE 0.2f
#define GG 64       // graphs

typedef unsigned short u16;
typedef unsigned int u32;
typedef __attribute__((ext_vector_type(8))) short short8;
typedef __attribute__((ext_vector_type(4))) float f32x4;

static __device__ inline u16 f2bf_rn(float f) {
  u32 x = __float_as_uint(f);
  u32 r = (x + 0x7fffu + ((x >> 16) & 1u)) >> 16;
  return (u16)r;
}
static __device__ inline float bf2f(u16 u) { return __uint_as_float(((u32)u) << 16); }

// ---------------- CSR build ----------------

__global__ void count_deg_kernel(const int* __restrict__ ei, int E, int Nn, int* __restrict__ deg) {
  int idx = blockIdx.x * 256 + threadIdx.x;
  int Et = E + Nn;
  if (idx >= Et) return;
  int d = (idx < E) ? ei[E + idx] : (idx - E);   // row1 of edge_index = dst; self loops appended
  atomicAdd(&deg[d], 1);
}

__global__ void scan_partial_kernel(const int* __restrict__ deg, int Nn,
                                    int* __restrict__ rowptr, int* __restrict__ bsum) {
  __shared__ int s[256];
  int t = threadIdx.x, i = blockIdx.x * 256 + t;
  int v = (i < Nn) ? deg[i] : 0;
  s[t] = v; __syncthreads();
  for (int off = 1; off < 256; off <<= 1) {
    int x = (t >= off) ? s[t - off] : 0; __syncthreads();
    s[t] += x; __syncthreads();
  }
  if (i < Nn) rowptr[i] = s[t] - v;          // exclusive within block
  if (t == 255) bsum[blockIdx.x] = s[t];     // block total
}

__global__ void scan_bsum_kernel(int* __restrict__ bsum, int nb) {
  __shared__ int s[512];
  int t = threadIdx.x;
  int v = (t < nb) ? bsum[t] : 0;
  s[t] = v; __syncthreads();
  for (int off = 1; off < 512; off <<= 1) {
    int x = (t >= off) ? s[t - off] : 0; __syncthreads();
    s[t] += x; __syncthreads();
  }
  if (t < nb) bsum[t] = s[t] - v;            // exclusive block offsets
}

__global__ void scan_add_kernel(int* __restrict__ rowptr, const int* __restrict__ bsum,
                                int Nn, int Etot) {
  int i = blockIdx.x * 256 + threadIdx.x;
  if (i < Nn) rowptr[i] += bsum[blockIdx.x];
  if (i == 0) rowptr[Nn] = Etot;
}

__global__ void fill_csr_kernel(const int* __restrict__ ei, int E, int Nn,
                                const int* __restrict__ rowptr, int* __restrict__ cursor,
                                int* __restrict__ col) {
  int idx = blockIdx.x * 256 + threadIdx.x;
  int Et = E + Nn;
  if (idx >= Et) return;
  int s, d;
  if (idx < E) { s = ei[idx]; d = ei[E + idx]; } else { s = d = idx - E; }
  int pos = atomicAdd(&cursor[d], 1);
  col[rowptr[d] + pos] = s;
}

// ---------------- merged prep: W2/W3 transpose+bf16, graph bounds ----------------
// blocks 0..255: W2t; 256..511: W3t; block 512: bounds binary search.

__global__ void prep_misc_kernel(const float* __restrict__ W2, const float* __restrict__ W3,
                                 u16* __restrict__ W2t, u16* __restrict__ W3t,
                                 const int* __restrict__ batch, int Nn, int* __restrict__ bounds) {
  int b = blockIdx.x;
  if (b < 512) {
    const float* W = (b < 256) ? W2 : W3;
    u16* dst = (b < 256) ? W2t : W3t;
    int idx = (b & 255) * 256 + threadIdx.x;
    int k = idx >> 8, n = idx & 255;           // coalesced read of W[k][n]
    dst[n * 256 + k] = f2bf_rn(W[idx]);
  } else {
    int g = threadIdx.x;
    if (g > GG) return;
    int lo = 0, hi = Nn;
    while (lo < hi) { int mid = (lo + hi) >> 1; if (batch[mid] < g) lo = mid + 1; else hi = mid; }
    bounds[g] = lo;                            // lower_bound of g; bounds[64] = N
  }
}

// ---------------- layer 1: fused va + logits + max-free softmax + x-space gather ----------
// va recomputed per block (wave q = head q: channels q*64..q*64+63), LDS broadcast.
// Per edge: load x[s] (8B) only; als_s computed inline (2 FMA/head).

__global__ __launch_bounds__(256) void l1_fused_kernel(const float* __restrict__ x,
    const float* __restrict__ W1, const float* __restrict__ a1s, const float* __restrict__ a1d,
    const int* __restrict__ rowptr, const int* __restrict__ col,
    float* __restrict__ xbar, int Nn) {
  __shared__ float va[16];
  int t = threadIdx.x, q = t >> 6, lane = t & 63;
  {
    float asv = a1s[t], adv = a1d[t];
    float w0 = W1[t], w1 = W1[256 + t];
    float s0 = w0 * asv, s1 = w1 * asv, d0 = w0 * adv, d1 = w1 * adv;
    #pragma unroll
    for (int off = 32; off >= 1; off >>= 1) {
      s0 += __shfl_xor(s0, off, 64); s1 += __shfl_xor(s1, off, 64);
      d0 += __shfl_xor(d0, off, 64); d1 += __shfl_xor(d1, off, 64);
    }
    if (lane == 0) { va[q] = s0; va[4 + q] = s1; va[8 + q] = d0; va[12 + q] = d1; }
  }
  __syncthreads();
  int node = blockIdx.x * 256 + t;
  if (node >= Nn) return;
  float4 vs0 = *(const float4*)&va[0], vs1 = *(const float4*)&va[4];
  float4 vd0 = *(const float4*)&va[8], vd1 = *(const float4*)&va[12];
  float2 xv = *(const float2*)&x[(size_t)node * 2];
  float ad0 = xv.x * vd0.x + xv.y * vd1.x;
  float ad1 = xv.x * vd0.y + xv.y * vd1.y;
  float ad2 = xv.x * vd0.z + xv.y * vd1.z;
  float ad3 = xv.x * vd0.w + xv.y * vd1.w;
  int rs = rowptr[node], re = rowptr[node + 1];
  float S0 = 0.f, S1 = 0.f, S2 = 0.f, S3 = 0.f;
  float a0 = 0.f, a1 = 0.f, a2 = 0.f, a3 = 0.f, a4 = 0.f, a5 = 0.f, a6 = 0.f, a7 = 0.f;
  for (int i = rs; i < re; ++i) {
    int s = col[i];
    float2 xs = *(const float2*)&x[(size_t)s * 2];
    float e0 = xs.x * vs0.x + xs.y * vs1.x + ad0; e0 = e0 > 0.f ? e0 : NEG_SLOPE * e0;
    float e1 = xs.x * vs0.y + xs.y * vs1.y + ad1; e1 = e1 > 0.f ? e1 : NEG_SLOPE * e1;
    float e2 = xs.x * vs0.z + xs.y * vs1.z + ad2; e2 = e2 > 0.f ? e2 : NEG_SLOPE * e2;
    float e3 = xs.x * vs0.w + xs.y * vs1.w + ad3; e3 = e3 > 0.f ? e3 : NEG_SLOPE * e3;
    float p0 = __expf(e0), p1 = __expf(e1), p2 = __expf(e2), p3 = __expf(e3);
    S0 += p0; S1 += p1; S2 += p2; S3 += p3;
    a0 += p0 * xs.x; a1 += p0 * xs.y;
    a2 += p1 * xs.x; a3 += p1 * xs.y;
    a4 += p2 * xs.x; a5 += p2 * xs.y;
    a6 += p3 * xs.x; a7 += p3 * xs.y;
  }
  float i0 = 1.f / (S0 + 1e-16f), i1 = 1.f / (S1 + 1e-16f);
  float i2 = 1.f / (S2 + 1e-16f), i3 = 1.f / (S3 + 1e-16f);
  *(float4*)&xbar[(size_t)node * 8]     = make_float4(a0 * i0, a1 * i0, a2 * i1, a3 * i1);
  *(float4*)&xbar[(size_t)node * 8 + 4] = make_float4(a4 * i2, a5 * i2, a6 * i3, a7 * i3);
}

// expand: out1[node][c] = xbar_q . W1[:,c] + b1[c], ELU, bf16-packed
__global__ __launch_bounds__(256) void expand1_kernel(const float* __restrict__ xbar,
    const float* __restrict__ W1, const float* __restrict__ b1,
    u16* __restrict__ out16, int Nn) {
  int node = blockIdx.x * 4 + (threadIdx.x >> 6);
  int lane = threadIdx.x & 63;
  if (node >= Nn) return;
  int hA = lane >> 5;                        // head of ch pair A (0/1); pair B head = 2+hA
  float4 xb0 = *(const float4*)&xbar[(size_t)node * 8];      // heads 0,1
  float4 xb1 = *(const float4*)&xbar[(size_t)node * 8 + 4];  // heads 2,3
  float xA0 = hA ? xb0.z : xb0.x, xA1 = hA ? xb0.w : xb0.y;
  float xB0 = hA ? xb1.z : xb1.x, xB1 = hA ? xb1.w : xb1.y;
  int cA = 2 * lane, cB = 128 + 2 * lane;
  float2 wA0 = *(const float2*)&W1[cA], wA1 = *(const float2*)&W1[256 + cA];
  float2 wB0 = *(const float2*)&W1[cB], wB1 = *(const float2*)&W1[256 + cB];
  float2 bA = *(const float2*)&b1[cA],  bB = *(const float2*)&b1[cB];
  float o0 = xA0 * wA0.x + xA1 * wA1.x + bA.x;
  float o1 = xA0 * wA0.y + xA1 * wA1.y + bA.y;
  float o2 = xB0 * wB0.x + xB1 * wB1.x + bB.x;
  float o3 = xB0 * wB0.y + xB1 * wB1.y + bB.y;
  o0 = o0 > 0.f ? o0 : (__expf(o0) - 1.0f);
  o1 = o1 > 0.f ? o1 : (__expf(o1) - 1.0f);
  o2 = o2 > 0.f ? o2 : (__expf(o2) - 1.0f);
  o3 = o3 > 0.f ? o3 : (__expf(o3) - 1.0f);
  u32* o32 = (u32*)out16;
  o32[(size_t)node * 128 + lane]      = (u32)f2bf_rn(o0) | ((u32)f2bf_rn(o1) << 16);
  o32[(size_t)node * 128 + 64 + lane] = (u32)f2bf_rn(o2) | ((u32)f2bf_rn(o3) << 16);
}

// ---------------- pipelined LDS MFMA GEMM: BM=64, BN=128, BK=64 (3 blocks/CU) ----------------

#define GBM 64
#define GBN 128

__global__ __launch_bounds__(256) void gemm_mfma_kernel(
    const u16* __restrict__ A, const u16* __restrict__ Bt,
    const float* __restrict__ as_, const float* __restrict__ ad_,
    u16* __restrict__ C16, float* __restrict__ als, float* __restrict__ ald, int Mrows) {
  __shared__ __align__(16) u16 smem[24576];   // 48KB: A dbuf @0,8K; B dbuf @16K,32K
  char* base_ = (char*)smem;
  int bc = blockIdx.x, br = blockIdx.y;
  int tid = threadIdx.x;
  int wid = tid >> 6, lane = tid & 63;
  int wr = wid >> 1, wc = wid & 1;             // 2x2 waves; each 32 rows x 64 cols
  int row0 = br * GBM, col0 = bc * GBN;
  int fr = lane & 15, fg = lane >> 4;

  const u16* agp[2];
  int wofA[2];
  #pragma unroll
  for (int p = 0; p < 2; ++p) {
    int row = p * 32 + (tid >> 3), c = tid & 7;
    int gr = row0 + row; if (gr >= Mrows) gr = Mrows - 1;
    agp[p] = A + (size_t)gr * 256 + c * 8;     // + kt*64 at use
    wofA[p] = row * 128 + ((c ^ (row & 7)) << 4);
  }
  const u16* bgp[4];
  int wofB[4];
  #pragma unroll
  for (int p = 0; p < 4; ++p) {
    int row = p * 32 + (tid >> 3), c = tid & 7;
    bgp[p] = Bt + (size_t)(col0 + row) * 256 + c * 8;
    wofB[p] = row * 128 + ((c ^ (row & 7)) << 4);
  }
  int rofA[2][2], rofB[2][4];
  #pragma unroll
  for (int ks = 0; ks < 2; ++ks) {
    #pragma unroll
    for (int m = 0; m < 2; ++m) {
      int rl = wr * 32 + m * 16 + fr;
      rofA[ks][m] = rl * 128 + (((ks * 4 + fg) ^ (rl & 7)) << 4);
    }
    #pragma unroll
    for (int n = 0; n < 4; ++n) {
      int cl_ = wc * 64 + n * 16 + fr;
      rofB[ks][n] = cl_ * 128 + (((ks * 4 + fg) ^ (cl_ & 7)) << 4);
    }
  }

  f32x4 acc[2][4];
  #pragma unroll
  for (int m = 0; m < 2; ++m)
    #pragma unroll
    for (int n = 0; n < 4; ++n) acc[m][n] = (f32x4){0.f, 0.f, 0.f, 0.f};

  uint4 va[2], vb[4];
  #pragma unroll
  for (int p = 0; p < 2; ++p) va[p] = *(const uint4*)agp[p];
  #pragma unroll
  for (int p = 0; p < 4; ++p) vb[p] = *(const uint4*)bgp[p];
  #pragma unroll
  for (int p = 0; p < 2; ++p) *(uint4*)(base_ + wofA[p]) = va[p];
  #pragma unroll
  for (int p = 0; p < 4; ++p) *(uint4*)(base_ + 16384 + wofB[p]) = vb[p];
  __syncthreads();

  #pragma unroll
  for (int kt = 0; kt < 4; ++kt) {             // K = 4 x 64
    int buf = kt & 1;
    if (kt < 3) {                              // T14: issue next-tile loads early
      #pragma unroll
      for (int p = 0; p < 2; ++p) va[p] = *(const uint4*)(agp[p] + (kt + 1) * 64);
      #pragma unroll
      for (int p = 0; p < 4; ++p) vb[p] = *(const uint4*)(bgp[p] + (kt + 1) * 64);
    }
    #pragma unroll
    for (int ks = 0; ks < 2; ++ks) {
      short8 af[2], bf[4];
      #pragma unroll
      for (int m = 0; m < 2; ++m) af[m] = *(const short8*)(base_ + buf * 8192 + rofA[ks][m]);
      #pragma unroll
      for (int n = 0; n < 4; ++n) bf[n] = *(const short8*)(base_ + 16384 + buf * 16384 + rofB[ks][n]);
      #pragma unroll
      for (int m = 0; m < 2; ++m)
        #pragma unroll
        for (int n = 0; n < 4; ++n)
          acc[m][n] = __builtin_amdgcn_mfma_f32_16x16x32_bf16(af[m], bf[n], acc[m][n], 0, 0, 0);
    }
    if (kt < 3) {                              // write next buffer, one barrier
      int nb = buf ^ 1;
      #pragma unroll
      for (int p = 0; p < 2; ++p) *(uint4*)(base_ + nb * 8192 + wofA[p]) = va[p];
      #pragma unroll
      for (int p = 0; p < 4; ++p) *(uint4*)(base_ + 16384 + nb * 16384 + wofB[p]) = vb[p];
      __syncthreads();
    }
  }

  // ---- C write via LDS transpose: [64][128] bf16 = 16KB, contiguous uint4 stores ----
  u16* cl = smem;
  __syncthreads();                             // all frag reads done
  #pragma unroll
  for (int m = 0; m < 2; ++m) {
    #pragma unroll
    for (int n = 0; n < 4; ++n) {
      int c = wc * 64 + n * 16 + fr;
      #pragma unroll
      for (int j = 0; j < 4; ++j) {
        int lr = wr * 32 + m * 16 + fg * 4 + j;
        cl[lr * 128 + c] = f2bf_rn(acc[m][n][j]);
      }
    }
  }
  __syncthreads();
  #pragma unroll
  for (int i = 0; i < 4; ++i) {
    int u = i * 256 + tid;                     // uint4 index within 64x128 tile
    int lr = u >> 4, ch = u & 15;
    int grow = row0 + lr;
    if (grow < Mrows) {
      uint4 v = *(const uint4*)&cl[lr * 128 + ch * 8];
      *(uint4*)&C16[(size_t)grow * 256 + col0 + ch * 8] = v;
    }
  }

  // fused logits: this wave's 64 cols = one head
  int head = bc * 2 + wc;
  float asv[4], adv[4];
  #pragma unroll
  for (int n = 0; n < 4; ++n) {
    asv[n] = as_[head * 64 + n * 16 + fr];
    adv[n] = ad_[head * 64 + n * 16 + fr];
  }
  #pragma unroll
  for (int m = 0; m < 2; ++m) {
    #pragma unroll
    for (int j = 0; j < 4; ++j) {
      float ps = 0.f, pd = 0.f;
      #pragma unroll
      for (int n = 0; n < 4; ++n) {
        ps += acc[m][n][j] * asv[n];
        pd += acc[m][n][j] * adv[n];
      }
      #pragma unroll
      for (int off = 1; off < 16; off <<= 1) {
        ps += __shfl_xor(ps, off, 64);
        pd += __shfl_xor(pd, off, 64);
      }
      int grow = row0 + wr * 32 + m * 16 + fg * 4 + j;
      if (fr == 0 && grow < Mrows) {
        als[grow * 4 + head] = ps;
        ald[grow * 4 + head] = pd;
      }
    }
  }
}

// ---------------- GAT gather v5: fused edge softmax (per-head redundant, no shuffles) ----

__global__ __launch_bounds__(256) void gat_gather_kernel(const u16* __restrict__ h16,
    const float* __restrict__ als, const float* __restrict__ ald,
    const int* __restrict__ rowptr, const int* __restrict__ col,
    const float* __restrict__ bias, u16* __restrict__ out16, int Nn) {
  int node = __builtin_amdgcn_readfirstlane(blockIdx.x * 4 + (threadIdx.x >> 6));
  int lane = threadIdx.x & 63;
  if (node >= Nn) return;
  int rs = rowptr[node], re = rowptr[node + 1];
  int head = lane >> 4;                       // 16 lanes per head
  float adv = ald[(size_t)node * 4 + head];
  float S = 0.f;
  float a0 = 0.f, a1 = 0.f, a2 = 0.f, a3 = 0.f;
  const uint2* h64 = (const uint2*)h16;       // 8B units; row = 64 units
  #pragma unroll 4
  for (int i = rs; i < re; ++i) {
    int s = col[i];
    float e = als[(size_t)s * 4 + head] + adv;
    e = e > 0.f ? e : NEG_SLOPE * e;
    float p = __expf(e);                      // max-free: logits O(1)-bounded
    S += p;
    uint2 pv = h64[(size_t)s * 64 + lane];    // ch 4l..4l+3
    a0 += p * __uint_as_float(pv.x << 16);
    a1 += p * __uint_as_float(pv.x & 0xffff0000u);
    a2 += p * __uint_as_float(pv.y << 16);
    a3 += p * __uint_as_float(pv.y & 0xffff0000u);
  }
  float iS = 1.f / (S + 1e-16f);
  float4 bv = *(const float4*)&bias[4 * lane];
  float o0 = a0 * iS + bv.x;
  float o1 = a1 * iS + bv.y;
  float o2 = a2 * iS + bv.z;
  float o3 = a3 * iS + bv.w;
  o0 = o0 > 0.f ? o0 : (__expf(o0) - 1.0f);   // ELU (alpha=1)
  o1 = o1 > 0.f ? o1 : (__expf(o1) - 1.0f);
  o2 = o2 > 0.f ? o2 : (__expf(o2) - 1.0f);
  o3 = o3 > 0.f ? o3 : (__expf(o3) - 1.0f);
  uint2 ov;
  ov.x = (u32)f2bf_rn(o0) | ((u32)f2bf_rn(o1) << 16);
  ov.y = (u32)f2bf_rn(o2) | ((u32)f2bf_rn(o3) << 16);
  ((uint2*)out16)[(size_t)node * 64 + lane] = ov;
}

// ---------------- pooling + MLP ----------------

__global__ __launch_bounds__(64) void pool_kernel(const u16* __restrict__ X,
    const int* __restrict__ bounds, float* __restrict__ pooled) {
  int g = blockIdx.x, split = blockIdx.y;
  int lane = threadIdx.x;                     // 64
  int s = bounds[g], e = bounds[g + 1];
  int cnt = e - s;
  if (cnt <= 0) return;
  int chunk = (cnt + gridDim.y - 1) / gridDim.y;
  int s2 = s + split * chunk, e2 = min(e, s2 + chunk);
  if (s2 >= e2) return;
  int r = lane >> 5, c = lane & 31;           // row parity, 16B chunk
  float acc[8] = {};
  for (int n = s2 + r; n < e2; n += 2) {
    uint4 v = *(const uint4*)&X[(size_t)n * HC + c * 8];
    acc[0] += __uint_as_float(v.x << 16);
    acc[1] += __uint_as_float(v.x & 0xffff0000u);
    acc[2] += __uint_as_float(v.y << 16);
    acc[3] += __uint_as_float(v.y & 0xffff0000u);
    acc[4] += __uint_as_float(v.z << 16);
    acc[5] += __uint_as_float(v.z & 0xffff0000u);
    acc[6] += __uint_as_float(v.w << 16);
    acc[7] += __uint_as_float(v.w & 0xffff0000u);
  }
  #pragma unroll
  for (int j = 0; j < 8; ++j) acc[j] += __shfl_xor(acc[j], 32, 64);
  if (r == 0) {
    #pragma unroll
    for (int j = 0; j < 8; ++j) atomicAdd(&pooled[g * HC + c * 8 + j], acc[j]);
  }
}

__global__ __launch_bounds__(512) void mlp_kernel(const float* __restrict__ pooled,
    const int* __restrict__ bounds, const float* __restrict__ Wp1, const float* __restrict__ bp1,
    const float* __restrict__ Wp2, const float* __restrict__ bp2, float* __restrict__ out) {
  __shared__ float p[256];
  __shared__ float z1[512];
  int g = blockIdx.x, t = threadIdx.x;
  if (t < 256) {
    int cnt = bounds[g + 1] - bounds[g];
    float inv = 1.0f / (float)(cnt > 1 ? cnt : 1);
    p[t] = pooled[g * 256 + t] * inv;
  }
  __syncthreads();
  float a1 = bp1[t];
  for (int k = 0; k < 256; ++k) a1 += p[k] * Wp1[k * 512 + t];
  z1[t] = fmaxf(a1, 0.f);
  __syncthreads();
  if (t < 256) {
    float a2 = bp2[t];
    for (int k = 0; k < 512; ++k) a2 += z1[k] * Wp2[k * 256 + t];
    out[g * 256 + t] = a2;
  }
}

// ---------------- launch ----------------

static inline size_t align_up(size_t x, size_t a) { return (x + a - 1) & ~(a - 1); }

extern "C" void kernel_launch(void* const* d_in, const int* in_sizes, int n_in,
                              void* d_out, int out_size, void* d_ws, size_t ws_size,
                              hipStream_t stream) {
  const float* x    = (const float*)d_in[0];
  const int*   ei   = (const int*)d_in[1];
  const int*   batch= (const int*)d_in[2];
  const float* W1   = (const float*)d_in[3];
  const float* a1s  = (const float*)d_in[4];
  const float* a1d  = (const float*)d_in[5];
  const float* b1   = (const float*)d_in[6];
  const float* W2   = (const float*)d_in[7];
  const float* a2s  = (const float*)d_in[8];
  const float* a2d  = (const float*)d_in[9];
  const float* b2   = (const float*)d_in[10];
  const float* W3   = (const float*)d_in[11];
  const float* a3s  = (const float*)d_in[12];
  const float* a3d  = (const float*)d_in[13];
  const float* b3   = (const float*)d_in[14];
  const float* Wp1  = (const float*)d_in[15];
  const float* bp1  = (const float*)d_in[16];
  const float* Wp2  = (const float*)d_in[17];
  const float* bp2  = (const float*)d_in[18];

  const int N = in_sizes[0] / 2;       // 100000
  const int E = in_sizes[1] / 2;       // 400000
  const int Et = E + N;                // with self loops

  char* base = (char*)d_ws;
  size_t off = 0;
  auto alloc = [&](size_t bytes) { size_t o = off; off = align_up(off + bytes, 256); return o; };
  u16*   h16    = (u16*)  (base + alloc((size_t)N * HC * 2));   // message-path h (bf16)
  u16*   xhi    = (u16*)  (base + alloc((size_t)N * HC * 2));   // gather out (bf16)
  float* als    = (float*)(base + alloc((size_t)N * 4 * 4));
  float* ald    = (float*)(base + alloc((size_t)N * 4 * 4));
  float* xbar   = (float*)(base + alloc((size_t)N * 8 * 4));    // layer-1 x-space gather
  int*   rowptr = (int*)  (base + alloc((size_t)(N + 1) * 4));
  int*   col    = (int*)  (base + alloc((size_t)Et * 4));
  // deg, cursor, pooled contiguous -> one memset clears all three
  size_t zoff0 = off;
  int*   deg    = (int*)  (base + alloc((size_t)N * 4));
  int*   cursor = (int*)  (base + alloc((size_t)N * 4));
  float* pooled = (float*)(base + alloc((size_t)GG * HC * 4));
  size_t zbytes = off - zoff0;
  int*   bsum   = (int*)  (base + alloc(512 * 4));
  int*   bounds = (int*)  (base + alloc((GG + 1) * 4));
  (void)ws_size; (void)n_in; (void)out_size;

  // W2t/W3t (bf16, 128KB each) parked in deg/cursor space (dead after CSR build)
  u16* W2t = (u16*)deg;
  u16* W3t = (u16*)cursor;

  hipMemsetAsync(base + zoff0, 0, zbytes, stream);   // deg + cursor + pooled

  // CSR by destination (same edge set for all layers)
  int ebk = (Et + 255) / 256;
  count_deg_kernel<<<ebk, 256, 0, stream>>>(ei, E, N, deg);
  int NT = (N + 255) / 256;
  scan_partial_kernel<<<NT, 256, 0, stream>>>(deg, N, rowptr, bsum);
  scan_bsum_kernel<<<1, 512, 0, stream>>>(bsum, NT);
  scan_add_kernel<<<NT, 256, 0, stream>>>(rowptr, bsum, N, Et);
  fill_csr_kernel<<<ebk, 256, 0, stream>>>(ei, E, N, rowptr, cursor, col);

  // merged: W conversions (deg/cursor now dead) + graph bounds
  prep_misc_kernel<<<513, 256, 0, stream>>>(W2, W3, W2t, W3t, batch, N, bounds);

  dim3 gemm_grid(HC / GBN, (N + GBM - 1) / GBM);
  int nodeblk = (N + 3) / 4;

  // layer 1 — fused rank-2 path: va+logits+softmax+x-gather in one kernel, then expand
  l1_fused_kernel<<<NT, 256, 0, stream>>>(x, W1, a1s, a1d, rowptr, col, xbar, N);
  expand1_kernel<<<nodeblk, 256, 0, stream>>>(xbar, W1, b1, xhi, N);
  // layer 2 (edge softmax fused into gather)
  gemm_mfma_kernel<<<gemm_grid, 256, 0, stream>>>(xhi, W2t, a2s, a2d, h16, als, ald, N);
  gat_gather_kernel<<<nodeblk, 256, 0, stream>>>(h16, als, ald, rowptr, col, b2, xhi, N);
  // layer 3
  gemm_mfma_kernel<<<gemm_grid, 256, 0, stream>>>(xhi, W3t, a3s, a3d, h16, als, ald, N);
  gat_gather_kernel<<<nodeblk, 256, 0, stream>>>(h16, als, ald, rowptr, col, b3, xhi, N);

  // pool + MLP
  pool_kernel<<<dim3(GG, 32), 64, 0, stream>>>(xhi, bounds, pooled);
  mlp_kernel<<<GG, 512, 0, stream>>>(pooled, bounds, Wp1, bp1, Wp2, bp2, (float*)d_out);
}

// Round 19
// 319.284 us; speedup vs baseline: 1.2104x; 1.0077x over previous
//
#include <hip/hip_runtime.h>
#include <math.h>

#define HC 256      // H*C
#define NHEAD 4
#define NEG_SLOPE 0.2f
#define GG 64       // graphs

typedef unsigned short u16;
typedef unsigned int u32;
typedef __attribute__((ext_vector_type(8))) short short8;
typedef __attribute__((ext_vector_type(4))) float f32x4;

static __device__ inline u16 f2bf_rn(float f) {
  u32 x = __float_as_uint(f);
  u32 r = (x + 0x7fffu + ((x >> 16) & 1u)) >> 16;
  return (u16)r;
}
static __device__ inline float bf2f(u16 u) { return __uint_as_float(((u32)u) << 16); }

// ---------------- CSR build ----------------

__global__ void count_deg_kernel(const int* __restrict__ ei, int E, int Nn, int* __restrict__ deg) {
  int idx = blockIdx.x * 256 + threadIdx.x;
  int Et = E + Nn;
  if (idx >= Et) return;
  int d = (idx < E) ? ei[E + idx] : (idx - E);   // row1 of edge_index = dst; self loops appended
  atomicAdd(&deg[d], 1);
}

__global__ void scan_partial_kernel(const int* __restrict__ deg, int Nn,
                                    int* __restrict__ rowptr, int* __restrict__ bsum) {
  __shared__ int s[256];
  int t = threadIdx.x, i = blockIdx.x * 256 + t;
  int v = (i < Nn) ? deg[i] : 0;
  s[t] = v; __syncthreads();
  for (int off = 1; off < 256; off <<= 1) {
    int x = (t >= off) ? s[t - off] : 0; __syncthreads();
    s[t] += x; __syncthreads();
  }
  if (i < Nn) rowptr[i] = s[t] - v;          // exclusive within block
  if (t == 255) bsum[blockIdx.x] = s[t];     // block total
}

__global__ void scan_bsum_kernel(int* __restrict__ bsum, int nb) {
  __shared__ int s[512];
  int t = threadIdx.x;
  int v = (t < nb) ? bsum[t] : 0;
  s[t] = v; __syncthreads();
  for (int off = 1; off < 512; off <<= 1) {
    int x = (t >= off) ? s[t - off] : 0; __syncthreads();
    s[t] += x; __syncthreads();
  }
  if (t < nb) bsum[t] = s[t] - v;            // exclusive block offsets
}

__global__ void scan_add_kernel(int* __restrict__ rowptr, const int* __restrict__ bsum,
                                int Nn, int Etot) {
  int i = blockIdx.x * 256 + threadIdx.x;
  if (i < Nn) rowptr[i] += bsum[blockIdx.x];
  if (i == 0) rowptr[Nn] = Etot;
}

__global__ void fill_csr_kernel(const int* __restrict__ ei, int E, int Nn,
                                const int* __restrict__ rowptr, int* __restrict__ cursor,
                                int* __restrict__ col) {
  int idx = blockIdx.x * 256 + threadIdx.x;
  int Et = E + Nn;
  if (idx >= Et) return;
  int s, d;
  if (idx < E) { s = ei[idx]; d = ei[E + idx]; } else { s = d = idx - E; }
  int pos = atomicAdd(&cursor[d], 1);
  col[rowptr[d] + pos] = s;
}

// ---------------- merged prep: W2/W3 transpose+bf16, graph bounds ----------------

__global__ void prep_misc_kernel(const float* __restrict__ W2, const float* __restrict__ W3,
                                 u16* __restrict__ W2t, u16* __restrict__ W3t,
                                 const int* __restrict__ batch, int Nn, int* __restrict__ bounds) {
  int b = blockIdx.x;
  if (b < 512) {
    const float* W = (b < 256) ? W2 : W3;
    u16* dst = (b < 256) ? W2t : W3t;
    int idx = (b & 255) * 256 + threadIdx.x;
    int k = idx >> 8, n = idx & 255;           // coalesced read of W[k][n]
    dst[n * 256 + k] = f2bf_rn(W[idx]);
  } else {
    int g = threadIdx.x;
    if (g > GG) return;
    int lo = 0, hi = Nn;
    while (lo < hi) { int mid = (lo + hi) >> 1; if (batch[mid] < g) lo = mid + 1; else hi = mid; }
    bounds[g] = lo;                            // lower_bound of g; bounds[64] = N
  }
}

// ---------------- layer 1: fully fused (va + logits + softmax + x-gather + expand) --------
// Phase 1 (thread-per-node): xbar -> LDS. Phase 2 (wave-per-node over the same
// 256 nodes): expand xbar @ W1 + b1, ELU, bf16 out. W1/b1 operands hoisted.

__global__ __launch_bounds__(256) void l1_fused_kernel(const float* __restrict__ x,
    const float* __restrict__ W1, const float* __restrict__ a1s, const float* __restrict__ a1d,
    const float* __restrict__ b1, const int* __restrict__ rowptr, const int* __restrict__ col,
    u16* __restrict__ out16, int Nn) {
  __shared__ float va[16];
  __shared__ float xb_s[256][8];
  int t = threadIdx.x, q = t >> 6, lane = t & 63, wid = t >> 6;
  {
    float asv = a1s[t], adv = a1d[t];
    float w0 = W1[t], w1 = W1[256 + t];
    float s0 = w0 * asv, s1 = w1 * asv, d0 = w0 * adv, d1 = w1 * adv;
    #pragma unroll
    for (int off = 32; off >= 1; off >>= 1) {
      s0 += __shfl_xor(s0, off, 64); s1 += __shfl_xor(s1, off, 64);
      d0 += __shfl_xor(d0, off, 64); d1 += __shfl_xor(d1, off, 64);
    }
    if (lane == 0) { va[q] = s0; va[4 + q] = s1; va[8 + q] = d0; va[12 + q] = d1; }
  }
  __syncthreads();
  int base = blockIdx.x * 256;
  int node = base + t;
  if (node < Nn) {
    float4 vs0 = *(const float4*)&va[0], vs1 = *(const float4*)&va[4];
    float4 vd0 = *(const float4*)&va[8], vd1 = *(const float4*)&va[12];
    float2 xv = *(const float2*)&x[(size_t)node * 2];
    float ad0 = xv.x * vd0.x + xv.y * vd1.x;
    float ad1 = xv.x * vd0.y + xv.y * vd1.y;
    float ad2 = xv.x * vd0.z + xv.y * vd1.z;
    float ad3 = xv.x * vd0.w + xv.y * vd1.w;
    int rs = rowptr[node], re = rowptr[node + 1];
    float S0 = 0.f, S1 = 0.f, S2 = 0.f, S3 = 0.f;
    float a0 = 0.f, a1 = 0.f, a2 = 0.f, a3 = 0.f, a4 = 0.f, a5 = 0.f, a6 = 0.f, a7 = 0.f;
    for (int i = rs; i < re; ++i) {
      int s = col[i];
      float2 xs = *(const float2*)&x[(size_t)s * 2];
      float e0 = xs.x * vs0.x + xs.y * vs1.x + ad0; e0 = e0 > 0.f ? e0 : NEG_SLOPE * e0;
      float e1 = xs.x * vs0.y + xs.y * vs1.y + ad1; e1 = e1 > 0.f ? e1 : NEG_SLOPE * e1;
      float e2 = xs.x * vs0.z + xs.y * vs1.z + ad2; e2 = e2 > 0.f ? e2 : NEG_SLOPE * e2;
      float e3 = xs.x * vs0.w + xs.y * vs1.w + ad3; e3 = e3 > 0.f ? e3 : NEG_SLOPE * e3;
      float p0 = __expf(e0), p1 = __expf(e1), p2 = __expf(e2), p3 = __expf(e3);
      S0 += p0; S1 += p1; S2 += p2; S3 += p3;
      a0 += p0 * xs.x; a1 += p0 * xs.y;
      a2 += p1 * xs.x; a3 += p1 * xs.y;
      a4 += p2 * xs.x; a5 += p2 * xs.y;
      a6 += p3 * xs.x; a7 += p3 * xs.y;
    }
    float i0 = 1.f / (S0 + 1e-16f), i1 = 1.f / (S1 + 1e-16f);
    float i2 = 1.f / (S2 + 1e-16f), i3 = 1.f / (S3 + 1e-16f);
    xb_s[t][0] = a0 * i0; xb_s[t][1] = a1 * i0;
    xb_s[t][2] = a2 * i1; xb_s[t][3] = a3 * i1;
    xb_s[t][4] = a4 * i2; xb_s[t][5] = a5 * i2;
    xb_s[t][6] = a6 * i3; xb_s[t][7] = a7 * i3;
  }
  __syncthreads();
  // phase 2: expand; lane owns ch {2l,2l+1,128+2l,128+2l+1}; W/b hoisted
  int hA = lane >> 5;
  int cA = 2 * lane, cB = 128 + 2 * lane;
  float2 wA0 = *(const float2*)&W1[cA], wA1 = *(const float2*)&W1[256 + cA];
  float2 wB0 = *(const float2*)&W1[cB], wB1 = *(const float2*)&W1[256 + cB];
  float2 bA = *(const float2*)&b1[cA],  bB = *(const float2*)&b1[cB];
  u32* o32 = (u32*)out16;
  #pragma unroll 4
  for (int it = 0; it < 64; ++it) {
    int slot = it * 4 + wid;
    int nd = base + slot;
    if (nd >= Nn) break;
    float xA0 = hA ? xb_s[slot][2] : xb_s[slot][0];
    float xA1 = hA ? xb_s[slot][3] : xb_s[slot][1];
    float xB0 = hA ? xb_s[slot][6] : xb_s[slot][4];
    float xB1 = hA ? xb_s[slot][7] : xb_s[slot][5];
    float o0 = xA0 * wA0.x + xA1 * wA1.x + bA.x;
    float o1 = xA0 * wA0.y + xA1 * wA1.y + bA.y;
    float o2 = xB0 * wB0.x + xB1 * wB1.x + bB.x;
    float o3 = xB0 * wB0.y + xB1 * wB1.y + bB.y;
    o0 = o0 > 0.f ? o0 : (__expf(o0) - 1.0f);
    o1 = o1 > 0.f ? o1 : (__expf(o1) - 1.0f);
    o2 = o2 > 0.f ? o2 : (__expf(o2) - 1.0f);
    o3 = o3 > 0.f ? o3 : (__expf(o3) - 1.0f);
    o32[(size_t)nd * 128 + lane]      = (u32)f2bf_rn(o0) | ((u32)f2bf_rn(o1) << 16);
    o32[(size_t)nd * 128 + 64 + lane] = (u32)f2bf_rn(o2) | ((u32)f2bf_rn(o3) << 16);
  }
}

// ---------------- pipelined LDS MFMA GEMM: BM=32, BN=128, BK=64 (4 blocks/CU) ----------------
// Continuation of the confirmed concurrency lever (2->3 blocks/CU gave 49->40us):
// 40KB LDS -> 4 blocks/CU, 16 waves/CU. acc 1x4 (16 VGPR). N/32 exact, no tail.

#define GBM 32
#define GBN 128

__global__ __launch_bounds__(256) void gemm_mfma_kernel(
    const u16* __restrict__ A, const u16* __restrict__ Bt,
    const float* __restrict__ as_, const float* __restrict__ ad_,
    u16* __restrict__ C16, float* __restrict__ als, float* __restrict__ ald, int Mrows) {
  __shared__ __align__(16) u16 smem[20480];   // 40KB: A dbuf @0,4K; B dbuf @8K,24K
  char* base_ = (char*)smem;
  int bc = blockIdx.x, br = blockIdx.y;
  int tid = threadIdx.x;
  int wid = tid >> 6, lane = tid & 63;
  int wr = wid >> 1, wc = wid & 1;             // 2x2 waves; each 16 rows x 64 cols
  int row0 = br * GBM, col0 = bc * GBN;
  int fr = lane & 15, fg = lane >> 4;

  // staging: A 1 pass (32 rows x 128B), B 4 passes (128 rows)
  const u16* agp;
  int wofA;
  {
    int row = tid >> 3, c = tid & 7;
    int gr = row0 + row; if (gr >= Mrows) gr = Mrows - 1;
    agp = A + (size_t)gr * 256 + c * 8;        // + kt*64 at use
    wofA = row * 128 + ((c ^ (row & 7)) << 4);
  }
  const u16* bgp[4];
  int wofB[4];
  #pragma unroll
  for (int p = 0; p < 4; ++p) {
    int row = p * 32 + (tid >> 3), c = tid & 7;
    bgp[p] = Bt + (size_t)(col0 + row) * 256 + c * 8;
    wofB[p] = row * 128 + ((c ^ (row & 7)) << 4);
  }
  int rofA[2], rofB[2][4];
  #pragma unroll
  for (int ks = 0; ks < 2; ++ks) {
    int rl = wr * 16 + fr;
    rofA[ks] = rl * 128 + (((ks * 4 + fg) ^ (rl & 7)) << 4);
    #pragma unroll
    for (int n = 0; n < 4; ++n) {
      int cl_ = wc * 64 + n * 16 + fr;
      rofB[ks][n] = cl_ * 128 + (((ks * 4 + fg) ^ (cl_ & 7)) << 4);
    }
  }

  f32x4 acc[4];
  #pragma unroll
  for (int n = 0; n < 4; ++n) acc[n] = (f32x4){0.f, 0.f, 0.f, 0.f};

  uint4 va, vb[4];
  va = *(const uint4*)agp;
  #pragma unroll
  for (int p = 0; p < 4; ++p) vb[p] = *(const uint4*)bgp[p];
  *(uint4*)(base_ + wofA) = va;
  #pragma unroll
  for (int p = 0; p < 4; ++p) *(uint4*)(base_ + 8192 + wofB[p]) = vb[p];
  __syncthreads();

  #pragma unroll
  for (int kt = 0; kt < 4; ++kt) {             // K = 4 x 64
    int buf = kt & 1;
    if (kt < 3) {                              // T14: issue next-tile loads early
      va = *(const uint4*)(agp + (kt + 1) * 64);
      #pragma unroll
      for (int p = 0; p < 4; ++p) vb[p] = *(const uint4*)(bgp[p] + (kt + 1) * 64);
    }
    #pragma unroll
    for (int ks = 0; ks < 2; ++ks) {
      short8 af = *(const short8*)(base_ + buf * 4096 + rofA[ks]);
      short8 bf[4];
      #pragma unroll
      for (int n = 0; n < 4; ++n) bf[n] = *(const short8*)(base_ + 8192 + buf * 16384 + rofB[ks][n]);
      #pragma unroll
      for (int n = 0; n < 4; ++n)
        acc[n] = __builtin_amdgcn_mfma_f32_16x16x32_bf16(af, bf[n], acc[n], 0, 0, 0);
    }
    if (kt < 3) {                              // write next buffer, one barrier
      int nb = buf ^ 1;
      *(uint4*)(base_ + nb * 4096 + wofA) = va;
      #pragma unroll
      for (int p = 0; p < 4; ++p) *(uint4*)(base_ + 8192 + nb * 16384 + wofB[p]) = vb[p];
      __syncthreads();
    }
  }

  // ---- C write via LDS transpose: [32][128] bf16 = 8KB, contiguous uint4 stores ----
  u16* cl = smem;
  __syncthreads();                             // all frag reads done
  #pragma unroll
  for (int n = 0; n < 4; ++n) {
    int c = wc * 64 + n * 16 + fr;
    #pragma unroll
    for (int j = 0; j < 4; ++j) {
      int lr = wr * 16 + fg * 4 + j;
      cl[lr * 128 + c] = f2bf_rn(acc[n][j]);
    }
  }
  __syncthreads();
  #pragma unroll
  for (int i = 0; i < 2; ++i) {
    int u = i * 256 + tid;                     // uint4 index within 32x128 tile
    int lr = u >> 4, ch = u & 15;
    int grow = row0 + lr;
    if (grow < Mrows) {
      uint4 v = *(const uint4*)&cl[lr * 128 + ch * 8];
      *(uint4*)&C16[(size_t)grow * 256 + col0 + ch * 8] = v;
    }
  }

  // fused logits: this wave's 64 cols = one head
  int head = bc * 2 + wc;
  float asv[4], adv[4];
  #pragma unroll
  for (int n = 0; n < 4; ++n) {
    asv[n] = as_[head * 64 + n * 16 + fr];
    adv[n] = ad_[head * 64 + n * 16 + fr];
  }
  #pragma unroll
  for (int j = 0; j < 4; ++j) {
    float ps = 0.f, pd = 0.f;
    #pragma unroll
    for (int n = 0; n < 4; ++n) {
      ps += acc[n][j] * asv[n];
      pd += acc[n][j] * adv[n];
    }
    #pragma unroll
    for (int off = 1; off < 16; off <<= 1) {
      ps += __shfl_xor(ps, off, 64);
      pd += __shfl_xor(pd, off, 64);
    }
    int grow = row0 + wr * 16 + fg * 4 + j;
    if (fr == 0 && grow < Mrows) {
      als[grow * 4 + head] = ps;
      ald[grow * 4 + head] = pd;
    }
  }
}

// ---------------- GAT gather v5: fused edge softmax (per-head redundant, no shuffles) ----

__global__ __launch_bounds__(256) void gat_gather_kernel(const u16* __restrict__ h16,
    const float* __restrict__ als, const float* __restrict__ ald,
    const int* __restrict__ rowptr, const int* __restrict__ col,
    const float* __restrict__ bias, u16* __restrict__ out16, int Nn) {
  int node = __builtin_amdgcn_readfirstlane(blockIdx.x * 4 + (threadIdx.x >> 6));
  int lane = threadIdx.x & 63;
  if (node >= Nn) return;
  int rs = rowptr[node], re = rowptr[node + 1];
  int head = lane >> 4;                       // 16 lanes per head
  float adv = ald[(size_t)node * 4 + head];
  float S = 0.f;
  float a0 = 0.f, a1 = 0.f, a2 = 0.f, a3 = 0.f;
  const uint2* h64 = (const uint2*)h16;       // 8B units; row = 64 units
  #pragma unroll 4
  for (int i = rs; i < re; ++i) {
    int s = col[i];
    float e = als[(size_t)s * 4 + head] + adv;
    e = e > 0.f ? e : NEG_SLOPE * e;
    float p = __expf(e);                      // max-free: logits O(1)-bounded
    S += p;
    uint2 pv = h64[(size_t)s * 64 + lane];    // ch 4l..4l+3
    a0 += p * __uint_as_float(pv.x << 16);
    a1 += p * __uint_as_float(pv.x & 0xffff0000u);
    a2 += p * __uint_as_float(pv.y << 16);
    a3 += p * __uint_as_float(pv.y & 0xffff0000u);
  }
  float iS = 1.f / (S + 1e-16f);
  float4 bv = *(const float4*)&bias[4 * lane];
  float o0 = a0 * iS + bv.x;
  float o1 = a1 * iS + bv.y;
  float o2 = a2 * iS + bv.z;
  float o3 = a3 * iS + bv.w;
  o0 = o0 > 0.f ? o0 : (__expf(o0) - 1.0f);   // ELU (alpha=1)
  o1 = o1 > 0.f ? o1 : (__expf(o1) - 1.0f);
  o2 = o2 > 0.f ? o2 : (__expf(o2) - 1.0f);
  o3 = o3 > 0.f ? o3 : (__expf(o3) - 1.0f);
  uint2 ov;
  ov.x = (u32)f2bf_rn(o0) | ((u32)f2bf_rn(o1) << 16);
  ov.y = (u32)f2bf_rn(o2) | ((u32)f2bf_rn(o3) << 16);
  ((uint2*)out16)[(size_t)node * 64 + lane] = ov;
}

// ---------------- pooling + MLP ----------------

__global__ __launch_bounds__(64) void pool_kernel(const u16* __restrict__ X,
    const int* __restrict__ bounds, float* __restrict__ pooled) {
  int g = blockIdx.x, split = blockIdx.y;
  int lane = threadIdx.x;                     // 64
  int s = bounds[g], e = bounds[g + 1];
  int cnt = e - s;
  if (cnt <= 0) return;
  int chunk = (cnt + gridDim.y - 1) / gridDim.y;
  int s2 = s + split * chunk, e2 = min(e, s2 + chunk);
  if (s2 >= e2) return;
  int r = lane >> 5, c = lane & 31;           // row parity, 16B chunk
  float acc[8] = {};
  for (int n = s2 + r; n < e2; n += 2) {
    uint4 v = *(const uint4*)&X[(size_t)n * HC + c * 8];
    acc[0] += __uint_as_float(v.x << 16);
    acc[1] += __uint_as_float(v.x & 0xffff0000u);
    acc[2] += __uint_as_float(v.y << 16);
    acc[3] += __uint_as_float(v.y & 0xffff0000u);
    acc[4] += __uint_as_float(v.z << 16);
    acc[5] += __uint_as_float(v.z & 0xffff0000u);
    acc[6] += __uint_as_float(v.w << 16);
    acc[7] += __uint_as_float(v.w & 0xffff0000u);
  }
  #pragma unroll
  for (int j = 0; j < 8; ++j) acc[j] += __shfl_xor(acc[j], 32, 64);
  if (r == 0) {
    #pragma unroll
    for (int j = 0; j < 8; ++j) atomicAdd(&pooled[g * HC + c * 8 + j], acc[j]);
  }
}

__global__ __launch_bounds__(512) void mlp_kernel(const float* __restrict__ pooled,
    const int* __restrict__ bounds, const float* __restrict__ Wp1, const float* __restrict__ bp1,
    const float* __restrict__ Wp2, const float* __restrict__ bp2, float* __restrict__ out) {
  __shared__ float p[256];
  __shared__ float z1[512];
  int g = blockIdx.x, t = threadIdx.x;
  if (t < 256) {
    int cnt = bounds[g + 1] - bounds[g];
    float inv = 1.0f / (float)(cnt > 1 ? cnt : 1);
    p[t] = pooled[g * 256 + t] * inv;
  }
  __syncthreads();
  float a1 = bp1[t];
  for (int k = 0; k < 256; ++k) a1 += p[k] * Wp1[k * 512 + t];
  z1[t] = fmaxf(a1, 0.f);
  __syncthreads();
  if (t < 256) {
    float a2 = bp2[t];
    for (int k = 0; k < 512; ++k) a2 += z1[k] * Wp2[k * 256 + t];
    out[g * 256 + t] = a2;
  }
}

// ---------------- launch ----------------

static inline size_t align_up(size_t x, size_t a) { return (x + a - 1) & ~(a - 1); }

extern "C" void kernel_launch(void* const* d_in, const int* in_sizes, int n_in,
                              void* d_out, int out_size, void* d_ws, size_t ws_size,
                              hipStream_t stream) {
  const float* x    = (const float*)d_in[0];
  const int*   ei   = (const int*)d_in[1];
  const int*   batch= (const int*)d_in[2];
  const float* W1   = (const float*)d_in[3];
  const float* a1s  = (const float*)d_in[4];
  const float* a1d  = (const float*)d_in[5];
  const float* b1   = (const float*)d_in[6];
  const float* W2   = (const float*)d_in[7];
  const float* a2s  = (const float*)d_in[8];
  const float* a2d  = (const float*)d_in[9];
  const float* b2   = (const float*)d_in[10];
  const float* W3   = (const float*)d_in[11];
  const float* a3s  = (const float*)d_in[12];
  const float* a3d  = (const float*)d_in[13];
  const float* b3   = (const float*)d_in[14];
  const float* Wp1  = (const float*)d_in[15];
  const float* bp1  = (const float*)d_in[16];
  const float* Wp2  = (const float*)d_in[17];
  const float* bp2  = (const float*)d_in[18];

  const int N = in_sizes[0] / 2;       // 100000
  const int E = in_sizes[1] / 2;       // 400000
  const int Et = E + N;                // with self loops

  char* base = (char*)d_ws;
  size_t off = 0;
  auto alloc = [&](size_t bytes) { size_t o = off; off = align_up(off + bytes, 256); return o; };
  u16*   h16    = (u16*)  (base + alloc((size_t)N * HC * 2));   // message-path h (bf16)
  u16*   xhi    = (u16*)  (base + alloc((size_t)N * HC * 2));   // gather out (bf16)
  float* als    = (float*)(base + alloc((size_t)N * 4 * 4));
  float* ald    = (float*)(base + alloc((size_t)N * 4 * 4));
  int*   rowptr = (int*)  (base + alloc((size_t)(N + 1) * 4));
  int*   col    = (int*)  (base + alloc((size_t)Et * 4));
  // deg, cursor, pooled contiguous -> one memset clears all three
  size_t zoff0 = off;
  int*   deg    = (int*)  (base + alloc((size_t)N * 4));
  int*   cursor = (int*)  (base + alloc((size_t)N * 4));
  float* pooled = (float*)(base + alloc((size_t)GG * HC * 4));
  size_t zbytes = off - zoff0;
  int*   bsum   = (int*)  (base + alloc(512 * 4));
  int*   bounds = (int*)  (base + alloc((GG + 1) * 4));
  (void)ws_size; (void)n_in; (void)out_size;

  // W2t/W3t (bf16, 128KB each) parked in deg/cursor space (dead after CSR build)
  u16* W2t = (u16*)deg;
  u16* W3t = (u16*)cursor;

  hipMemsetAsync(base + zoff0, 0, zbytes, stream);   // deg + cursor + pooled

  // CSR by destination (same edge set for all layers)
  int ebk = (Et + 255) / 256;
  count_deg_kernel<<<ebk, 256, 0, stream>>>(ei, E, N, deg);
  int NT = (N + 255) / 256;
  scan_partial_kernel<<<NT, 256, 0, stream>>>(deg, N, rowptr, bsum);
  scan_bsum_kernel<<<1, 512, 0, stream>>>(bsum, NT);
  scan_add_kernel<<<NT, 256, 0, stream>>>(rowptr, bsum, N, Et);
  fill_csr_kernel<<<ebk, 256, 0, stream>>>(ei, E, N, rowptr, cursor, col);

  // merged: W conversions (deg/cursor now dead) + graph bounds
  prep_misc_kernel<<<513, 256, 0, stream>>>(W2, W3, W2t, W3t, batch, N, bounds);

  dim3 gemm_grid(HC / GBN, (N + GBM - 1) / GBM);
  int nodeblk = (N + 3) / 4;

  // layer 1 — single fused kernel: va + logits + softmax + x-gather + expand
  l1_fused_kernel<<<NT, 256, 0, stream>>>(x, W1, a1s, a1d, b1, rowptr, col, xhi, N);
  // layer 2 (edge softmax fused into gather)
  gemm_mfma_kernel<<<gemm_grid, 256, 0, stream>>>(xhi, W2t, a2s, a2d, h16, als, ald, N);
  gat_gather_kernel<<<nodeblk, 256, 0, stream>>>(h16, als, ald, rowptr, col, b2, xhi, N);
  // layer 3
  gemm_mfma_kernel<<<gemm_grid, 256, 0, stream>>>(xhi, W3t, a3s, a3d, h16, als, ald, N);
  gat_gather_kernel<<<nodeblk, 256, 0, stream>>>(h16, als, ald, rowptr, col, b3, xhi, N);

  // pool + MLP
  pool_kernel<<<dim3(GG, 32), 64, 0, stream>>>(xhi, bounds, pooled);
  mlp_kernel<<<GG, 512, 0, stream>>>(pooled, bounds, Wp1, bp1, Wp2, bp2, (float*)d_out);
}